// Round 8
// baseline (1319.978 us; speedup 1.0000x reference)
//
#include <hip/hip_runtime.h>
#include <hip/hip_bf16.h>

// WaveNet forward on gfx950 — round 8 (supertile W/X reuse + 3-phase gated loop).
// Fused layer kernel: gated dilated conv (MFMA) + in-LDS acts + residual conv.
// Split-bf16 (hi/lo, 3-plane) arithmetic; fast exp2/rcp activations.
// Gated K-loop: 8 superchunks, each stages {Whi,Wlo,Xhi,Xlo} once and runs
// 3 MFMA phases (Whi*Xhi, Whi*Xlo, Wlo*Xhi) -> 33% less staging + LDS reads,
// 16 barriers instead of 48, counted vmcnt keeps loads in flight.
// Fallback (ws too small): round-1 fp32 VALU path.

#define KC 32

typedef __bf16 bf16_t;
typedef __bf16 bf16x4 __attribute__((ext_vector_type(4)));
typedef __bf16 bf16x8 __attribute__((ext_vector_type(8)));
typedef float f32x16 __attribute__((ext_vector_type(16)));

__device__ __align__(16) __bf16 g_wi_dev[98304];   // w_in split+swizzled
__device__ float g_pooled[4096];                    // [b][256] pooled skip

__device__ __forceinline__ void gl_lds16(const void* g, void* l) {
    __builtin_amdgcn_global_load_lds(
        (const __attribute__((address_space(1))) unsigned int*)g,
        (__attribute__((address_space(3))) unsigned int*)l, 16, 0, 0);
}

__device__ __forceinline__ float fast_sigmoid(float x) {
    float e = __builtin_amdgcn_exp2f(-1.4426950408889634f * x);
    return __builtin_amdgcn_rcpf(1.0f + e);
}
__device__ __forceinline__ float fast_tanh(float x) {
    float e = __builtin_amdgcn_exp2f(-2.8853900817779268f * x);
    return fmaf(2.0f, __builtin_amdgcn_rcpf(1.0f + e), -1.0f);
}

// ---------------- weight prep: split + swizzle ----------------
// wg layout per layer: 16 chunks of 16KB: c in [0,8) = Whi over k=(c)*32..,
// c in [8,16) = Wlo over k=(c-8)*32.. ; chunk: [row<256][slot ps<4][e<8],
// content slot s = ps ^ ((row>>1)&3); k = c32*32 + s*8 + e; tap=k>>7, ch=k&127.
__global__ __launch_bounds__(256) void prep_wg_kernel(
    const float* __restrict__ dw, bf16_t* __restrict__ wg)
{
    int idx = blockIdx.x * 256 + threadIdx.x;   // 2,097,152
    int e = idx & 7, ps = (idx >> 3) & 3, row = (idx >> 5) & 255;
    int c = (idx >> 13) & 15, layer = idx >> 17;
    int s = ps ^ ((row >> 1) & 3);
    int k = (c & 7) * 32 + s * 8 + e;
    int tap = k >> 7, ch = k & 127;
    float w = dw[(((size_t)layer * 256 + row) * 128 + ch) * 2 + tap];
    bf16_t hb = (bf16_t)w;
    wg[idx] = (c < 8) ? hb : (bf16_t)(w - (float)hb);
}

__global__ __launch_bounds__(256) void prep_wr_kernel(
    const float* __restrict__ rw, bf16_t* __restrict__ wr)
{
    int idx = blockIdx.x * 256 + threadIdx.x;   // 737,280
    int e = idx & 7, ps = (idx >> 3) & 3, row = (idx >> 5) & 127;
    int lc = idx >> 12, c = lc % 12, layer = lc / 12;
    int s = ps ^ ((row >> 1) & 3);
    int k = c * 32 + s * 8 + e;
    int plane = k >> 7, ch = k & 127;
    float w = rw[((size_t)layer * 128 + row) * 128 + ch];
    bf16_t hb = (bf16_t)w;
    wr[idx] = (plane < 2) ? hb : (bf16_t)(w - (float)hb);
}

__global__ __launch_bounds__(256) void prep_wi_kernel(const float* __restrict__ wi)
{
    int idx = blockIdx.x * 256 + threadIdx.x;   // 98,304
    int e = idx & 7, ps = (idx >> 3) & 3, row = (idx >> 5) & 127;
    int c = idx >> 12;                          // 0..23
    int s = ps ^ ((row >> 1) & 3);
    int k = c * 32 + s * 8 + e;
    int plane = k >> 8, ch = k & 255;
    float w = wi[(size_t)row * 256 + ch];
    bf16_t hb = (bf16_t)w;
    g_wi_dev[idx] = (plane < 2) ? hb : (bf16_t)(w - (float)hb);
}

__global__ __launch_bounds__(256) void zero_misc_kernel(bf16_t* __restrict__ zeros)
{
    int idx = blockIdx.x * 256 + threadIdx.x;   // 32768
    zeros[idx] = (bf16_t)0.0f;
    if (idx < 4096) g_pooled[idx] = 0.0f;
}

// ---------------- input transpose: fp32 [ch][t] -> bf16 hi/lo [t][ch] ----------------
__global__ __launch_bounds__(256) void transpose_in(
    const float* __restrict__ input, bf16_t* __restrict__ th,
    bf16_t* __restrict__ tl, int b_off)
{
    __shared__ float Sl[64][65];
    const int tid = threadIdx.x;
    const int t0 = blockIdx.x * 64, ch0 = blockIdx.y * 64, bz = blockIdx.z;
    const int b = b_off + bz;
#pragma unroll
    for (int it = 0; it < 16; ++it) {
        int idx = it * 256 + tid;
        int t = idx & 63, ch = idx >> 6;
        Sl[ch][t] = input[((size_t)b * 256 + ch0 + ch) * 4096 + t0 + t];
    }
    __syncthreads();
#pragma unroll
    for (int it = 0; it < 16; ++it) {
        int idx = it * 256 + tid;
        int ch = idx & 63, t = idx >> 6;
        float v = Sl[ch][t];
        bf16_t hb = (bf16_t)v;
        size_t o = ((size_t)bz * 4096 + t0 + t) * 256 + ch0 + ch;
        th[o] = hb;
        tl[o] = (bf16_t)(v - (float)hb);
    }
}

// ---------------- fused layer: gated conv + acts + residual conv ----------------
// 512 threads (8 waves). LDS 80KB:
//   gated loop : Whi 2x16K [0,32K), Wlo 1x16K [32K,48K),
//                Xhi 2x8K [49152,65536), Xlo 2x8K [65536,81920)
//   epilogue   : acts hi [0,32K), acts lo [32K,64K), resW dbuf [64K,80K)
__global__ __launch_bounds__(512, 4) void fused_layer(
    const bf16_t* __restrict__ xc_hi, const bf16_t* __restrict__ xc_lo,
    bf16_t* __restrict__ xn_hi, bf16_t* __restrict__ xn_lo,
    const bf16_t* __restrict__ zeros,
    const bf16_t* __restrict__ wg_l, const float* __restrict__ dbias,
    const bf16_t* __restrict__ wr_l, const float* __restrict__ rbias,
    float* __restrict__ asum_l, int d, int skipres)
{
    __shared__ __align__(16) char lds[81920];
    const int tid = threadIdx.x;
    const int wave = tid >> 6, lane = tid & 63;
    const int l31 = lane & 31, h = lane >> 5;
    const int wm = wave & 3, wn = wave >> 2;
    const int t0 = blockIdx.x * 128;
    const int b = blockIdx.z;

    f32x16 acc[2][2];
#pragma unroll
    for (int m = 0; m < 2; ++m)
#pragma unroll
        for (int n = 0; n < 2; ++n) acc[m][n] = (f32x16)(0.0f);

    const int t_pos = tid >> 2;
    const int s_x = (tid & 3) ^ ((t_pos >> 1) & 3);
    const int chx = s_x << 3;

    auto stage_whi = [&](int u) {            // 2 loads/thread, slot u&1
        const char* src = (const char*)wg_l + (size_t)u * 16384;
        char* dst = lds + (u & 1) * 16384;
        gl_lds16(src + tid * 16, dst + tid * 16);
        gl_lds16(src + (tid + 512) * 16, dst + (tid + 512) * 16);
    };
    auto stage_wlo = [&](int u) {            // 2 loads/thread, single slot
        const char* src = (const char*)wg_l + (size_t)(8 + u) * 16384;
        char* dst = lds + 32768;
        gl_lds16(src + tid * 16, dst + tid * 16);
        gl_lds16(src + (tid + 512) * 16, dst + (tid + 512) * 16);
    };
    auto stage_x = [&](int u) {              // 2 loads/thread (hi+lo), slot u&1
        int tap = (u >> 2) & 1;
        int ch = ((u & 3) << 5) + chx;
        int tg = t0 + t_pos - (tap ? 0 : d);
        size_t gi = ((size_t)b * 4096 + tg) * 128 + ch;
        const bf16_t* sph = (tg >= 0) ? (xc_hi + gi) : (zeros + ch);
        const bf16_t* spl = (tg >= 0) ? (xc_lo + gi) : (zeros + ch);
        gl_lds16(sph, lds + 49152 + (u & 1) * 8192 + tid * 16);
        gl_lds16(spl, lds + 65536 + (u & 1) * 8192 + tid * 16);
    };

    // prologue
    stage_whi(0);
    stage_x(0);

    const int swz = (l31 >> 1) & 3;
    int aoff[2][2], boff[2][2];
#pragma unroll
    for (int m = 0; m < 2; ++m)
#pragma unroll
        for (int s2 = 0; s2 < 2; ++s2)
            aoff[m][s2] = ((m ? 128 + wm * 32 : wm * 32) + l31) * 64 +
                          (((s2 * 2 + h) ^ swz) << 4);
#pragma unroll
    for (int n = 0; n < 2; ++n)
#pragma unroll
        for (int s2 = 0; s2 < 2; ++s2)
            boff[n][s2] = (wn * 64 + n * 32 + l31) * 64 + (((s2 * 2 + h) ^ swz) << 4);

    for (int u = 0; u < 8; ++u) {
        // P0-issue: Wlo[u] (used in P2), Whi[u+1]
        stage_wlo(u);
        if (u < 7) {
            stage_whi(u + 1);
            asm volatile("s_waitcnt vmcnt(4)" ::: "memory"); // Whi[u], X[u] landed
        } else {
            asm volatile("s_waitcnt vmcnt(2)" ::: "memory");
        }
        __builtin_amdgcn_s_barrier();

        const char* whb = lds + (u & 1) * 16384;
        const char* xhb = lds + 49152 + (u & 1) * 8192;
        const char* xlb = lds + 65536 + (u & 1) * 8192;

        // ---- P0: Whi x Xhi ----
        {
            bf16x8 a0[2], a1[2], b0[2], b1[2];
#pragma unroll
            for (int s2 = 0; s2 < 2; ++s2) {
                a0[s2] = *(const bf16x8*)(whb + aoff[0][s2]);
                a1[s2] = *(const bf16x8*)(whb + aoff[1][s2]);
                b0[s2] = *(const bf16x8*)(xhb + boff[0][s2]);
                b1[s2] = *(const bf16x8*)(xhb + boff[1][s2]);
            }
            __builtin_amdgcn_s_setprio(1);
#pragma unroll
            for (int s2 = 0; s2 < 2; ++s2) {
                acc[0][0] = __builtin_amdgcn_mfma_f32_32x32x16_bf16(a0[s2], b0[s2], acc[0][0], 0, 0, 0);
                acc[0][1] = __builtin_amdgcn_mfma_f32_32x32x16_bf16(a0[s2], b1[s2], acc[0][1], 0, 0, 0);
                acc[1][0] = __builtin_amdgcn_mfma_f32_32x32x16_bf16(a1[s2], b0[s2], acc[1][0], 0, 0, 0);
                acc[1][1] = __builtin_amdgcn_mfma_f32_32x32x16_bf16(a1[s2], b1[s2], acc[1][1], 0, 0, 0);
            }
            __builtin_amdgcn_s_setprio(0);
        }

        // ---- P1: Whi x Xlo (issue X[u+1]; no barrier needed) ----
        if (u < 7) stage_x(u + 1);
        {
            bf16x8 a0[2], a1[2], b0[2], b1[2];
#pragma unroll
            for (int s2 = 0; s2 < 2; ++s2) {
                a0[s2] = *(const bf16x8*)(whb + aoff[0][s2]);
                a1[s2] = *(const bf16x8*)(whb + aoff[1][s2]);
                b0[s2] = *(const bf16x8*)(xlb + boff[0][s2]);
                b1[s2] = *(const bf16x8*)(xlb + boff[1][s2]);
            }
            __builtin_amdgcn_s_setprio(1);
#pragma unroll
            for (int s2 = 0; s2 < 2; ++s2) {
                acc[0][0] = __builtin_amdgcn_mfma_f32_32x32x16_bf16(a0[s2], b0[s2], acc[0][0], 0, 0, 0);
                acc[0][1] = __builtin_amdgcn_mfma_f32_32x32x16_bf16(a0[s2], b1[s2], acc[0][1], 0, 0, 0);
                acc[1][0] = __builtin_amdgcn_mfma_f32_32x32x16_bf16(a1[s2], b0[s2], acc[1][0], 0, 0, 0);
                acc[1][1] = __builtin_amdgcn_mfma_f32_32x32x16_bf16(a1[s2], b1[s2], acc[1][1], 0, 0, 0);
            }
            __builtin_amdgcn_s_setprio(0);
        }

        // ---- P2: Wlo x Xhi ----
        if (u < 7) {
            asm volatile("s_waitcnt vmcnt(4)" ::: "memory"); // Wlo[u] landed
        } else {
            asm volatile("s_waitcnt vmcnt(0)" ::: "memory");
        }
        __builtin_amdgcn_s_barrier();
        {
            const char* wlb = lds + 32768;
            bf16x8 a0[2], a1[2], b0[2], b1[2];
#pragma unroll
            for (int s2 = 0; s2 < 2; ++s2) {
                a0[s2] = *(const bf16x8*)(wlb + aoff[0][s2]);
                a1[s2] = *(const bf16x8*)(wlb + aoff[1][s2]);
                b0[s2] = *(const bf16x8*)(xhb + boff[0][s2]);
                b1[s2] = *(const bf16x8*)(xhb + boff[1][s2]);
            }
            __builtin_amdgcn_s_setprio(1);
#pragma unroll
            for (int s2 = 0; s2 < 2; ++s2) {
                acc[0][0] = __builtin_amdgcn_mfma_f32_32x32x16_bf16(a0[s2], b0[s2], acc[0][0], 0, 0, 0);
                acc[0][1] = __builtin_amdgcn_mfma_f32_32x32x16_bf16(a0[s2], b1[s2], acc[0][1], 0, 0, 0);
                acc[1][0] = __builtin_amdgcn_mfma_f32_32x32x16_bf16(a1[s2], b0[s2], acc[1][0], 0, 0, 0);
                acc[1][1] = __builtin_amdgcn_mfma_f32_32x32x16_bf16(a1[s2], b1[s2], acc[1][1], 0, 0, 0);
            }
            __builtin_amdgcn_s_setprio(0);
        }
        __builtin_amdgcn_s_barrier();  // protect Wlo/X/Whi slots from restage
    }
    __syncthreads();

    // ---- acts epilogue ----
    auto stage_rw = [&](int c, int sl) {
        gl_lds16((const char*)wr_l + (size_t)c * 8192 + tid * 16,
                 lds + 65536 + sl * 8192 + tid * 16);
    };
    if (!skipres) stage_rw(0, 0);   // HBM latency hides under activation VALU

    float psum[16];
#pragma unroll
    for (int u = 0; u < 16; ++u) psum[u] = 0.0f;

#pragma unroll
    for (int n = 0; n < 2; ++n) {
        int t = wn * 64 + n * 32 + l31;
        int sw = (t & 7) << 4;
#pragma unroll
        for (int rg = 0; rg < 4; ++rg) {
            int ch0 = wm * 32 + rg * 8 + 4 * h;
            bf16x4 hv, lv;
#pragma unroll
            for (int j = 0; j < 4; ++j) {
                int r = rg * 4 + j;
                float a1v = acc[0][n][r] + dbias[ch0 + j];
                float a2v = acc[1][n][r] + dbias[128 + ch0 + j];
                float a = fast_tanh(a1v) * fast_sigmoid(a2v);
                psum[rg * 4 + j] += a;
                bf16_t hb = (bf16_t)a;
                hv[j] = hb;
                lv[j] = (bf16_t)(a - (float)hb);
            }
            int low = (ch0 * 2) ^ sw;
            *(bf16x4*)(lds + t * 256 + low) = hv;
            *(bf16x4*)(lds + 32768 + t * 256 + low) = lv;
        }
    }

#pragma unroll
    for (int u = 0; u < 16; ++u) {
        float v = psum[u];
        v += __shfl_xor(v, 1);
        v += __shfl_xor(v, 2);
        v += __shfl_xor(v, 4);
        v += __shfl_xor(v, 8);
        v += __shfl_xor(v, 16);
        psum[u] = v;
    }
    if (l31 == 0) {
#pragma unroll
        for (int u = 0; u < 16; ++u) {
            int ch = wm * 32 + (u >> 2) * 8 + 4 * h + (u & 3);
            atomicAdd(asum_l + b * 128 + ch, psum[u]);
        }
    }
    if (skipres) return;

    asm volatile("s_waitcnt lgkmcnt(0)" ::: "memory");
    __builtin_amdgcn_s_barrier();   // acts visible to all waves (resW c0 in flight)

    // ---- residual K-loop: M=128(x ch) x N=128(t), K''=384, 12 chunks ----
    f32x16 accr[2];
    accr[0] = (f32x16)(0.0f);
    accr[1] = (f32x16)(0.0f);
    int tl_[2], mk_[2];
#pragma unroll
    for (int n = 0; n < 2; ++n) {
        tl_[n] = wn * 64 + n * 32 + l31;
        mk_[n] = (tl_[n] & 7) << 4;
    }

    for (int c = 0; c < 12; ++c) {
        if (c < 11) {
            stage_rw(c + 1, (c + 1) & 1);
            asm volatile("s_waitcnt vmcnt(1)" ::: "memory");
        } else {
            asm volatile("s_waitcnt vmcnt(0)" ::: "memory");
        }
        __builtin_amdgcn_s_barrier();

        const char* ab = lds + 65536 + (c & 1) * 8192;
        int p = c >> 2;
        int cb = (c & 3) << 6;
        const char* bb = lds + (p == 1 ? 32768 : 0);
        bf16x8 av[2], bv[2][2];
#pragma unroll
        for (int s2 = 0; s2 < 2; ++s2) {
            av[s2] = *(const bf16x8*)(ab + (wm * 32 + l31) * 64 +
                                      (((s2 * 2 + h) ^ swz) << 4));
#pragma unroll
            for (int n = 0; n < 2; ++n) {
                int low = (cb + ((s2 * 2 + h) << 4)) ^ mk_[n];
                bv[n][s2] = *(const bf16x8*)(bb + tl_[n] * 256 + low);
            }
        }
        __builtin_amdgcn_s_setprio(1);
#pragma unroll
        for (int s2 = 0; s2 < 2; ++s2) {
            accr[0] = __builtin_amdgcn_mfma_f32_32x32x16_bf16(av[s2], bv[0][s2], accr[0], 0, 0, 0);
            accr[1] = __builtin_amdgcn_mfma_f32_32x32x16_bf16(av[s2], bv[1][s2], accr[1], 0, 0, 0);
        }
        __builtin_amdgcn_s_setprio(0);
        __builtin_amdgcn_s_barrier();
    }

    // ---- residual epilogue: x_new = accr + rbias + x_old(hi+lo) ----
#pragma unroll
    for (int n = 0; n < 2; ++n) {
        int t = tl_[n];
        size_t trow = ((size_t)b * 4096 + t0 + t) * 128;
#pragma unroll
        for (int rg = 0; rg < 4; ++rg) {
            int ch0 = wm * 32 + rg * 8 + 4 * h;
            bf16x4 oh = *(const bf16x4*)(xc_hi + trow + ch0);
            bf16x4 ol = *(const bf16x4*)(xc_lo + trow + ch0);
            bf16x4 nh, nl;
#pragma unroll
            for (int j = 0; j < 4; ++j) {
                float v = accr[n][rg * 4 + j] + rbias[ch0 + j] +
                          (float)oh[j] + (float)ol[j];
                bf16_t hb = (bf16_t)v;
                nh[j] = hb;
                nl[j] = (bf16_t)(v - (float)hb);
            }
            *(bf16x4*)(xn_hi + trow + ch0) = nh;
            *(bf16x4*)(xn_lo + trow + ch0) = nl;
        }
    }
}

// ---------------- input pointwise MFMA (K=256, 3 planes) ----------------
__global__ __launch_bounds__(256) void pw_mfma_in(
    const bf16_t* __restrict__ sh, const bf16_t* __restrict__ sl,
    const float* __restrict__ bias,
    bf16_t* __restrict__ xth, bf16_t* __restrict__ xtl, int b_off)
{
    constexpr int NCHUNK = 24;
    __shared__ __align__(16) char lds[32768];
    const int tid = threadIdx.x;
    const int wave = tid >> 6, lane = tid & 63;
    const int l31 = lane & 31, h = lane >> 5;
    const int wm = wave & 1, wn = wave >> 1;
    const int t0 = blockIdx.x * 128;
    const int bz = blockIdx.z;
    const bf16_t* w = (const bf16_t*)g_wi_dev;

    f32x16 acc[2][2];
#pragma unroll
    for (int m = 0; m < 2; ++m)
#pragma unroll
        for (int n = 0; n < 2; ++n) acc[m][n] = (f32x16)(0.0f);

    auto stage = [&](int c, int sl_) {
        const char* wsrc = (const char*)w + (size_t)c * 8192;
        char* wdst = lds + sl_ * 8192;
#pragma unroll
        for (int it = 0; it < 2; ++it) {
            int g = tid + 256 * it;
            gl_lds16(wsrc + g * 16, wdst + g * 16);
        }
        int plane = c / 8;
        int chb = (c % 8) * 32;
        const bf16_t* src = (plane == 1) ? sl : sh;
#pragma unroll
        for (int it = 0; it < 2; ++it) {
            int row = (tid >> 2) + it * 64;
            int ps = tid & 3;
            int s_x = ps ^ ((row >> 1) & 3);
            size_t gi = ((size_t)bz * 4096 + t0 + row) * 256 + chb + s_x * 8;
            gl_lds16(src + gi, lds + 16384 + sl_ * 8192 + (row * 4 + ps) * 16);
        }
    };

    stage(0, 0);
    const int swz = (l31 >> 1) & 3;
    int aoff[2][2], boff[2][2];
#pragma unroll
    for (int m = 0; m < 2; ++m)
#pragma unroll
        for (int s2 = 0; s2 < 2; ++s2)
            aoff[m][s2] = (wm * 64 + m * 32 + l31) * 64 + (((s2 * 2 + h) ^ swz) << 4);
#pragma unroll
    for (int n = 0; n < 2; ++n)
#pragma unroll
        for (int s2 = 0; s2 < 2; ++s2)
            boff[n][s2] = (wn * 64 + n * 32 + l31) * 64 + (((s2 * 2 + h) ^ swz) << 4);

    for (int c = 0; c < NCHUNK; ++c) {
        if (c < NCHUNK - 1) {
            stage(c + 1, (c + 1) & 1);
            asm volatile("s_waitcnt vmcnt(4)" ::: "memory");
        } else {
            asm volatile("s_waitcnt vmcnt(0)" ::: "memory");
        }
        __builtin_amdgcn_s_barrier();

        const char* wb = lds + (c & 1) * 8192;
        const char* xb = lds + 16384 + (c & 1) * 8192;
#pragma unroll
        for (int s2 = 0; s2 < 2; ++s2) {
            bf16x8 a0 = *(const bf16x8*)(wb + aoff[0][s2]);
            bf16x8 a1 = *(const bf16x8*)(wb + aoff[1][s2]);
            bf16x8 b0 = *(const bf16x8*)(xb + boff[0][s2]);
            bf16x8 b1 = *(const bf16x8*)(xb + boff[1][s2]);
            acc[0][0] = __builtin_amdgcn_mfma_f32_32x32x16_bf16(a0, b0, acc[0][0], 0, 0, 0);
            acc[0][1] = __builtin_amdgcn_mfma_f32_32x32x16_bf16(a0, b1, acc[0][1], 0, 0, 0);
            acc[1][0] = __builtin_amdgcn_mfma_f32_32x32x16_bf16(a1, b0, acc[1][0], 0, 0, 0);
            acc[1][1] = __builtin_amdgcn_mfma_f32_32x32x16_bf16(a1, b1, acc[1][1], 0, 0, 0);
        }
        __builtin_amdgcn_s_barrier();
    }

    const int b = b_off + bz;
#pragma unroll
    for (int n = 0; n < 2; ++n) {
        int t = wn * 64 + n * 32 + l31;
        size_t trow = ((size_t)b * 4096 + t0 + t) * 128;
#pragma unroll
        for (int m = 0; m < 2; ++m) {
#pragma unroll
            for (int rg = 0; rg < 4; ++rg) {
                int ch0 = wm * 64 + m * 32 + rg * 8 + 4 * h;
                bf16x4 nh, nl;
#pragma unroll
                for (int j = 0; j < 4; ++j) {
                    float v = acc[m][n][rg * 4 + j] + bias[ch0 + j];
                    bf16_t hb = (bf16_t)v;
                    nh[j] = hb;
                    nl[j] = (bf16_t)(v - (float)hb);
                }
                *(bf16x4*)(xth + trow + ch0) = nh;
                *(bf16x4*)(xtl + trow + ch0) = nl;
            }
        }
    }
}

// ---------------- output head ----------------
__global__ __launch_bounds__(256) void skip_partial(
    const float* __restrict__ asum, const float* __restrict__ skip_w)
{
    const int i = blockIdx.x >> 4, b = blockIdx.x & 15, s = threadIdx.x;
    const float* sw = skip_w + ((size_t)i * 256 + s) * 128;
    const float* as = asum + i * 2048 + b * 128;
    float t = 0.0f;
#pragma unroll 8
    for (int r = 0; r < 128; ++r) t = fmaf(sw[r], as[r], t);
    atomicAdd(&g_pooled[b * 256 + s], t);
}

__global__ __launch_bounds__(256) void head_kernel(
    const float* __restrict__ skip_b, const float* __restrict__ w_out,
    const float* __restrict__ lin_w, const float* __restrict__ lin_b,
    float* __restrict__ out)
{
    const int b = blockIdx.x;
    const int s = threadIdx.x;
    float sb = 0.0f;
#pragma unroll
    for (int i = 0; i < 16; ++i) sb += skip_b[i * 256 + s];
    __shared__ float pl[256];
    pl[s] = g_pooled[b * 256 + s] * (1.0f / 4096.0f) + sb;
    __syncthreads();
    __shared__ float o1[12];
    if (s < 12) {
        float v = 0.0f;
        for (int q = 0; q < 256; ++q) v = fmaf(w_out[s * 256 + q], pl[q], v);
        o1[s] = v;
    }
    __syncthreads();
    if (s < 12) {
        float v = lin_b[s];
#pragma unroll
        for (int m = 0; m < 12; ++m) v = fmaf(lin_w[s * 12 + m], o1[m], v);
        out[b * 12 + s] = v;
    }
}

// ================= fallback fp32 path (round-1, proven) =================
__global__ __launch_bounds__(256) void pw_conv_kernel(
    const float* __restrict__ src, const float* __restrict__ W,
    const float* __restrict__ bias, float* __restrict__ dst,
    int K, int accumulate)
{
    __shared__ float Wl[KC][68];
    __shared__ float Sl[KC][68];
    const int tid = threadIdx.x;
    const int t0 = blockIdx.x * 64;
    const int row0 = blockIdx.y * 64;
    const int b = blockIdx.z;
    const int i4 = (tid >> 4) * 4;
    const int j4 = (tid & 15) * 4;
    float acc[4][4];
#pragma unroll
    for (int r = 0; r < 4; ++r) {
        float bv = bias[row0 + i4 + r];
#pragma unroll
        for (int c = 0; c < 4; ++c) acc[r][c] = bv;
    }
    const float* sb = src + (size_t)b * K * 4096;
    for (int k0 = 0; k0 < K; k0 += KC) {
        __syncthreads();
#pragma unroll
        for (int it = 0; it < 8; ++it) {
            int idx = it * 256 + tid;
            int kk = idx & 31, oo = idx >> 5;
            Wl[kk][oo] = W[(size_t)(row0 + oo) * K + (k0 + kk)];
        }
#pragma unroll
        for (int it = 0; it < 8; ++it) {
            int idx = it * 256 + tid;
            int t = idx & 63, kk = idx >> 6;
            Sl[kk][t] = sb[(size_t)(k0 + kk) * 4096 + t0 + t];
        }
        __syncthreads();
#pragma unroll
        for (int kk = 0; kk < KC; ++kk) {
            float4 wv = *(const float4*)&Wl[kk][i4];
            float4 sv = *(const float4*)&Sl[kk][j4];
            float wr_[4] = {wv.x, wv.y, wv.z, wv.w};
            float sc[4] = {sv.x, sv.y, sv.z, sv.w};
#pragma unroll
            for (int r = 0; r < 4; ++r)
#pragma unroll
                for (int c = 0; c < 4; ++c)
                    acc[r][c] = fmaf(wr_[r], sc[c], acc[r][c]);
        }
    }
    float* db = dst + (size_t)b * 128 * 4096;
#pragma unroll
    for (int r = 0; r < 4; ++r) {
        float* p = db + (size_t)(row0 + i4 + r) * 4096 + t0 + j4;
        float4 v;
        if (accumulate) {
            float4 old = *(const float4*)p;
            v.x = acc[r][0] + old.x; v.y = acc[r][1] + old.y;
            v.z = acc[r][2] + old.z; v.w = acc[r][3] + old.w;
        } else {
            v.x = acc[r][0]; v.y = acc[r][1]; v.z = acc[r][2]; v.w = acc[r][3];
        }
        *(float4*)p = v;
    }
}

__global__ __launch_bounds__(256) void gated_conv_kernel(
    const float* __restrict__ x, const float* __restrict__ Wd,
    const float* __restrict__ dbias, float* __restrict__ acts, int d)
{
    __shared__ float Wt0[KC][68], Wt1[KC][68], Ws0[KC][68], Ws1[KC][68];
    __shared__ float Sc[KC][68], Sp[KC][68];
    const int tid = threadIdx.x;
    const int t0 = blockIdx.x * 64;
    const int row0 = blockIdx.y * 64;
    const int b = blockIdx.z;
    const int i4 = (tid >> 4) * 4;
    const int j4 = (tid & 15) * 4;
    float a1[4][4], a2[4][4];
#pragma unroll
    for (int r = 0; r < 4; ++r) {
        float bt = dbias[row0 + i4 + r];
        float bs = dbias[128 + row0 + i4 + r];
#pragma unroll
        for (int c = 0; c < 4; ++c) { a1[r][c] = bt; a2[r][c] = bs; }
    }
    const float* xb = x + (size_t)b * 128 * 4096;
    for (int k0 = 0; k0 < 128; k0 += KC) {
        __syncthreads();
#pragma unroll
        for (int it = 0; it < 8; ++it) {
            int idx = it * 256 + tid;
            int kk = idx & 31, oo = idx >> 5;
            float2 wt = *(const float2*)(Wd + ((size_t)(row0 + oo) * 128 + (k0 + kk)) * 2);
            float2 ws = *(const float2*)(Wd + ((size_t)(128 + row0 + oo) * 128 + (k0 + kk)) * 2);
            Wt0[kk][oo] = wt.x; Wt1[kk][oo] = wt.y;
            Ws0[kk][oo] = ws.x; Ws1[kk][oo] = ws.y;
        }
#pragma unroll
        for (int it = 0; it < 8; ++it) {
            int idx = it * 256 + tid;
            int t = idx & 63, kk = idx >> 6;
            Sc[kk][t] = xb[(size_t)(k0 + kk) * 4096 + t0 + t];
            int gt = t0 + t - d;
            Sp[kk][t] = (gt >= 0) ? xb[(size_t)(k0 + kk) * 4096 + gt] : 0.0f;
        }
        __syncthreads();
#pragma unroll
        for (int kk = 0; kk < KC; ++kk) {
            float4 xcv4 = *(const float4*)&Sc[kk][j4];
            float4 xpv4 = *(const float4*)&Sp[kk][j4];
            float4 wt0 = *(const float4*)&Wt0[kk][i4];
            float4 wt1 = *(const float4*)&Wt1[kk][i4];
            float4 ws0 = *(const float4*)&Ws0[kk][i4];
            float4 ws1 = *(const float4*)&Ws1[kk][i4];
            float xc[4] = {xcv4.x, xcv4.y, xcv4.z, xcv4.w};
            float xp[4] = {xpv4.x, xpv4.y, xpv4.z, xpv4.w};
            float t0r[4] = {wt0.x, wt0.y, wt0.z, wt0.w};
            float t1r[4] = {wt1.x, wt1.y, wt1.z, wt1.w};
            float s0r[4] = {ws0.x, ws0.y, ws0.z, ws0.w};
            float s1r[4] = {ws1.x, ws1.y, ws1.z, ws1.w};
#pragma unroll
            for (int r = 0; r < 4; ++r)
#pragma unroll
                for (int c = 0; c < 4; ++c) {
                    a1[r][c] = fmaf(t0r[r], xp[c], a1[r][c]);
                    a1[r][c] = fmaf(t1r[r], xc[c], a1[r][c]);
                    a2[r][c] = fmaf(s0r[r], xp[c], a2[r][c]);
                    a2[r][c] = fmaf(s1r[r], xc[c], a2[r][c]);
                }
        }
    }
    float* ab = acts + (size_t)b * 128 * 4096;
#pragma unroll
    for (int r = 0; r < 4; ++r) {
        float4 v;
#pragma unroll
        for (int c = 0; c < 4; ++c) {
            float th = tanhf(a1[r][c]);
            float sg = 1.0f / (1.0f + expf(-a2[r][c]));
            ((float*)&v)[c] = th * sg;
        }
        *(float4*)&ab[(size_t)(row0 + i4 + r) * 4096 + t0 + j4] = v;
    }
}

__global__ __launch_bounds__(256) void actsum_kernel(
    const float* __restrict__ acts, float* __restrict__ out)
{
    const int br = blockIdx.x;
    const float* p = acts + (size_t)br * 4096;
    float s = 0.0f;
#pragma unroll
    for (int c = 0; c < 16; ++c) s += p[c * 256 + threadIdx.x];
    __shared__ float red[256];
    red[threadIdx.x] = s;
    __syncthreads();
    for (int off = 128; off > 0; off >>= 1) {
        if (threadIdx.x < off) red[threadIdx.x] += red[threadIdx.x + off];
        __syncthreads();
    }
    if (threadIdx.x == 0) out[br] = red[0];
}

__global__ __launch_bounds__(256) void final_kernel(
    const float* __restrict__ actsum, const float* __restrict__ skip_w,
    const float* __restrict__ skip_b, const float* __restrict__ w_out,
    const float* __restrict__ lin_w, const float* __restrict__ lin_b,
    float* __restrict__ out)
{
    const int b = blockIdx.x;
    const int s = threadIdx.x;
    float acc = 0.0f;
    for (int i = 0; i < 16; ++i) {
        const float* sw = skip_w + ((size_t)i * 256 + s) * 128;
        const float* as = actsum + ((size_t)i * 16 + b) * 128;
        float t = 0.0f;
#pragma unroll 8
        for (int r = 0; r < 128; ++r) t = fmaf(sw[r], as[r], t);
        acc += t;
    }
    float sb = 0.0f;
    for (int i = 0; i < 16; ++i) sb += skip_b[i * 256 + s];
    __shared__ float pl[256];
    pl[s] = acc * (1.0f / 4096.0f) + sb;
    __syncthreads();
    __shared__ float o1[12];
    if (s < 12) {
        float v = 0.0f;
        for (int qq = 0; qq < 256; ++qq) v = fmaf(w_out[s * 256 + qq], pl[qq], v);
        o1[s] = v;
    }
    __syncthreads();
    if (s < 12) {
        float v = lin_b[s];
#pragma unroll
        for (int m = 0; m < 12; ++m) v = fmaf(lin_w[s * 12 + m], o1[m], v);
        out[b * 12 + s] = v;
    }
}

// =======================================================================
extern "C" void kernel_launch(void* const* d_in, const int* in_sizes, int n_in,
                              void* d_out, int out_size, void* d_ws, size_t ws_size,
                              hipStream_t stream)
{
    const float* input    = (const float*)d_in[0];
    const float* w_in     = (const float*)d_in[1];
    const float* b_in     = (const float*)d_in[2];
    const float* dilate_w = (const float*)d_in[3];
    const float* dilate_b = (const float*)d_in[4];
    const float* res_w    = (const float*)d_in[5];
    const float* res_b    = (const float*)d_in[6];
    const float* skip_w   = (const float*)d_in[7];
    const float* skip_b   = (const float*)d_in[8];
    const float* w_out    = (const float*)d_in[9];
    const float* lin_w    = (const float*)d_in[10];
    const float* lin_b    = (const float*)d_in[11];
    float* out = (float*)d_out;

    const size_t NEED = 77103104ULL;
    if (ws_size >= NEED) {
        char* base = (char*)d_ws;
        bf16_t* xtA_hi = (bf16_t*)(base);                 // 16,777,216 B
        bf16_t* xtA_lo = (bf16_t*)(base + 16777216);      // 16,777,216 B
        bf16_t* xtB_hi = (bf16_t*)(base + 33554432);      // 16,777,216 B
        bf16_t* xtB_lo = (bf16_t*)(base + 50331648);      // 16,777,216 B
        bf16_t* wg     = (bf16_t*)(base + 67108864);      //  4,194,304 B (16 layers x 256KB)
        bf16_t* wr     = (bf16_t*)(base + 71303168);      //  1,474,560 B
        float*  asum   = (float*)(base + 72777728);       //    131,072 B
        bf16_t* zeros  = (bf16_t*)(base + 72908800);      //     65,536 B

        hipMemsetAsync(asum, 0, 131072, stream);
        zero_misc_kernel<<<dim3(128), dim3(256), 0, stream>>>(zeros);
        prep_wg_kernel<<<dim3(8192), dim3(256), 0, stream>>>(dilate_w, wg);
        prep_wr_kernel<<<dim3(2880), dim3(256), 0, stream>>>(res_w, wr);
        prep_wi_kernel<<<dim3(384), dim3(256), 0, stream>>>(w_in);

        // input conv in two 8-batch passes; xtB buffers as transpose scratch
        for (int pass = 0; pass < 2; ++pass) {
            transpose_in<<<dim3(64, 4, 8), dim3(256), 0, stream>>>(
                input, xtB_hi, xtB_lo, pass * 8);
            pw_mfma_in<<<dim3(32, 1, 8), dim3(256), 0, stream>>>(
                xtB_hi, xtB_lo, b_in, xtA_hi, xtA_lo, pass * 8);
        }

        for (int i = 0; i < 16; ++i) {
            int d = 1 << (i % 9);
            const bf16_t* xc_hi = (i & 1) ? xtB_hi : xtA_hi;
            const bf16_t* xc_lo = (i & 1) ? xtB_lo : xtA_lo;
            bf16_t* xn_hi = (i & 1) ? xtA_hi : xtB_hi;
            bf16_t* xn_lo = (i & 1) ? xtA_lo : xtB_lo;
            int skipres = (i == 15) ? 1 : 0;
            fused_layer<<<dim3(32, 1, 16), dim3(512), 0, stream>>>(
                xc_hi, xc_lo, xn_hi, xn_lo, zeros,
                wg + (size_t)i * 131072, dilate_b + i * 256,
                wr + (size_t)(skipres ? 0 : i) * 49152,
                res_b + (skipres ? 0 : i) * 128,
                asum + i * 2048, d, skipres);
        }
        skip_partial<<<dim3(256), dim3(256), 0, stream>>>(asum, skip_w);
        head_kernel<<<dim3(16), dim3(256), 0, stream>>>(
            skip_b, w_out, lin_w, lin_b, out);
    } else {
        // fallback: fp32 VALU path (round 1)
        float* ws   = (float*)d_ws;
        float* x    = ws;
        float* acts = ws + 8388608;
        float* asum = ws + 16777216;
        dim3 grid(64, 2, 16), blk(256, 1, 1);
        pw_conv_kernel<<<grid, blk, 0, stream>>>(input, w_in, b_in, x, 256, 0);
        for (int i = 0; i < 16; ++i) {
            int d = 1 << (i % 9);
            gated_conv_kernel<<<grid, blk, 0, stream>>>(
                x, dilate_w + (size_t)i * 256 * 128 * 2, dilate_b + i * 256, acts, d);
            actsum_kernel<<<dim3(2048), blk, 0, stream>>>(acts, asum + i * 2048);
            if (i < 15) {
                pw_conv_kernel<<<grid, blk, 0, stream>>>(
                    acts, res_w + (size_t)i * 128 * 128, res_b + i * 128, x, 128, 1);
            }
        }
        final_kernel<<<dim3(16), blk, 0, stream>>>(
            asum, skip_w, skip_b, w_out, lin_w, lin_b, out);
    }
}

// Round 9
// 1227.177 us; speedup vs baseline: 1.0756x; 1.0756x over previous
//
#include <hip/hip_runtime.h>
#include <hip/hip_bf16.h>

// WaveNet forward on gfx950 — round 9.
// 2-product split: W quantized to bf16 (Whi only), X kept as hi/lo pair.
//   W·X ≈ Whi·Xhi + Whi·Xlo  (error = Wlo·X ~ 2^-9 relative, systematic)
// Per gated superchunk u (8 total): stage {Whi 16K, Xhi 8K, Xlo 8K} once,
// run 2 MFMA phases against the SAME resident W tile. Double-buffered,
// counted vmcnt, 2 barriers/superchunk. Res conv and input conv same scheme.
// Fused layer: gated conv + in-LDS acts + residual conv, one dispatch/layer.
// Fallback (ws too small): round-1 fp32 VALU path.

#define KC 32

typedef __bf16 bf16_t;
typedef __bf16 bf16x4 __attribute__((ext_vector_type(4)));
typedef __bf16 bf16x8 __attribute__((ext_vector_type(8)));
typedef float f32x16 __attribute__((ext_vector_type(16)));

__device__ __align__(16) __bf16 g_wi_dev[32768];   // w_in bf16, swizzled
__device__ float g_pooled[4096];                    // [b][256] pooled skip

__device__ __forceinline__ void gl_lds16(const void* g, void* l) {
    __builtin_amdgcn_global_load_lds(
        (const __attribute__((address_space(1))) unsigned int*)g,
        (__attribute__((address_space(3))) unsigned int*)l, 16, 0, 0);
}

__device__ __forceinline__ float fast_sigmoid(float x) {
    float e = __builtin_amdgcn_exp2f(-1.4426950408889634f * x);
    return __builtin_amdgcn_rcpf(1.0f + e);
}
__device__ __forceinline__ float fast_tanh(float x) {
    float e = __builtin_amdgcn_exp2f(-2.8853900817779268f * x);
    return fmaf(2.0f, __builtin_amdgcn_rcpf(1.0f + e), -1.0f);
}

// ---------------- weight prep: bf16 quantize + swizzle ----------------
// gated: 8 chunks/layer of 16KB: [row<256][ps<4][e<8], s = ps^((row>>1)&3),
// k = c*32+s*8+e (k<256), tap=k>>7, ch=k&127.
__global__ __launch_bounds__(256) void prep_wg_kernel(
    const float* __restrict__ dw, bf16_t* __restrict__ wg)
{
    int idx = blockIdx.x * 256 + threadIdx.x;   // 1,048,576
    int e = idx & 7, ps = (idx >> 3) & 3, row = (idx >> 5) & 255;
    int c = (idx >> 13) & 7, layer = idx >> 16;
    int s = ps ^ ((row >> 1) & 3);
    int k = c * 32 + s * 8 + e;
    int tap = k >> 7, ch = k & 127;
    wg[idx] = (bf16_t)dw[(((size_t)layer * 256 + row) * 128 + ch) * 2 + tap];
}

// res: 4 chunks/layer of 8KB: [row<128][ps<4][e<8], k = c*32+s*8+e = ch.
__global__ __launch_bounds__(256) void prep_wr_kernel(
    const float* __restrict__ rw, bf16_t* __restrict__ wr)
{
    int idx = blockIdx.x * 256 + threadIdx.x;   // 245,760 (15 layers)
    int e = idx & 7, ps = (idx >> 3) & 3, row = (idx >> 5) & 127;
    int c = (idx >> 12) & 3, layer = idx >> 14;
    int s = ps ^ ((row >> 1) & 3);
    int ch = c * 32 + s * 8 + e;
    wr[idx] = (bf16_t)rw[((size_t)layer * 128 + row) * 128 + ch];
}

// input conv: 8 chunks of 8KB: k = c*32+s*8+e = ch (0..255).
__global__ __launch_bounds__(256) void prep_wi_kernel(const float* __restrict__ wi)
{
    int idx = blockIdx.x * 256 + threadIdx.x;   // 32,768
    int e = idx & 7, ps = (idx >> 3) & 3, row = (idx >> 5) & 127;
    int c = idx >> 12;
    int s = ps ^ ((row >> 1) & 3);
    int ch = c * 32 + s * 8 + e;
    g_wi_dev[idx] = (bf16_t)wi[(size_t)row * 256 + ch];
}

__global__ __launch_bounds__(256) void zero_misc_kernel(bf16_t* __restrict__ zeros)
{
    int idx = blockIdx.x * 256 + threadIdx.x;   // 32768
    zeros[idx] = (bf16_t)0.0f;
    if (idx < 4096) g_pooled[idx] = 0.0f;
}

// ---------------- input transpose: fp32 [ch][t] -> bf16 hi/lo [t][ch] ----------------
__global__ __launch_bounds__(256) void transpose_in(
    const float* __restrict__ input, bf16_t* __restrict__ th,
    bf16_t* __restrict__ tl, int b_off)
{
    __shared__ float Sl[64][65];
    const int tid = threadIdx.x;
    const int t0 = blockIdx.x * 64, ch0 = blockIdx.y * 64, bz = blockIdx.z;
    const int b = b_off + bz;
#pragma unroll
    for (int it = 0; it < 16; ++it) {
        int idx = it * 256 + tid;
        int t = idx & 63, ch = idx >> 6;
        Sl[ch][t] = input[((size_t)b * 256 + ch0 + ch) * 4096 + t0 + t];
    }
    __syncthreads();
#pragma unroll
    for (int it = 0; it < 16; ++it) {
        int idx = it * 256 + tid;
        int ch = idx & 63, t = idx >> 6;
        float v = Sl[ch][t];
        bf16_t hb = (bf16_t)v;
        size_t o = ((size_t)bz * 4096 + t0 + t) * 256 + ch0 + ch;
        th[o] = hb;
        tl[o] = (bf16_t)(v - (float)hb);
    }
}

// ---------------- fused layer: gated conv + acts + residual conv ----------------
// 512 threads (8 waves). LDS 80KB:
//   gated loop : Whi dbuf 2x16K [0,32K), Xhi dbuf 2x8K [32K,48K),
//                Xlo dbuf 2x8K [48K,64K)
//   epilogue   : acts hi [0,32K), acts lo [32K,64K), resW dbuf 2x8K [64K,80K)
__global__ __launch_bounds__(512, 4) void fused_layer(
    const bf16_t* __restrict__ xc_hi, const bf16_t* __restrict__ xc_lo,
    bf16_t* __restrict__ xn_hi, bf16_t* __restrict__ xn_lo,
    const bf16_t* __restrict__ zeros,
    const bf16_t* __restrict__ wg_l, const float* __restrict__ dbias,
    const bf16_t* __restrict__ wr_l, const float* __restrict__ rbias,
    float* __restrict__ asum_l, int d, int skipres)
{
    __shared__ __align__(16) char lds[81920];
    const int tid = threadIdx.x;
    const int wave = tid >> 6, lane = tid & 63;
    const int l31 = lane & 31, h = lane >> 5;
    const int wm = wave & 3, wn = wave >> 2;
    const int t0 = blockIdx.x * 128;
    const int b = blockIdx.z;

    f32x16 acc[2][2];
#pragma unroll
    for (int m = 0; m < 2; ++m)
#pragma unroll
        for (int n = 0; n < 2; ++n) acc[m][n] = (f32x16)(0.0f);

    const int t_pos = tid >> 2;
    const int s_x = (tid & 3) ^ ((t_pos >> 1) & 3);
    const int chx = s_x << 3;

    // 4 loads/thread per superchunk: 2x Whi, 1x Xhi, 1x Xlo
    auto stage_g = [&](int u, int sl) {
        const char* wsrc = (const char*)wg_l + (size_t)u * 16384;
        char* wdst = lds + sl * 16384;
        gl_lds16(wsrc + tid * 16, wdst + tid * 16);
        gl_lds16(wsrc + (tid + 512) * 16, wdst + (tid + 512) * 16);
        int tap = (u >> 2) & 1;
        int ch = ((u & 3) << 5) + chx;
        int tg = t0 + t_pos - (tap ? 0 : d);
        size_t gi = ((size_t)b * 4096 + tg) * 128 + ch;
        const bf16_t* sph = (tg >= 0) ? (xc_hi + gi) : (zeros + ch);
        const bf16_t* spl = (tg >= 0) ? (xc_lo + gi) : (zeros + ch);
        gl_lds16(sph, lds + 32768 + sl * 8192 + tid * 16);
        gl_lds16(spl, lds + 49152 + sl * 8192 + tid * 16);
    };

    stage_g(0, 0);
    const int swz = (l31 >> 1) & 3;
    int aoff[2][2], boff[2][2];
#pragma unroll
    for (int m = 0; m < 2; ++m)
#pragma unroll
        for (int s2 = 0; s2 < 2; ++s2)
            aoff[m][s2] = ((m ? 128 + wm * 32 : wm * 32) + l31) * 64 +
                          (((s2 * 2 + h) ^ swz) << 4);
#pragma unroll
    for (int n = 0; n < 2; ++n)
#pragma unroll
        for (int s2 = 0; s2 < 2; ++s2)
            boff[n][s2] = (wn * 64 + n * 32 + l31) * 64 + (((s2 * 2 + h) ^ swz) << 4);

    for (int u = 0; u < 8; ++u) {
        if (u < 7) {
            stage_g(u + 1, (u + 1) & 1);
            asm volatile("s_waitcnt vmcnt(4)" ::: "memory"); // chunk u's 4 landed
        } else {
            asm volatile("s_waitcnt vmcnt(0)" ::: "memory");
        }
        __builtin_amdgcn_s_barrier();

        const char* whb = lds + (u & 1) * 16384;
        const char* xhb = lds + 32768 + (u & 1) * 8192;
        const char* xlb = lds + 49152 + (u & 1) * 8192;

        // P0: Whi x Xhi
        {
            bf16x8 a0[2], a1[2], b0[2], b1[2];
#pragma unroll
            for (int s2 = 0; s2 < 2; ++s2) {
                a0[s2] = *(const bf16x8*)(whb + aoff[0][s2]);
                a1[s2] = *(const bf16x8*)(whb + aoff[1][s2]);
                b0[s2] = *(const bf16x8*)(xhb + boff[0][s2]);
                b1[s2] = *(const bf16x8*)(xhb + boff[1][s2]);
            }
            __builtin_amdgcn_s_setprio(1);
#pragma unroll
            for (int s2 = 0; s2 < 2; ++s2) {
                acc[0][0] = __builtin_amdgcn_mfma_f32_32x32x16_bf16(a0[s2], b0[s2], acc[0][0], 0, 0, 0);
                acc[0][1] = __builtin_amdgcn_mfma_f32_32x32x16_bf16(a0[s2], b1[s2], acc[0][1], 0, 0, 0);
                acc[1][0] = __builtin_amdgcn_mfma_f32_32x32x16_bf16(a1[s2], b0[s2], acc[1][0], 0, 0, 0);
                acc[1][1] = __builtin_amdgcn_mfma_f32_32x32x16_bf16(a1[s2], b1[s2], acc[1][1], 0, 0, 0);
            }
            __builtin_amdgcn_s_setprio(0);
        }
        // P1: Whi x Xlo (same W tile resident; no barrier needed between phases)
        {
            bf16x8 a0[2], a1[2], b0[2], b1[2];
#pragma unroll
            for (int s2 = 0; s2 < 2; ++s2) {
                a0[s2] = *(const bf16x8*)(whb + aoff[0][s2]);
                a1[s2] = *(const bf16x8*)(whb + aoff[1][s2]);
                b0[s2] = *(const bf16x8*)(xlb + boff[0][s2]);
                b1[s2] = *(const bf16x8*)(xlb + boff[1][s2]);
            }
            __builtin_amdgcn_s_setprio(1);
#pragma unroll
            for (int s2 = 0; s2 < 2; ++s2) {
                acc[0][0] = __builtin_amdgcn_mfma_f32_32x32x16_bf16(a0[s2], b0[s2], acc[0][0], 0, 0, 0);
                acc[0][1] = __builtin_amdgcn_mfma_f32_32x32x16_bf16(a0[s2], b1[s2], acc[0][1], 0, 0, 0);
                acc[1][0] = __builtin_amdgcn_mfma_f32_32x32x16_bf16(a1[s2], b0[s2], acc[1][0], 0, 0, 0);
                acc[1][1] = __builtin_amdgcn_mfma_f32_32x32x16_bf16(a1[s2], b1[s2], acc[1][1], 0, 0, 0);
            }
            __builtin_amdgcn_s_setprio(0);
        }
        __builtin_amdgcn_s_barrier();  // reads of slot u&1 retired -> restage safe
    }
    __syncthreads();

    // ---- acts epilogue ----
    auto stage_rw = [&](int c, int sl) {
        gl_lds16((const char*)wr_l + (size_t)c * 8192 + tid * 16,
                 lds + 65536 + sl * 8192 + tid * 16);
    };
    if (!skipres) stage_rw(0, 0);   // HBM latency hides under activation VALU

    float psum[16];
#pragma unroll
    for (int u = 0; u < 16; ++u) psum[u] = 0.0f;

#pragma unroll
    for (int n = 0; n < 2; ++n) {
        int t = wn * 64 + n * 32 + l31;
        int sw = (t & 7) << 4;
#pragma unroll
        for (int rg = 0; rg < 4; ++rg) {
            int ch0 = wm * 32 + rg * 8 + 4 * h;
            bf16x4 hv, lv;
#pragma unroll
            for (int j = 0; j < 4; ++j) {
                int r = rg * 4 + j;
                float a1v = acc[0][n][r] + dbias[ch0 + j];
                float a2v = acc[1][n][r] + dbias[128 + ch0 + j];
                float a = fast_tanh(a1v) * fast_sigmoid(a2v);
                psum[rg * 4 + j] += a;
                bf16_t hb = (bf16_t)a;
                hv[j] = hb;
                lv[j] = (bf16_t)(a - (float)hb);
            }
            int low = (ch0 * 2) ^ sw;
            *(bf16x4*)(lds + t * 256 + low) = hv;
            *(bf16x4*)(lds + 32768 + t * 256 + low) = lv;
        }
    }

#pragma unroll
    for (int u = 0; u < 16; ++u) {
        float v = psum[u];
        v += __shfl_xor(v, 1);
        v += __shfl_xor(v, 2);
        v += __shfl_xor(v, 4);
        v += __shfl_xor(v, 8);
        v += __shfl_xor(v, 16);
        psum[u] = v;
    }
    if (l31 == 0) {
#pragma unroll
        for (int u = 0; u < 16; ++u) {
            int ch = wm * 32 + (u >> 2) * 8 + 4 * h + (u & 3);
            atomicAdd(asum_l + b * 128 + ch, psum[u]);
        }
    }
    if (skipres) return;

    asm volatile("s_waitcnt lgkmcnt(0)" ::: "memory");
    __builtin_amdgcn_s_barrier();   // acts visible to all waves; resW c0 in flight

    // ---- residual K-loop: M=128 x N=128, 4 superchunks x 2 phases ----
    f32x16 accr[2];
    accr[0] = (f32x16)(0.0f);
    accr[1] = (f32x16)(0.0f);
    int tl_[2], mk_[2];
#pragma unroll
    for (int n = 0; n < 2; ++n) {
        tl_[n] = wn * 64 + n * 32 + l31;
        mk_[n] = (tl_[n] & 7) << 4;
    }

    for (int u = 0; u < 4; ++u) {
        if (u < 3) {
            stage_rw(u + 1, (u + 1) & 1);
            asm volatile("s_waitcnt vmcnt(1)" ::: "memory");
        } else {
            asm volatile("s_waitcnt vmcnt(0)" ::: "memory");
        }
        __builtin_amdgcn_s_barrier();

        const char* ab = lds + 65536 + (u & 1) * 8192;
        int cb = u << 6;
#pragma unroll
        for (int ph = 0; ph < 2; ++ph) {
            const char* bb = lds + (ph ? 32768 : 0);
            bf16x8 av[2], bv[2][2];
#pragma unroll
            for (int s2 = 0; s2 < 2; ++s2) {
                av[s2] = *(const bf16x8*)(ab + (wm * 32 + l31) * 64 +
                                          (((s2 * 2 + h) ^ swz) << 4));
#pragma unroll
                for (int n = 0; n < 2; ++n) {
                    int low = (cb + ((s2 * 2 + h) << 4)) ^ mk_[n];
                    bv[n][s2] = *(const bf16x8*)(bb + tl_[n] * 256 + low);
                }
            }
            __builtin_amdgcn_s_setprio(1);
#pragma unroll
            for (int s2 = 0; s2 < 2; ++s2) {
                accr[0] = __builtin_amdgcn_mfma_f32_32x32x16_bf16(av[s2], bv[0][s2], accr[0], 0, 0, 0);
                accr[1] = __builtin_amdgcn_mfma_f32_32x32x16_bf16(av[s2], bv[1][s2], accr[1], 0, 0, 0);
            }
            __builtin_amdgcn_s_setprio(0);
        }
        __builtin_amdgcn_s_barrier();
    }

    // ---- residual epilogue: x_new = accr + rbias + x_old(hi+lo) ----
#pragma unroll
    for (int n = 0; n < 2; ++n) {
        int t = tl_[n];
        size_t trow = ((size_t)b * 4096 + t0 + t) * 128;
#pragma unroll
        for (int rg = 0; rg < 4; ++rg) {
            int ch0 = wm * 32 + rg * 8 + 4 * h;
            bf16x4 oh = *(const bf16x4*)(xc_hi + trow + ch0);
            bf16x4 ol = *(const bf16x4*)(xc_lo + trow + ch0);
            bf16x4 nh, nl;
#pragma unroll
            for (int j = 0; j < 4; ++j) {
                float v = accr[n][rg * 4 + j] + rbias[ch0 + j] +
                          (float)oh[j] + (float)ol[j];
                bf16_t hb = (bf16_t)v;
                nh[j] = hb;
                nl[j] = (bf16_t)(v - (float)hb);
            }
            *(bf16x4*)(xn_hi + trow + ch0) = nh;
            *(bf16x4*)(xn_lo + trow + ch0) = nl;
        }
    }
}

// ---------------- input pointwise MFMA (K=256 ch, 2 phases) ----------------
// BM=128, BN=128, 4 waves. LDS 48KB: W dbuf 2x8K @0, Xhi 2x8K @16K, Xlo 2x8K @32K.
__global__ __launch_bounds__(256) void pw_mfma_in(
    const bf16_t* __restrict__ sh, const bf16_t* __restrict__ sl,
    const float* __restrict__ bias,
    bf16_t* __restrict__ xth, bf16_t* __restrict__ xtl, int b_off)
{
    __shared__ __align__(16) char lds[49152];
    const int tid = threadIdx.x;
    const int wave = tid >> 6, lane = tid & 63;
    const int l31 = lane & 31, h = lane >> 5;
    const int wm = wave & 1, wn = wave >> 1;
    const int t0 = blockIdx.x * 128;
    const int bz = blockIdx.z;
    const bf16_t* w = (const bf16_t*)g_wi_dev;

    f32x16 acc[2][2];
#pragma unroll
    for (int m = 0; m < 2; ++m)
#pragma unroll
        for (int n = 0; n < 2; ++n) acc[m][n] = (f32x16)(0.0f);

    auto stage = [&](int u, int sl_) {
        const char* wsrc = (const char*)w + (size_t)u * 8192;
        char* wdst = lds + sl_ * 8192;
        gl_lds16(wsrc + tid * 16, wdst + tid * 16);
        gl_lds16(wsrc + (tid + 256) * 16, wdst + (tid + 256) * 16);
#pragma unroll
        for (int it = 0; it < 2; ++it) {
            int row = (tid >> 2) + it * 64;
            int ps = tid & 3;
            int sx = ps ^ ((row >> 1) & 3);
            size_t gi = ((size_t)bz * 4096 + t0 + row) * 256 + u * 32 + sx * 8;
            gl_lds16(sh + gi, lds + 16384 + sl_ * 8192 + (row * 4 + ps) * 16);
            gl_lds16(sl + gi, lds + 32768 + sl_ * 8192 + (row * 4 + ps) * 16);
        }
    };

    stage(0, 0);
    const int swz = (l31 >> 1) & 3;
    int aoff[2][2], boff[2][2];
#pragma unroll
    for (int m = 0; m < 2; ++m)
#pragma unroll
        for (int s2 = 0; s2 < 2; ++s2)
            aoff[m][s2] = (wm * 64 + m * 32 + l31) * 64 + (((s2 * 2 + h) ^ swz) << 4);
#pragma unroll
    for (int n = 0; n < 2; ++n)
#pragma unroll
        for (int s2 = 0; s2 < 2; ++s2)
            boff[n][s2] = (wn * 64 + n * 32 + l31) * 64 + (((s2 * 2 + h) ^ swz) << 4);

    for (int u = 0; u < 8; ++u) {
        if (u < 7) {
            stage(u + 1, (u + 1) & 1);
            asm volatile("s_waitcnt vmcnt(6)" ::: "memory");
        } else {
            asm volatile("s_waitcnt vmcnt(0)" ::: "memory");
        }
        __builtin_amdgcn_s_barrier();

        const char* wb = lds + (u & 1) * 8192;
#pragma unroll
        for (int ph = 0; ph < 2; ++ph) {
            const char* xb = lds + (ph ? 32768 : 16384) + (u & 1) * 8192;
            bf16x8 a0[2], a1[2], b0[2], b1[2];
#pragma unroll
            for (int s2 = 0; s2 < 2; ++s2) {
                a0[s2] = *(const bf16x8*)(wb + aoff[0][s2]);
                a1[s2] = *(const bf16x8*)(wb + aoff[1][s2]);
                b0[s2] = *(const bf16x8*)(xb + boff[0][s2]);
                b1[s2] = *(const bf16x8*)(xb + boff[1][s2]);
            }
#pragma unroll
            for (int s2 = 0; s2 < 2; ++s2) {
                acc[0][0] = __builtin_amdgcn_mfma_f32_32x32x16_bf16(a0[s2], b0[s2], acc[0][0], 0, 0, 0);
                acc[0][1] = __builtin_amdgcn_mfma_f32_32x32x16_bf16(a0[s2], b1[s2], acc[0][1], 0, 0, 0);
                acc[1][0] = __builtin_amdgcn_mfma_f32_32x32x16_bf16(a1[s2], b0[s2], acc[1][0], 0, 0, 0);
                acc[1][1] = __builtin_amdgcn_mfma_f32_32x32x16_bf16(a1[s2], b1[s2], acc[1][1], 0, 0, 0);
            }
        }
        __builtin_amdgcn_s_barrier();
    }

    const int b = b_off + bz;
#pragma unroll
    for (int n = 0; n < 2; ++n) {
        int t = wn * 64 + n * 32 + l31;
        size_t trow = ((size_t)b * 4096 + t0 + t) * 128;
#pragma unroll
        for (int m = 0; m < 2; ++m) {
#pragma unroll
            for (int rg = 0; rg < 4; ++rg) {
                int ch0 = wm * 64 + m * 32 + rg * 8 + 4 * h;
                bf16x4 nh, nl;
#pragma unroll
                for (int j = 0; j < 4; ++j) {
                    float v = acc[m][n][rg * 4 + j] + bias[ch0 + j];
                    bf16_t hb = (bf16_t)v;
                    nh[j] = hb;
                    nl[j] = (bf16_t)(v - (float)hb);
                }
                *(bf16x4*)(xth + trow + ch0) = nh;
                *(bf16x4*)(xtl + trow + ch0) = nl;
            }
        }
    }
}

// ---------------- output head ----------------
__global__ __launch_bounds__(256) void skip_partial(
    const float* __restrict__ asum, const float* __restrict__ skip_w)
{
    const int i = blockIdx.x >> 4, b = blockIdx.x & 15, s = threadIdx.x;
    const float* sw = skip_w + ((size_t)i * 256 + s) * 128;
    const float* as = asum + i * 2048 + b * 128;
    float t = 0.0f;
#pragma unroll 8
    for (int r = 0; r < 128; ++r) t = fmaf(sw[r], as[r], t);
    atomicAdd(&g_pooled[b * 256 + s], t);
}

__global__ __launch_bounds__(256) void head_kernel(
    const float* __restrict__ skip_b, const float* __restrict__ w_out,
    const float* __restrict__ lin_w, const float* __restrict__ lin_b,
    float* __restrict__ out)
{
    const int b = blockIdx.x;
    const int s = threadIdx.x;
    float sb = 0.0f;
#pragma unroll
    for (int i = 0; i < 16; ++i) sb += skip_b[i * 256 + s];
    __shared__ float pl[256];
    pl[s] = g_pooled[b * 256 + s] * (1.0f / 4096.0f) + sb;
    __syncthreads();
    __shared__ float o1[12];
    if (s < 12) {
        float v = 0.0f;
        for (int q = 0; q < 256; ++q) v = fmaf(w_out[s * 256 + q], pl[q], v);
        o1[s] = v;
    }
    __syncthreads();
    if (s < 12) {
        float v = lin_b[s];
#pragma unroll
        for (int m = 0; m < 12; ++m) v = fmaf(lin_w[s * 12 + m], o1[m], v);
        out[b * 12 + s] = v;
    }
}

// ================= fallback fp32 path (round-1, proven) =================
__global__ __launch_bounds__(256) void pw_conv_kernel(
    const float* __restrict__ src, const float* __restrict__ W,
    const float* __restrict__ bias, float* __restrict__ dst,
    int K, int accumulate)
{
    __shared__ float Wl[KC][68];
    __shared__ float Sl[KC][68];
    const int tid = threadIdx.x;
    const int t0 = blockIdx.x * 64;
    const int row0 = blockIdx.y * 64;
    const int b = blockIdx.z;
    const int i4 = (tid >> 4) * 4;
    const int j4 = (tid & 15) * 4;
    float acc[4][4];
#pragma unroll
    for (int r = 0; r < 4; ++r) {
        float bv = bias[row0 + i4 + r];
#pragma unroll
        for (int c = 0; c < 4; ++c) acc[r][c] = bv;
    }
    const float* sb = src + (size_t)b * K * 4096;
    for (int k0 = 0; k0 < K; k0 += KC) {
        __syncthreads();
#pragma unroll
        for (int it = 0; it < 8; ++it) {
            int idx = it * 256 + tid;
            int kk = idx & 31, oo = idx >> 5;
            Wl[kk][oo] = W[(size_t)(row0 + oo) * K + (k0 + kk)];
        }
#pragma unroll
        for (int it = 0; it < 8; ++it) {
            int idx = it * 256 + tid;
            int t = idx & 63, kk = idx >> 6;
            Sl[kk][t] = sb[(size_t)(k0 + kk) * 4096 + t0 + t];
        }
        __syncthreads();
#pragma unroll
        for (int kk = 0; kk < KC; ++kk) {
            float4 wv = *(const float4*)&Wl[kk][i4];
            float4 sv = *(const float4*)&Sl[kk][j4];
            float wr_[4] = {wv.x, wv.y, wv.z, wv.w};
            float sc[4] = {sv.x, sv.y, sv.z, sv.w};
#pragma unroll
            for (int r = 0; r < 4; ++r)
#pragma unroll
                for (int c = 0; c < 4; ++c)
                    acc[r][c] = fmaf(wr_[r], sc[c], acc[r][c]);
        }
    }
    float* db = dst + (size_t)b * 128 * 4096;
#pragma unroll
    for (int r = 0; r < 4; ++r) {
        float* p = db + (size_t)(row0 + i4 + r) * 4096 + t0 + j4;
        float4 v;
        if (accumulate) {
            float4 old = *(const float4*)p;
            v.x = acc[r][0] + old.x; v.y = acc[r][1] + old.y;
            v.z = acc[r][2] + old.z; v.w = acc[r][3] + old.w;
        } else {
            v.x = acc[r][0]; v.y = acc[r][1]; v.z = acc[r][2]; v.w = acc[r][3];
        }
        *(float4*)p = v;
    }
}

__global__ __launch_bounds__(256) void gated_conv_kernel(
    const float* __restrict__ x, const float* __restrict__ Wd,
    const float* __restrict__ dbias, float* __restrict__ acts, int d)
{
    __shared__ float Wt0[KC][68], Wt1[KC][68], Ws0[KC][68], Ws1[KC][68];
    __shared__ float Sc[KC][68], Sp[KC][68];
    const int tid = threadIdx.x;
    const int t0 = blockIdx.x * 64;
    const int row0 = blockIdx.y * 64;
    const int b = blockIdx.z;
    const int i4 = (tid >> 4) * 4;
    const int j4 = (tid & 15) * 4;
    float a1[4][4], a2[4][4];
#pragma unroll
    for (int r = 0; r < 4; ++r) {
        float bt = dbias[row0 + i4 + r];
        float bs = dbias[128 + row0 + i4 + r];
#pragma unroll
        for (int c = 0; c < 4; ++c) { a1[r][c] = bt; a2[r][c] = bs; }
    }
    const float* xb = x + (size_t)b * 128 * 4096;
    for (int k0 = 0; k0 < 128; k0 += KC) {
        __syncthreads();
#pragma unroll
        for (int it = 0; it < 8; ++it) {
            int idx = it * 256 + tid;
            int kk = idx & 31, oo = idx >> 5;
            float2 wt = *(const float2*)(Wd + ((size_t)(row0 + oo) * 128 + (k0 + kk)) * 2);
            float2 ws = *(const float2*)(Wd + ((size_t)(128 + row0 + oo) * 128 + (k0 + kk)) * 2);
            Wt0[kk][oo] = wt.x; Wt1[kk][oo] = wt.y;
            Ws0[kk][oo] = ws.x; Ws1[kk][oo] = ws.y;
        }
#pragma unroll
        for (int it = 0; it < 8; ++it) {
            int idx = it * 256 + tid;
            int t = idx & 63, kk = idx >> 6;
            Sc[kk][t] = xb[(size_t)(k0 + kk) * 4096 + t0 + t];
            int gt = t0 + t - d;
            Sp[kk][t] = (gt >= 0) ? xb[(size_t)(k0 + kk) * 4096 + gt] : 0.0f;
        }
        __syncthreads();
#pragma unroll
        for (int kk = 0; kk < KC; ++kk) {
            float4 xcv4 = *(const float4*)&Sc[kk][j4];
            float4 xpv4 = *(const float4*)&Sp[kk][j4];
            float4 wt0 = *(const float4*)&Wt0[kk][i4];
            float4 wt1 = *(const float4*)&Wt1[kk][i4];
            float4 ws0 = *(const float4*)&Ws0[kk][i4];
            float4 ws1 = *(const float4*)&Ws1[kk][i4];
            float xc[4] = {xcv4.x, xcv4.y, xcv4.z, xcv4.w};
            float xp[4] = {xpv4.x, xpv4.y, xpv4.z, xpv4.w};
            float t0r[4] = {wt0.x, wt0.y, wt0.z, wt0.w};
            float t1r[4] = {wt1.x, wt1.y, wt1.z, wt1.w};
            float s0r[4] = {ws0.x, ws0.y, ws0.z, ws0.w};
            float s1r[4] = {ws1.x, ws1.y, ws1.z, ws1.w};
#pragma unroll
            for (int r = 0; r < 4; ++r)
#pragma unroll
                for (int c = 0; c < 4; ++c) {
                    a1[r][c] = fmaf(t0r[r], xp[c], a1[r][c]);
                    a1[r][c] = fmaf(t1r[r], xc[c], a1[r][c]);
                    a2[r][c] = fmaf(s0r[r], xp[c], a2[r][c]);
                    a2[r][c] = fmaf(s1r[r], xc[c], a2[r][c]);
                }
        }
    }
    float* ab = acts + (size_t)b * 128 * 4096;
#pragma unroll
    for (int r = 0; r < 4; ++r) {
        float4 v;
#pragma unroll
        for (int c = 0; c < 4; ++c) {
            float th = tanhf(a1[r][c]);
            float sg = 1.0f / (1.0f + expf(-a2[r][c]));
            ((float*)&v)[c] = th * sg;
        }
        *(float4*)&ab[(size_t)(row0 + i4 + r) * 4096 + t0 + j4] = v;
    }
}

__global__ __launch_bounds__(256) void actsum_kernel(
    const float* __restrict__ acts, float* __restrict__ out)
{
    const int br = blockIdx.x;
    const float* p = acts + (size_t)br * 4096;
    float s = 0.0f;
#pragma unroll
    for (int c = 0; c < 16; ++c) s += p[c * 256 + threadIdx.x];
    __shared__ float red[256];
    red[threadIdx.x] = s;
    __syncthreads();
    for (int off = 128; off > 0; off >>= 1) {
        if (threadIdx.x < off) red[threadIdx.x] += red[threadIdx.x + off];
        __syncthreads();
    }
    if (threadIdx.x == 0) out[br] = red[0];
}

__global__ __launch_bounds__(256) void final_kernel(
    const float* __restrict__ actsum, const float* __restrict__ skip_w,
    const float* __restrict__ skip_b, const float* __restrict__ w_out,
    const float* __restrict__ lin_w, const float* __restrict__ lin_b,
    float* __restrict__ out)
{
    const int b = blockIdx.x;
    const int s = threadIdx.x;
    float acc = 0.0f;
    for (int i = 0; i < 16; ++i) {
        const float* sw = skip_w + ((size_t)i * 256 + s) * 128;
        const float* as = actsum + ((size_t)i * 16 + b) * 128;
        float t = 0.0f;
#pragma unroll 8
        for (int r = 0; r < 128; ++r) t = fmaf(sw[r], as[r], t);
        acc += t;
    }
    float sb = 0.0f;
    for (int i = 0; i < 16; ++i) sb += skip_b[i * 256 + s];
    __shared__ float pl[256];
    pl[s] = acc * (1.0f / 4096.0f) + sb;
    __syncthreads();
    __shared__ float o1[12];
    if (s < 12) {
        float v = 0.0f;
        for (int qq = 0; qq < 256; ++qq) v = fmaf(w_out[s * 256 + qq], pl[qq], v);
        o1[s] = v;
    }
    __syncthreads();
    if (s < 12) {
        float v = lin_b[s];
#pragma unroll
        for (int m = 0; m < 12; ++m) v = fmaf(lin_w[s * 12 + m], o1[m], v);
        out[b * 12 + s] = v;
    }
}

// =======================================================================
extern "C" void kernel_launch(void* const* d_in, const int* in_sizes, int n_in,
                              void* d_out, int out_size, void* d_ws, size_t ws_size,
                              hipStream_t stream)
{
    const float* input    = (const float*)d_in[0];
    const float* w_in     = (const float*)d_in[1];
    const float* b_in     = (const float*)d_in[2];
    const float* dilate_w = (const float*)d_in[3];
    const float* dilate_b = (const float*)d_in[4];
    const float* res_w    = (const float*)d_in[5];
    const float* res_b    = (const float*)d_in[6];
    const float* skip_w   = (const float*)d_in[7];
    const float* skip_b   = (const float*)d_in[8];
    const float* w_out    = (const float*)d_in[9];
    const float* lin_w    = (const float*)d_in[10];
    const float* lin_b    = (const float*)d_in[11];
    float* out = (float*)d_out;

    const size_t NEED = 77103104ULL;
    if (ws_size >= NEED) {
        char* base = (char*)d_ws;
        bf16_t* xtA_hi = (bf16_t*)(base);                 // 16,777,216 B
        bf16_t* xtA_lo = (bf16_t*)(base + 16777216);      // 16,777,216 B
        bf16_t* xtB_hi = (bf16_t*)(base + 33554432);      // 16,777,216 B
        bf16_t* xtB_lo = (bf16_t*)(base + 50331648);      // 16,777,216 B
        bf16_t* wg     = (bf16_t*)(base + 67108864);      //  2,097,152 B (16 x 131072 B)
        bf16_t* wr     = (bf16_t*)(base + 69206016);      //    524,288 B (15 x 32768 B)
        float*  asum   = (float*)(base + 69730304);       //    131,072 B
        bf16_t* zeros  = (bf16_t*)(base + 69861376);      //     65,536 B

        hipMemsetAsync(asum, 0, 131072, stream);
        zero_misc_kernel<<<dim3(128), dim3(256), 0, stream>>>(zeros);
        prep_wg_kernel<<<dim3(4096), dim3(256), 0, stream>>>(dilate_w, wg);
        prep_wr_kernel<<<dim3(960), dim3(256), 0, stream>>>(res_w, wr);
        prep_wi_kernel<<<dim3(128), dim3(256), 0, stream>>>(w_in);

        // input conv in two 8-batch passes; xtB buffers as transpose scratch
        for (int pass = 0; pass < 2; ++pass) {
            transpose_in<<<dim3(64, 4, 8), dim3(256), 0, stream>>>(
                input, xtB_hi, xtB_lo, pass * 8);
            pw_mfma_in<<<dim3(32, 1, 8), dim3(256), 0, stream>>>(
                xtB_hi, xtB_lo, b_in, xtA_hi, xtA_lo, pass * 8);
        }

        for (int i = 0; i < 16; ++i) {
            int d = 1 << (i % 9);
            const bf16_t* xc_hi = (i & 1) ? xtB_hi : xtA_hi;
            const bf16_t* xc_lo = (i & 1) ? xtB_lo : xtA_lo;
            bf16_t* xn_hi = (i & 1) ? xtA_hi : xtB_hi;
            bf16_t* xn_lo = (i & 1) ? xtA_lo : xtB_lo;
            int skipres = (i == 15) ? 1 : 0;
            fused_layer<<<dim3(32, 1, 16), dim3(512), 0, stream>>>(
                xc_hi, xc_lo, xn_hi, xn_lo, zeros,
                wg + (size_t)i * 65536, dilate_b + i * 256,
                wr + (size_t)(skipres ? 0 : i) * 16384,
                res_b + (skipres ? 0 : i) * 128,
                asum + i * 2048, d, skipres);
        }
        skip_partial<<<dim3(256), dim3(256), 0, stream>>>(asum, skip_w);
        head_kernel<<<dim3(16), dim3(256), 0, stream>>>(
            skip_b, w_out, lin_w, lin_b, out);
    } else {
        // fallback: fp32 VALU path (round 1)
        float* ws   = (float*)d_ws;
        float* x    = ws;
        float* acts = ws + 8388608;
        float* asum = ws + 16777216;
        dim3 grid(64, 2, 16), blk(256, 1, 1);
        pw_conv_kernel<<<grid, blk, 0, stream>>>(input, w_in, b_in, x, 256, 0);
        for (int i = 0; i < 16; ++i) {
            int d = 1 << (i % 9);
            gated_conv_kernel<<<grid, blk, 0, stream>>>(
                x, dilate_w + (size_t)i * 256 * 128 * 2, dilate_b + i * 256, acts, d);
            actsum_kernel<<<dim3(2048), blk, 0, stream>>>(acts, asum + i * 2048);
            if (i < 15) {
                pw_conv_kernel<<<grid, blk, 0, stream>>>(
                    acts, res_w + (size_t)i * 128 * 128, res_b + i * 128, x, 128, 1);
            }
        }
        final_kernel<<<dim3(16), blk, 0, stream>>>(
            asum, skip_w, skip_b, w_out, lin_w, lin_b, out);
    }
}

// Round 10
// 993.909 us; speedup vs baseline: 1.3281x; 1.2347x over previous
//
#include <hip/hip_runtime.h>
#include <hip/hip_bf16.h>

// WaveNet forward on gfx950 — round 10 (r9 + coalesced residual epilogue).
// 2-product split: W quantized to bf16 (Whi only), X kept as hi/lo pair.
// Per gated superchunk u (8 total): stage {Whi 16K, Xhi 8K, Xlo 8K} once,
// run 2 MFMA phases against the SAME resident W tile.
// Residual epilogue now routes through LDS: accr staged hi/lo in the dead
// acts region, then coalesced 16B/lane RMW of x (was scattered 8B accesses
// with ~8x line amplification -> 104MB WRITE_SIZE in r9).
// Fallback (ws too small): round-1 fp32 VALU path.

#define KC 32

typedef __bf16 bf16_t;
typedef __bf16 bf16x4 __attribute__((ext_vector_type(4)));
typedef __bf16 bf16x8 __attribute__((ext_vector_type(8)));
typedef float f32x16 __attribute__((ext_vector_type(16)));

__device__ __align__(16) __bf16 g_wi_dev[32768];   // w_in bf16, swizzled
__device__ float g_pooled[4096];                    // [b][256] pooled skip

__device__ __forceinline__ void gl_lds16(const void* g, void* l) {
    __builtin_amdgcn_global_load_lds(
        (const __attribute__((address_space(1))) unsigned int*)g,
        (__attribute__((address_space(3))) unsigned int*)l, 16, 0, 0);
}

__device__ __forceinline__ float fast_sigmoid(float x) {
    float e = __builtin_amdgcn_exp2f(-1.4426950408889634f * x);
    return __builtin_amdgcn_rcpf(1.0f + e);
}
__device__ __forceinline__ float fast_tanh(float x) {
    float e = __builtin_amdgcn_exp2f(-2.8853900817779268f * x);
    return fmaf(2.0f, __builtin_amdgcn_rcpf(1.0f + e), -1.0f);
}

// ---------------- weight prep: bf16 quantize + swizzle ----------------
__global__ __launch_bounds__(256) void prep_wg_kernel(
    const float* __restrict__ dw, bf16_t* __restrict__ wg)
{
    int idx = blockIdx.x * 256 + threadIdx.x;   // 1,048,576
    int e = idx & 7, ps = (idx >> 3) & 3, row = (idx >> 5) & 255;
    int c = (idx >> 13) & 7, layer = idx >> 16;
    int s = ps ^ ((row >> 1) & 3);
    int k = c * 32 + s * 8 + e;
    int tap = k >> 7, ch = k & 127;
    wg[idx] = (bf16_t)dw[(((size_t)layer * 256 + row) * 128 + ch) * 2 + tap];
}

__global__ __launch_bounds__(256) void prep_wr_kernel(
    const float* __restrict__ rw, bf16_t* __restrict__ wr)
{
    int idx = blockIdx.x * 256 + threadIdx.x;   // 245,760 (15 layers)
    int e = idx & 7, ps = (idx >> 3) & 3, row = (idx >> 5) & 127;
    int c = (idx >> 12) & 3, layer = idx >> 14;
    int s = ps ^ ((row >> 1) & 3);
    int ch = c * 32 + s * 8 + e;
    wr[idx] = (bf16_t)rw[((size_t)layer * 128 + row) * 128 + ch];
}

__global__ __launch_bounds__(256) void prep_wi_kernel(const float* __restrict__ wi)
{
    int idx = blockIdx.x * 256 + threadIdx.x;   // 32,768
    int e = idx & 7, ps = (idx >> 3) & 3, row = (idx >> 5) & 127;
    int c = idx >> 12;
    int s = ps ^ ((row >> 1) & 3);
    int ch = c * 32 + s * 8 + e;
    g_wi_dev[idx] = (bf16_t)wi[(size_t)row * 256 + ch];
}

__global__ __launch_bounds__(256) void zero_misc_kernel(bf16_t* __restrict__ zeros)
{
    int idx = blockIdx.x * 256 + threadIdx.x;   // 32768
    zeros[idx] = (bf16_t)0.0f;
    if (idx < 4096) g_pooled[idx] = 0.0f;
}

// ---------------- input transpose: fp32 [ch][t] -> bf16 hi/lo [t][ch] ----------------
__global__ __launch_bounds__(256) void transpose_in(
    const float* __restrict__ input, bf16_t* __restrict__ th,
    bf16_t* __restrict__ tl, int b_off)
{
    __shared__ float Sl[64][65];
    const int tid = threadIdx.x;
    const int t0 = blockIdx.x * 64, ch0 = blockIdx.y * 64, bz = blockIdx.z;
    const int b = b_off + bz;
#pragma unroll
    for (int it = 0; it < 16; ++it) {
        int idx = it * 256 + tid;
        int t = idx & 63, ch = idx >> 6;
        Sl[ch][t] = input[((size_t)b * 256 + ch0 + ch) * 4096 + t0 + t];
    }
    __syncthreads();
#pragma unroll
    for (int it = 0; it < 16; ++it) {
        int idx = it * 256 + tid;
        int ch = idx & 63, t = idx >> 6;
        float v = Sl[ch][t];
        bf16_t hb = (bf16_t)v;
        size_t o = ((size_t)bz * 4096 + t0 + t) * 256 + ch0 + ch;
        th[o] = hb;
        tl[o] = (bf16_t)(v - (float)hb);
    }
}

// ---------------- fused layer: gated conv + acts + residual conv ----------------
// 512 threads (8 waves). LDS 80KB:
//   gated loop : Whi dbuf 2x16K [0,32K), Xhi dbuf 2x8K [32K,48K),
//                Xlo dbuf 2x8K [48K,64K)
//   epilogue   : acts hi [0,32K), acts lo [32K,64K), resW dbuf 2x8K [64K,80K)
//   res epi    : xn hi [0,32K), xn lo [32K,64K) (acts dead after res loop)
__global__ __launch_bounds__(512, 4) void fused_layer(
    const bf16_t* __restrict__ xc_hi, const bf16_t* __restrict__ xc_lo,
    bf16_t* __restrict__ xn_hi, bf16_t* __restrict__ xn_lo,
    const bf16_t* __restrict__ zeros,
    const bf16_t* __restrict__ wg_l, const float* __restrict__ dbias,
    const bf16_t* __restrict__ wr_l, const float* __restrict__ rbias,
    float* __restrict__ asum_l, int d, int skipres)
{
    __shared__ __align__(16) char lds[81920];
    const int tid = threadIdx.x;
    const int wave = tid >> 6, lane = tid & 63;
    const int l31 = lane & 31, h = lane >> 5;
    const int wm = wave & 3, wn = wave >> 2;
    const int t0 = blockIdx.x * 128;
    const int b = blockIdx.z;

    f32x16 acc[2][2];
#pragma unroll
    for (int m = 0; m < 2; ++m)
#pragma unroll
        for (int n = 0; n < 2; ++n) acc[m][n] = (f32x16)(0.0f);

    const int t_pos = tid >> 2;
    const int s_x = (tid & 3) ^ ((t_pos >> 1) & 3);
    const int chx = s_x << 3;

    // 4 loads/thread per superchunk: 2x Whi, 1x Xhi, 1x Xlo
    auto stage_g = [&](int u, int sl) {
        const char* wsrc = (const char*)wg_l + (size_t)u * 16384;
        char* wdst = lds + sl * 16384;
        gl_lds16(wsrc + tid * 16, wdst + tid * 16);
        gl_lds16(wsrc + (tid + 512) * 16, wdst + (tid + 512) * 16);
        int tap = (u >> 2) & 1;
        int ch = ((u & 3) << 5) + chx;
        int tg = t0 + t_pos - (tap ? 0 : d);
        size_t gi = ((size_t)b * 4096 + tg) * 128 + ch;
        const bf16_t* sph = (tg >= 0) ? (xc_hi + gi) : (zeros + ch);
        const bf16_t* spl = (tg >= 0) ? (xc_lo + gi) : (zeros + ch);
        gl_lds16(sph, lds + 32768 + sl * 8192 + tid * 16);
        gl_lds16(spl, lds + 49152 + sl * 8192 + tid * 16);
    };

    stage_g(0, 0);
    const int swz = (l31 >> 1) & 3;
    int aoff[2][2], boff[2][2];
#pragma unroll
    for (int m = 0; m < 2; ++m)
#pragma unroll
        for (int s2 = 0; s2 < 2; ++s2)
            aoff[m][s2] = ((m ? 128 + wm * 32 : wm * 32) + l31) * 64 +
                          (((s2 * 2 + h) ^ swz) << 4);
#pragma unroll
    for (int n = 0; n < 2; ++n)
#pragma unroll
        for (int s2 = 0; s2 < 2; ++s2)
            boff[n][s2] = (wn * 64 + n * 32 + l31) * 64 + (((s2 * 2 + h) ^ swz) << 4);

    for (int u = 0; u < 8; ++u) {
        if (u < 7) {
            stage_g(u + 1, (u + 1) & 1);
            asm volatile("s_waitcnt vmcnt(4)" ::: "memory"); // chunk u's 4 landed
        } else {
            asm volatile("s_waitcnt vmcnt(0)" ::: "memory");
        }
        __builtin_amdgcn_s_barrier();

        const char* whb = lds + (u & 1) * 16384;
        const char* xhb = lds + 32768 + (u & 1) * 8192;
        const char* xlb = lds + 49152 + (u & 1) * 8192;

        // P0: Whi x Xhi
        {
            bf16x8 a0[2], a1[2], b0[2], b1[2];
#pragma unroll
            for (int s2 = 0; s2 < 2; ++s2) {
                a0[s2] = *(const bf16x8*)(whb + aoff[0][s2]);
                a1[s2] = *(const bf16x8*)(whb + aoff[1][s2]);
                b0[s2] = *(const bf16x8*)(xhb + boff[0][s2]);
                b1[s2] = *(const bf16x8*)(xhb + boff[1][s2]);
            }
            __builtin_amdgcn_s_setprio(1);
#pragma unroll
            for (int s2 = 0; s2 < 2; ++s2) {
                acc[0][0] = __builtin_amdgcn_mfma_f32_32x32x16_bf16(a0[s2], b0[s2], acc[0][0], 0, 0, 0);
                acc[0][1] = __builtin_amdgcn_mfma_f32_32x32x16_bf16(a0[s2], b1[s2], acc[0][1], 0, 0, 0);
                acc[1][0] = __builtin_amdgcn_mfma_f32_32x32x16_bf16(a1[s2], b0[s2], acc[1][0], 0, 0, 0);
                acc[1][1] = __builtin_amdgcn_mfma_f32_32x32x16_bf16(a1[s2], b1[s2], acc[1][1], 0, 0, 0);
            }
            __builtin_amdgcn_s_setprio(0);
        }
        // P1: Whi x Xlo (same W tile resident)
        {
            bf16x8 a0[2], a1[2], b0[2], b1[2];
#pragma unroll
            for (int s2 = 0; s2 < 2; ++s2) {
                a0[s2] = *(const bf16x8*)(whb + aoff[0][s2]);
                a1[s2] = *(const bf16x8*)(whb + aoff[1][s2]);
                b0[s2] = *(const bf16x8*)(xlb + boff[0][s2]);
                b1[s2] = *(const bf16x8*)(xlb + boff[1][s2]);
            }
            __builtin_amdgcn_s_setprio(1);
#pragma unroll
            for (int s2 = 0; s2 < 2; ++s2) {
                acc[0][0] = __builtin_amdgcn_mfma_f32_32x32x16_bf16(a0[s2], b0[s2], acc[0][0], 0, 0, 0);
                acc[0][1] = __builtin_amdgcn_mfma_f32_32x32x16_bf16(a0[s2], b1[s2], acc[0][1], 0, 0, 0);
                acc[1][0] = __builtin_amdgcn_mfma_f32_32x32x16_bf16(a1[s2], b0[s2], acc[1][0], 0, 0, 0);
                acc[1][1] = __builtin_amdgcn_mfma_f32_32x32x16_bf16(a1[s2], b1[s2], acc[1][1], 0, 0, 0);
            }
            __builtin_amdgcn_s_setprio(0);
        }
        __builtin_amdgcn_s_barrier();  // reads of slot u&1 retired -> restage safe
    }
    __syncthreads();

    // ---- acts epilogue ----
    auto stage_rw = [&](int c, int sl) {
        gl_lds16((const char*)wr_l + (size_t)c * 8192 + tid * 16,
                 lds + 65536 + sl * 8192 + tid * 16);
    };
    if (!skipres) stage_rw(0, 0);   // HBM latency hides under activation VALU

    float psum[16];
#pragma unroll
    for (int u = 0; u < 16; ++u) psum[u] = 0.0f;

#pragma unroll
    for (int n = 0; n < 2; ++n) {
        int t = wn * 64 + n * 32 + l31;
        int sw = (t & 7) << 4;
#pragma unroll
        for (int rg = 0; rg < 4; ++rg) {
            int ch0 = wm * 32 + rg * 8 + 4 * h;
            bf16x4 hv, lv;
#pragma unroll
            for (int j = 0; j < 4; ++j) {
                int r = rg * 4 + j;
                float a1v = acc[0][n][r] + dbias[ch0 + j];
                float a2v = acc[1][n][r] + dbias[128 + ch0 + j];
                float a = fast_tanh(a1v) * fast_sigmoid(a2v);
                psum[rg * 4 + j] += a;
                bf16_t hb = (bf16_t)a;
                hv[j] = hb;
                lv[j] = (bf16_t)(a - (float)hb);
            }
            int low = (t * 256 + ch0 * 2) ^ sw;
            *(bf16x4*)(lds + low) = hv;
            *(bf16x4*)(lds + 32768 + low) = lv;
        }
    }

#pragma unroll
    for (int u = 0; u < 16; ++u) {
        float v = psum[u];
        v += __shfl_xor(v, 1);
        v += __shfl_xor(v, 2);
        v += __shfl_xor(v, 4);
        v += __shfl_xor(v, 8);
        v += __shfl_xor(v, 16);
        psum[u] = v;
    }
    if (l31 == 0) {
#pragma unroll
        for (int u = 0; u < 16; ++u) {
            int ch = wm * 32 + (u >> 2) * 8 + 4 * h + (u & 3);
            atomicAdd(asum_l + b * 128 + ch, psum[u]);
        }
    }
    if (skipres) return;

    asm volatile("s_waitcnt lgkmcnt(0)" ::: "memory");
    __builtin_amdgcn_s_barrier();   // acts visible to all waves; resW c0 in flight

    // ---- residual K-loop: M=128 x N=128, 4 superchunks x 2 phases ----
    f32x16 accr[2];
    accr[0] = (f32x16)(0.0f);
    accr[1] = (f32x16)(0.0f);
    int tl_[2], mk_[2];
#pragma unroll
    for (int n = 0; n < 2; ++n) {
        tl_[n] = wn * 64 + n * 32 + l31;
        mk_[n] = (tl_[n] & 7) << 4;
    }

    for (int u = 0; u < 4; ++u) {
        if (u < 3) {
            stage_rw(u + 1, (u + 1) & 1);
            asm volatile("s_waitcnt vmcnt(1)" ::: "memory");
        } else {
            asm volatile("s_waitcnt vmcnt(0)" ::: "memory");
        }
        __builtin_amdgcn_s_barrier();

        const char* ab = lds + 65536 + (u & 1) * 8192;
        int cb = u << 6;
#pragma unroll
        for (int ph = 0; ph < 2; ++ph) {
            const char* bb = lds + (ph ? 32768 : 0);
            bf16x8 av[2], bv[2][2];
#pragma unroll
            for (int s2 = 0; s2 < 2; ++s2) {
                av[s2] = *(const bf16x8*)(ab + (wm * 32 + l31) * 64 +
                                          (((s2 * 2 + h) ^ swz) << 4));
#pragma unroll
                for (int n = 0; n < 2; ++n) {
                    int low = (cb + ((s2 * 2 + h) << 4)) ^ mk_[n];
                    bv[n][s2] = *(const bf16x8*)(bb + tl_[n] * 256 + low);
                }
            }
            __builtin_amdgcn_s_setprio(1);
#pragma unroll
            for (int s2 = 0; s2 < 2; ++s2) {
                accr[0] = __builtin_amdgcn_mfma_f32_32x32x16_bf16(av[s2], bv[0][s2], accr[0], 0, 0, 0);
                accr[1] = __builtin_amdgcn_mfma_f32_32x32x16_bf16(av[s2], bv[1][s2], accr[1], 0, 0, 0);
            }
            __builtin_amdgcn_s_setprio(0);
        }
        __builtin_amdgcn_s_barrier();
    }

    // ---- residual epilogue (coalesced via LDS) ----
    // Stage (accr + rbias) hi/lo into the dead acts region [0,64K), then
    // coalesced 16B/lane RMW: xn = staged + x_old, re-split.
#pragma unroll
    for (int n = 0; n < 2; ++n) {
        int t = tl_[n];
        int sw = (t & 7) << 4;
#pragma unroll
        for (int rg = 0; rg < 4; ++rg) {
            int ch0 = wm * 32 + rg * 8 + 4 * h;
            bf16x4 hv, lv;
#pragma unroll
            for (int j = 0; j < 4; ++j) {
                float v = accr[n][rg * 4 + j] + rbias[ch0 + j];
                bf16_t hb = (bf16_t)v;
                hv[j] = hb;
                lv[j] = (bf16_t)(v - (float)hb);
            }
            int low = (t * 256 + ch0 * 2) ^ sw;
            *(bf16x4*)(lds + low) = hv;
            *(bf16x4*)(lds + 32768 + low) = lv;
        }
    }
    __syncthreads();

#pragma unroll
    for (int it = 0; it < 4; ++it) {
        int g = it * 512 + tid;
        int byte = g * 16;                  // [0,32K): hi-plane logical bytes
        int t = byte >> 8;
        int off = byte & 255;
        int phys = byte ^ ((t & 7) << 4);   // XOR preserves 16B chunks
        bf16x8 hv = *(const bf16x8*)(lds + phys);
        bf16x8 lv = *(const bf16x8*)(lds + 32768 + phys);
        size_t gofs = ((size_t)b * 4096 + t0 + t) * 256 + off;   // bytes
        bf16x8 oh = *(const bf16x8*)((const char*)xc_hi + gofs);
        bf16x8 ol = *(const bf16x8*)((const char*)xc_lo + gofs);
        bf16x8 nh, nl;
#pragma unroll
        for (int j = 0; j < 8; ++j) {
            float v = (float)hv[j] + (float)lv[j] + (float)oh[j] + (float)ol[j];
            bf16_t hb = (bf16_t)v;
            nh[j] = hb;
            nl[j] = (bf16_t)(v - (float)hb);
        }
        *(bf16x8*)((char*)xn_hi + gofs) = nh;
        *(bf16x8*)((char*)xn_lo + gofs) = nl;
    }
}

// ---------------- input pointwise MFMA (K=256 ch, 2 phases) ----------------
__global__ __launch_bounds__(256) void pw_mfma_in(
    const bf16_t* __restrict__ sh, const bf16_t* __restrict__ sl,
    const float* __restrict__ bias,
    bf16_t* __restrict__ xth, bf16_t* __restrict__ xtl, int b_off)
{
    __shared__ __align__(16) char lds[49152];
    const int tid = threadIdx.x;
    const int wave = tid >> 6, lane = tid & 63;
    const int l31 = lane & 31, h = lane >> 5;
    const int wm = wave & 1, wn = wave >> 1;
    const int t0 = blockIdx.x * 128;
    const int bz = blockIdx.z;
    const bf16_t* w = (const bf16_t*)g_wi_dev;

    f32x16 acc[2][2];
#pragma unroll
    for (int m = 0; m < 2; ++m)
#pragma unroll
        for (int n = 0; n < 2; ++n) acc[m][n] = (f32x16)(0.0f);

    auto stage = [&](int u, int sl_) {
        const char* wsrc = (const char*)w + (size_t)u * 8192;
        char* wdst = lds + sl_ * 8192;
        gl_lds16(wsrc + tid * 16, wdst + tid * 16);
        gl_lds16(wsrc + (tid + 256) * 16, wdst + (tid + 256) * 16);
#pragma unroll
        for (int it = 0; it < 2; ++it) {
            int row = (tid >> 2) + it * 64;
            int ps = tid & 3;
            int sx = ps ^ ((row >> 1) & 3);
            size_t gi = ((size_t)bz * 4096 + t0 + row) * 256 + u * 32 + sx * 8;
            gl_lds16(sh + gi, lds + 16384 + sl_ * 8192 + (row * 4 + ps) * 16);
            gl_lds16(sl + gi, lds + 32768 + sl_ * 8192 + (row * 4 + ps) * 16);
        }
    };

    stage(0, 0);
    const int swz = (l31 >> 1) & 3;
    int aoff[2][2], boff[2][2];
#pragma unroll
    for (int m = 0; m < 2; ++m)
#pragma unroll
        for (int s2 = 0; s2 < 2; ++s2)
            aoff[m][s2] = (wm * 64 + m * 32 + l31) * 64 + (((s2 * 2 + h) ^ swz) << 4);
#pragma unroll
    for (int n = 0; n < 2; ++n)
#pragma unroll
        for (int s2 = 0; s2 < 2; ++s2)
            boff[n][s2] = (wn * 64 + n * 32 + l31) * 64 + (((s2 * 2 + h) ^ swz) << 4);

    for (int u = 0; u < 8; ++u) {
        if (u < 7) {
            stage(u + 1, (u + 1) & 1);
            asm volatile("s_waitcnt vmcnt(6)" ::: "memory");
        } else {
            asm volatile("s_waitcnt vmcnt(0)" ::: "memory");
        }
        __builtin_amdgcn_s_barrier();

        const char* wb = lds + (u & 1) * 8192;
#pragma unroll
        for (int ph = 0; ph < 2; ++ph) {
            const char* xb = lds + (ph ? 32768 : 16384) + (u & 1) * 8192;
            bf16x8 a0[2], a1[2], b0[2], b1[2];
#pragma unroll
            for (int s2 = 0; s2 < 2; ++s2) {
                a0[s2] = *(const bf16x8*)(wb + aoff[0][s2]);
                a1[s2] = *(const bf16x8*)(wb + aoff[1][s2]);
                b0[s2] = *(const bf16x8*)(xb + boff[0][s2]);
                b1[s2] = *(const bf16x8*)(xb + boff[1][s2]);
            }
#pragma unroll
            for (int s2 = 0; s2 < 2; ++s2) {
                acc[0][0] = __builtin_amdgcn_mfma_f32_32x32x16_bf16(a0[s2], b0[s2], acc[0][0], 0, 0, 0);
                acc[0][1] = __builtin_amdgcn_mfma_f32_32x32x16_bf16(a0[s2], b1[s2], acc[0][1], 0, 0, 0);
                acc[1][0] = __builtin_amdgcn_mfma_f32_32x32x16_bf16(a1[s2], b0[s2], acc[1][0], 0, 0, 0);
                acc[1][1] = __builtin_amdgcn_mfma_f32_32x32x16_bf16(a1[s2], b1[s2], acc[1][1], 0, 0, 0);
            }
        }
        __builtin_amdgcn_s_barrier();
    }

    const int b = b_off + bz;
#pragma unroll
    for (int n = 0; n < 2; ++n) {
        int t = wn * 64 + n * 32 + l31;
        size_t trow = ((size_t)b * 4096 + t0 + t) * 128;
#pragma unroll
        for (int m = 0; m < 2; ++m) {
#pragma unroll
            for (int rg = 0; rg < 4; ++rg) {
                int ch0 = wm * 64 + m * 32 + rg * 8 + 4 * h;
                bf16x4 nh, nl;
#pragma unroll
                for (int j = 0; j < 4; ++j) {
                    float v = acc[m][n][rg * 4 + j] + bias[ch0 + j];
                    bf16_t hb = (bf16_t)v;
                    nh[j] = hb;
                    nl[j] = (bf16_t)(v - (float)hb);
                }
                *(bf16x4*)(xth + trow + ch0) = nh;
                *(bf16x4*)(xtl + trow + ch0) = nl;
            }
        }
    }
}

// ---------------- output head ----------------
__global__ __launch_bounds__(256) void skip_partial(
    const float* __restrict__ asum, const float* __restrict__ skip_w)
{
    const int i = blockIdx.x >> 4, b = blockIdx.x & 15, s = threadIdx.x;
    const float* sw = skip_w + ((size_t)i * 256 + s) * 128;
    const float* as = asum + i * 2048 + b * 128;
    float t = 0.0f;
#pragma unroll 8
    for (int r = 0; r < 128; ++r) t = fmaf(sw[r], as[r], t);
    atomicAdd(&g_pooled[b * 256 + s], t);
}

__global__ __launch_bounds__(256) void head_kernel(
    const float* __restrict__ skip_b, const float* __restrict__ w_out,
    const float* __restrict__ lin_w, const float* __restrict__ lin_b,
    float* __restrict__ out)
{
    const int b = blockIdx.x;
    const int s = threadIdx.x;
    float sb = 0.0f;
#pragma unroll
    for (int i = 0; i < 16; ++i) sb += skip_b[i * 256 + s];
    __shared__ float pl[256];
    pl[s] = g_pooled[b * 256 + s] * (1.0f / 4096.0f) + sb;
    __syncthreads();
    __shared__ float o1[12];
    if (s < 12) {
        float v = 0.0f;
        for (int q = 0; q < 256; ++q) v = fmaf(w_out[s * 256 + q], pl[q], v);
        o1[s] = v;
    }
    __syncthreads();
    if (s < 12) {
        float v = lin_b[s];
#pragma unroll
        for (int m = 0; m < 12; ++m) v = fmaf(lin_w[s * 12 + m], o1[m], v);
        out[b * 12 + s] = v;
    }
}

// ================= fallback fp32 path (round-1, proven) =================
__global__ __launch_bounds__(256) void pw_conv_kernel(
    const float* __restrict__ src, const float* __restrict__ W,
    const float* __restrict__ bias, float* __restrict__ dst,
    int K, int accumulate)
{
    __shared__ float Wl[KC][68];
    __shared__ float Sl[KC][68];
    const int tid = threadIdx.x;
    const int t0 = blockIdx.x * 64;
    const int row0 = blockIdx.y * 64;
    const int b = blockIdx.z;
    const int i4 = (tid >> 4) * 4;
    const int j4 = (tid & 15) * 4;
    float acc[4][4];
#pragma unroll
    for (int r = 0; r < 4; ++r) {
        float bv = bias[row0 + i4 + r];
#pragma unroll
        for (int c = 0; c < 4; ++c) acc[r][c] = bv;
    }
    const float* sb = src + (size_t)b * K * 4096;
    for (int k0 = 0; k0 < K; k0 += KC) {
        __syncthreads();
#pragma unroll
        for (int it = 0; it < 8; ++it) {
            int idx = it * 256 + tid;
            int kk = idx & 31, oo = idx >> 5;
            Wl[kk][oo] = W[(size_t)(row0 + oo) * K + (k0 + kk)];
        }
#pragma unroll
        for (int it = 0; it < 8; ++it) {
            int idx = it * 256 + tid;
            int t = idx & 63, kk = idx >> 6;
            Sl[kk][t] = sb[(size_t)(k0 + kk) * 4096 + t0 + t];
        }
        __syncthreads();
#pragma unroll
        for (int kk = 0; kk < KC; ++kk) {
            float4 wv = *(const float4*)&Wl[kk][i4];
            float4 sv = *(const float4*)&Sl[kk][j4];
            float wr_[4] = {wv.x, wv.y, wv.z, wv.w};
            float sc[4] = {sv.x, sv.y, sv.z, sv.w};
#pragma unroll
            for (int r = 0; r < 4; ++r)
#pragma unroll
                for (int c = 0; c < 4; ++c)
                    acc[r][c] = fmaf(wr_[r], sc[c], acc[r][c]);
        }
    }
    float* db = dst + (size_t)b * 128 * 4096;
#pragma unroll
    for (int r = 0; r < 4; ++r) {
        float* p = db + (size_t)(row0 + i4 + r) * 4096 + t0 + j4;
        float4 v;
        if (accumulate) {
            float4 old = *(const float4*)p;
            v.x = acc[r][0] + old.x; v.y = acc[r][1] + old.y;
            v.z = acc[r][2] + old.z; v.w = acc[r][3] + old.w;
        } else {
            v.x = acc[r][0]; v.y = acc[r][1]; v.z = acc[r][2]; v.w = acc[r][3];
        }
        *(float4*)p = v;
    }
}

__global__ __launch_bounds__(256) void gated_conv_kernel(
    const float* __restrict__ x, const float* __restrict__ Wd,
    const float* __restrict__ dbias, float* __restrict__ acts, int d)
{
    __shared__ float Wt0[KC][68], Wt1[KC][68], Ws0[KC][68], Ws1[KC][68];
    __shared__ float Sc[KC][68], Sp[KC][68];
    const int tid = threadIdx.x;
    const int t0 = blockIdx.x * 64;
    const int row0 = blockIdx.y * 64;
    const int b = blockIdx.z;
    const int i4 = (tid >> 4) * 4;
    const int j4 = (tid & 15) * 4;
    float a1[4][4], a2[4][4];
#pragma unroll
    for (int r = 0; r < 4; ++r) {
        float bt = dbias[row0 + i4 + r];
        float bs = dbias[128 + row0 + i4 + r];
#pragma unroll
        for (int c = 0; c < 4; ++c) { a1[r][c] = bt; a2[r][c] = bs; }
    }
    const float* xb = x + (size_t)b * 128 * 4096;
    for (int k0 = 0; k0 < 128; k0 += KC) {
        __syncthreads();
#pragma unroll
        for (int it = 0; it < 8; ++it) {
            int idx = it * 256 + tid;
            int kk = idx & 31, oo = idx >> 5;
            float2 wt = *(const float2*)(Wd + ((size_t)(row0 + oo) * 128 + (k0 + kk)) * 2);
            float2 ws = *(const float2*)(Wd + ((size_t)(128 + row0 + oo) * 128 + (k0 + kk)) * 2);
            Wt0[kk][oo] = wt.x; Wt1[kk][oo] = wt.y;
            Ws0[kk][oo] = ws.x; Ws1[kk][oo] = ws.y;
        }
#pragma unroll
        for (int it = 0; it < 8; ++it) {
            int idx = it * 256 + tid;
            int t = idx & 63, kk = idx >> 6;
            Sc[kk][t] = xb[(size_t)(k0 + kk) * 4096 + t0 + t];
            int gt = t0 + t - d;
            Sp[kk][t] = (gt >= 0) ? xb[(size_t)(k0 + kk) * 4096 + gt] : 0.0f;
        }
        __syncthreads();
#pragma unroll
        for (int kk = 0; kk < KC; ++kk) {
            float4 xcv4 = *(const float4*)&Sc[kk][j4];
            float4 xpv4 = *(const float4*)&Sp[kk][j4];
            float4 wt0 = *(const float4*)&Wt0[kk][i4];
            float4 wt1 = *(const float4*)&Wt1[kk][i4];
            float4 ws0 = *(const float4*)&Ws0[kk][i4];
            float4 ws1 = *(const float4*)&Ws1[kk][i4];
            float xc[4] = {xcv4.x, xcv4.y, xcv4.z, xcv4.w};
            float xp[4] = {xpv4.x, xpv4.y, xpv4.z, xpv4.w};
            float t0r[4] = {wt0.x, wt0.y, wt0.z, wt0.w};
            float t1r[4] = {wt1.x, wt1.y, wt1.z, wt1.w};
            float s0r[4] = {ws0.x, ws0.y, ws0.z, ws0.w};
            float s1r[4] = {ws1.x, ws1.y, ws1.z, ws1.w};
#pragma unroll
            for (int r = 0; r < 4; ++r)
#pragma unroll
                for (int c = 0; c < 4; ++c) {
                    a1[r][c] = fmaf(t0r[r], xp[c], a1[r][c]);
                    a1[r][c] = fmaf(t1r[r], xc[c], a1[r][c]);
                    a2[r][c] = fmaf(s0r[r], xp[c], a2[r][c]);
                    a2[r][c] = fmaf(s1r[r], xc[c], a2[r][c]);
                }
        }
    }
    float* ab = acts + (size_t)b * 128 * 4096;
#pragma unroll
    for (int r = 0; r < 4; ++r) {
        float4 v;
#pragma unroll
        for (int c = 0; c < 4; ++c) {
            float th = tanhf(a1[r][c]);
            float sg = 1.0f / (1.0f + expf(-a2[r][c]));
            ((float*)&v)[c] = th * sg;
        }
        *(float4*)&ab[(size_t)(row0 + i4 + r) * 4096 + t0 + j4] = v;
    }
}

__global__ __launch_bounds__(256) void actsum_kernel(
    const float* __restrict__ acts, float* __restrict__ out)
{
    const int br = blockIdx.x;
    const float* p = acts + (size_t)br * 4096;
    float s = 0.0f;
#pragma unroll
    for (int c = 0; c < 16; ++c) s += p[c * 256 + threadIdx.x];
    __shared__ float red[256];
    red[threadIdx.x] = s;
    __syncthreads();
    for (int off = 128; off > 0; off >>= 1) {
        if (threadIdx.x < off) red[threadIdx.x] += red[threadIdx.x + off];
        __syncthreads();
    }
    if (threadIdx.x == 0) out[br] = red[0];
}

__global__ __launch_bounds__(256) void final_kernel(
    const float* __restrict__ actsum, const float* __restrict__ skip_w,
    const float* __restrict__ skip_b, const float* __restrict__ w_out,
    const float* __restrict__ lin_w, const float* __restrict__ lin_b,
    float* __restrict__ out)
{
    const int b = blockIdx.x;
    const int s = threadIdx.x;
    float acc = 0.0f;
    for (int i = 0; i < 16; ++i) {
        const float* sw = skip_w + ((size_t)i * 256 + s) * 128;
        const float* as = actsum + ((size_t)i * 16 + b) * 128;
        float t = 0.0f;
#pragma unroll 8
        for (int r = 0; r < 128; ++r) t = fmaf(sw[r], as[r], t);
        acc += t;
    }
    float sb = 0.0f;
    for (int i = 0; i < 16; ++i) sb += skip_b[i * 256 + s];
    __shared__ float pl[256];
    pl[s] = acc * (1.0f / 4096.0f) + sb;
    __syncthreads();
    __shared__ float o1[12];
    if (s < 12) {
        float v = 0.0f;
        for (int qq = 0; qq < 256; ++qq) v = fmaf(w_out[s * 256 + qq], pl[qq], v);
        o1[s] = v;
    }
    __syncthreads();
    if (s < 12) {
        float v = lin_b[s];
#pragma unroll
        for (int m = 0; m < 12; ++m) v = fmaf(lin_w[s * 12 + m], o1[m], v);
        out[b * 12 + s] = v;
    }
}

// =======================================================================
extern "C" void kernel_launch(void* const* d_in, const int* in_sizes, int n_in,
                              void* d_out, int out_size, void* d_ws, size_t ws_size,
                              hipStream_t stream)
{
    const float* input    = (const float*)d_in[0];
    const float* w_in     = (const float*)d_in[1];
    const float* b_in     = (const float*)d_in[2];
    const float* dilate_w = (const float*)d_in[3];
    const float* dilate_b = (const float*)d_in[4];
    const float* res_w    = (const float*)d_in[5];
    const float* res_b    = (const float*)d_in[6];
    const float* skip_w   = (const float*)d_in[7];
    const float* skip_b   = (const float*)d_in[8];
    const float* w_out    = (const float*)d_in[9];
    const float* lin_w    = (const float*)d_in[10];
    const float* lin_b    = (const float*)d_in[11];
    float* out = (float*)d_out;

    const size_t NEED = 77103104ULL;
    if (ws_size >= NEED) {
        char* base = (char*)d_ws;
        bf16_t* xtA_hi = (bf16_t*)(base);                 // 16,777,216 B
        bf16_t* xtA_lo = (bf16_t*)(base + 16777216);      // 16,777,216 B
        bf16_t* xtB_hi = (bf16_t*)(base + 33554432);      // 16,777,216 B
        bf16_t* xtB_lo = (bf16_t*)(base + 50331648);      // 16,777,216 B
        bf16_t* wg     = (bf16_t*)(base + 67108864);      //  2,097,152 B
        bf16_t* wr     = (bf16_t*)(base + 69206016);      //    524,288 B
        float*  asum   = (float*)(base + 69730304);       //    131,072 B
        bf16_t* zeros  = (bf16_t*)(base + 69861376);      //     65,536 B

        hipMemsetAsync(asum, 0, 131072, stream);
        zero_misc_kernel<<<dim3(128), dim3(256), 0, stream>>>(zeros);
        prep_wg_kernel<<<dim3(4096), dim3(256), 0, stream>>>(dilate_w, wg);
        prep_wr_kernel<<<dim3(960), dim3(256), 0, stream>>>(res_w, wr);
        prep_wi_kernel<<<dim3(128), dim3(256), 0, stream>>>(w_in);

        // input conv in two 8-batch passes; xtB buffers as transpose scratch
        for (int pass = 0; pass < 2; ++pass) {
            transpose_in<<<dim3(64, 4, 8), dim3(256), 0, stream>>>(
                input, xtB_hi, xtB_lo, pass * 8);
            pw_mfma_in<<<dim3(32, 1, 8), dim3(256), 0, stream>>>(
                xtB_hi, xtB_lo, b_in, xtA_hi, xtA_lo, pass * 8);
        }

        for (int i = 0; i < 16; ++i) {
            int d = 1 << (i % 9);
            const bf16_t* xc_hi = (i & 1) ? xtB_hi : xtA_hi;
            const bf16_t* xc_lo = (i & 1) ? xtB_lo : xtA_lo;
            bf16_t* xn_hi = (i & 1) ? xtA_hi : xtB_hi;
            bf16_t* xn_lo = (i & 1) ? xtA_lo : xtB_lo;
            int skipres = (i == 15) ? 1 : 0;
            fused_layer<<<dim3(32, 1, 16), dim3(512), 0, stream>>>(
                xc_hi, xc_lo, xn_hi, xn_lo, zeros,
                wg + (size_t)i * 65536, dilate_b + i * 256,
                wr + (size_t)(skipres ? 0 : i) * 16384,
                res_b + (skipres ? 0 : i) * 128,
                asum + i * 2048, d, skipres);
        }
        skip_partial<<<dim3(256), dim3(256), 0, stream>>>(asum, skip_w);
        head_kernel<<<dim3(16), dim3(256), 0, stream>>>(
            skip_b, w_out, lin_w, lin_b, out);
    } else {
        // fallback: fp32 VALU path (round 1)
        float* ws   = (float*)d_ws;
        float* x    = ws;
        float* acts = ws + 8388608;
        float* asum = ws + 16777216;
        dim3 grid(64, 2, 16), blk(256, 1, 1);
        pw_conv_kernel<<<grid, blk, 0, stream>>>(input, w_in, b_in, x, 256, 0);
        for (int i = 0; i < 16; ++i) {
            int d = 1 << (i % 9);
            gated_conv_kernel<<<grid, blk, 0, stream>>>(
                x, dilate_w + (size_t)i * 256 * 128 * 2, dilate_b + i * 256, acts, d);
            actsum_kernel<<<dim3(2048), blk, 0, stream>>>(acts, asum + i * 2048);
            if (i < 15) {
                pw_conv_kernel<<<grid, blk, 0, stream>>>(
                    acts, res_w + (size_t)i * 128 * 128, res_b + i * 128, x, 128, 1);
            }
        }
        final_kernel<<<dim3(16), blk, 0, stream>>>(
            asum, skip_w, skip_b, w_out, lin_w, lin_b, out);
    }
}

// Round 11
// 774.515 us; speedup vs baseline: 1.7043x; 1.2833x over previous
//
#include <hip/hip_runtime.h>
#include <hip/hip_bf16.h>

// WaveNet forward on gfx950 — round 11.
// Gated GEMM consumes only Xhi (W bf16 · Xhi); x remains hi/lo in global so
// the residual stream keeps ~fp32 precision (error doesn't compound).
// Gated superchunk: stage {Whi 16K, Xhi 8K}, 1 MFMA phase. Res conv still
// 2-phase over acts hi/lo (LDS-resident, free).
// XCD-aware block remap: each XCD owns 2 batches x 32 contiguous t-tiles
// -> dilated-tap re-reads hit local L2 (2MB working set < 4MB L2/XCD).
// Residual epilogue coalesced via LDS (r10).
// Fallback (ws too small): round-1 fp32 VALU path.

#define KC 32

typedef __bf16 bf16_t;
typedef __bf16 bf16x4 __attribute__((ext_vector_type(4)));
typedef __bf16 bf16x8 __attribute__((ext_vector_type(8)));
typedef float f32x16 __attribute__((ext_vector_type(16)));

__device__ __align__(16) __bf16 g_wi_dev[32768];   // w_in bf16, swizzled
__device__ float g_pooled[4096];                    // [b][256] pooled skip

__device__ __forceinline__ void gl_lds16(const void* g, void* l) {
    __builtin_amdgcn_global_load_lds(
        (const __attribute__((address_space(1))) unsigned int*)g,
        (__attribute__((address_space(3))) unsigned int*)l, 16, 0, 0);
}

__device__ __forceinline__ float fast_sigmoid(float x) {
    float e = __builtin_amdgcn_exp2f(-1.4426950408889634f * x);
    return __builtin_amdgcn_rcpf(1.0f + e);
}
__device__ __forceinline__ float fast_tanh(float x) {
    float e = __builtin_amdgcn_exp2f(-2.8853900817779268f * x);
    return fmaf(2.0f, __builtin_amdgcn_rcpf(1.0f + e), -1.0f);
}

// ---------------- weight prep: bf16 quantize + swizzle ----------------
__global__ __launch_bounds__(256) void prep_wg_kernel(
    const float* __restrict__ dw, bf16_t* __restrict__ wg)
{
    int idx = blockIdx.x * 256 + threadIdx.x;   // 1,048,576
    int e = idx & 7, ps = (idx >> 3) & 3, row = (idx >> 5) & 255;
    int c = (idx >> 13) & 7, layer = idx >> 16;
    int s = ps ^ ((row >> 1) & 3);
    int k = c * 32 + s * 8 + e;
    int tap = k >> 7, ch = k & 127;
    wg[idx] = (bf16_t)dw[(((size_t)layer * 256 + row) * 128 + ch) * 2 + tap];
}

__global__ __launch_bounds__(256) void prep_wr_kernel(
    const float* __restrict__ rw, bf16_t* __restrict__ wr)
{
    int idx = blockIdx.x * 256 + threadIdx.x;   // 245,760 (15 layers)
    int e = idx & 7, ps = (idx >> 3) & 3, row = (idx >> 5) & 127;
    int c = (idx >> 12) & 3, layer = idx >> 14;
    int s = ps ^ ((row >> 1) & 3);
    int ch = c * 32 + s * 8 + e;
    wr[idx] = (bf16_t)rw[((size_t)layer * 128 + row) * 128 + ch];
}

__global__ __launch_bounds__(256) void prep_wi_kernel(const float* __restrict__ wi)
{
    int idx = blockIdx.x * 256 + threadIdx.x;   // 32,768
    int e = idx & 7, ps = (idx >> 3) & 3, row = (idx >> 5) & 127;
    int c = idx >> 12;
    int s = ps ^ ((row >> 1) & 3);
    int ch = c * 32 + s * 8 + e;
    g_wi_dev[idx] = (bf16_t)wi[(size_t)row * 256 + ch];
}

__global__ __launch_bounds__(256) void zero_misc_kernel(bf16_t* __restrict__ zeros)
{
    int idx = blockIdx.x * 256 + threadIdx.x;   // 32768
    zeros[idx] = (bf16_t)0.0f;
    if (idx < 4096) g_pooled[idx] = 0.0f;
}

// ---------------- input transpose: fp32 [ch][t] -> bf16 hi/lo [t][ch] ----------------
__global__ __launch_bounds__(256) void transpose_in(
    const float* __restrict__ input, bf16_t* __restrict__ th,
    bf16_t* __restrict__ tl, int b_off)
{
    __shared__ float Sl[64][65];
    const int tid = threadIdx.x;
    const int t0 = blockIdx.x * 64, ch0 = blockIdx.y * 64, bz = blockIdx.z;
    const int b = b_off + bz;
#pragma unroll
    for (int it = 0; it < 16; ++it) {
        int idx = it * 256 + tid;
        int t = idx & 63, ch = idx >> 6;
        Sl[ch][t] = input[((size_t)b * 256 + ch0 + ch) * 4096 + t0 + t];
    }
    __syncthreads();
#pragma unroll
    for (int it = 0; it < 16; ++it) {
        int idx = it * 256 + tid;
        int ch = idx & 63, t = idx >> 6;
        float v = Sl[ch][t];
        bf16_t hb = (bf16_t)v;
        size_t o = ((size_t)bz * 4096 + t0 + t) * 256 + ch0 + ch;
        th[o] = hb;
        tl[o] = (bf16_t)(v - (float)hb);
    }
}

// ---------------- fused layer: gated conv + acts + residual conv ----------------
// 512 threads (8 waves). LDS 80KB:
//   gated loop : Whi dbuf 2x16K [0,32K), Xhi dbuf 2x8K [32K,48K)
//   epilogue   : acts hi [0,32K), acts lo [32K,64K), resW dbuf 2x8K [64K,80K)
//   res epi    : xn hi [0,32K), xn lo [32K,64K)
__global__ __launch_bounds__(512, 4) void fused_layer(
    const bf16_t* __restrict__ xc_hi, const bf16_t* __restrict__ xc_lo,
    bf16_t* __restrict__ xn_hi, bf16_t* __restrict__ xn_lo,
    const bf16_t* __restrict__ zeros,
    const bf16_t* __restrict__ wg_l, const float* __restrict__ dbias,
    const bf16_t* __restrict__ wr_l, const float* __restrict__ rbias,
    float* __restrict__ asum_l, int d, int skipres)
{
    __shared__ __align__(16) char lds[81920];
    const int tid = threadIdx.x;
    const int wave = tid >> 6, lane = tid & 63;
    const int l31 = lane & 31, h = lane >> 5;
    const int wm = wave & 3, wn = wave >> 2;

    // XCD-aware remap: wg linear id -> (b, t_tile) so each XCD (wg&7) owns
    // 2 batches x 32 contiguous t-tiles (keeps dilated-tap reads in local L2).
    const int wg = blockIdx.x + 32 * blockIdx.z;   // 0..511, dispatch-linear
    const int xcd = wg & 7;
    const int idxin = wg >> 3;                      // 0..63
    const int b = (xcd << 1) | (idxin >> 5);
    const int t0 = (idxin & 31) * 128;

    f32x16 acc[2][2];
#pragma unroll
    for (int m = 0; m < 2; ++m)
#pragma unroll
        for (int n = 0; n < 2; ++n) acc[m][n] = (f32x16)(0.0f);

    const int t_pos = tid >> 2;
    const int s_x = (tid & 3) ^ ((t_pos >> 1) & 3);
    const int chx = s_x << 3;

    // 3 loads/thread per superchunk: 2x Whi, 1x Xhi
    auto stage_g = [&](int u, int sl) {
        const char* wsrc = (const char*)wg_l + (size_t)u * 16384;
        char* wdst = lds + sl * 16384;
        gl_lds16(wsrc + tid * 16, wdst + tid * 16);
        gl_lds16(wsrc + (tid + 512) * 16, wdst + (tid + 512) * 16);
        int tap = (u >> 2) & 1;
        int ch = ((u & 3) << 5) + chx;
        int tg = t0 + t_pos - (tap ? 0 : d);
        const bf16_t* sph = (tg >= 0)
            ? (xc_hi + ((size_t)b * 4096 + tg) * 128 + ch) : (zeros + ch);
        gl_lds16(sph, lds + 32768 + sl * 8192 + tid * 16);
    };

    stage_g(0, 0);
    const int swz = (l31 >> 1) & 3;
    int aoff[2][2], boff[2][2];
#pragma unroll
    for (int m = 0; m < 2; ++m)
#pragma unroll
        for (int s2 = 0; s2 < 2; ++s2)
            aoff[m][s2] = ((m ? 128 + wm * 32 : wm * 32) + l31) * 64 +
                          (((s2 * 2 + h) ^ swz) << 4);
#pragma unroll
    for (int n = 0; n < 2; ++n)
#pragma unroll
        for (int s2 = 0; s2 < 2; ++s2)
            boff[n][s2] = (wn * 64 + n * 32 + l31) * 64 + (((s2 * 2 + h) ^ swz) << 4);

    for (int u = 0; u < 8; ++u) {
        if (u < 7) {
            stage_g(u + 1, (u + 1) & 1);
            asm volatile("s_waitcnt vmcnt(3)" ::: "memory"); // chunk u's 3 landed
        } else {
            asm volatile("s_waitcnt vmcnt(0)" ::: "memory");
        }
        __builtin_amdgcn_s_barrier();

        const char* whb = lds + (u & 1) * 16384;
        const char* xhb = lds + 32768 + (u & 1) * 8192;
        bf16x8 a0[2], a1[2], b0[2], b1[2];
#pragma unroll
        for (int s2 = 0; s2 < 2; ++s2) {
            a0[s2] = *(const bf16x8*)(whb + aoff[0][s2]);
            a1[s2] = *(const bf16x8*)(whb + aoff[1][s2]);
            b0[s2] = *(const bf16x8*)(xhb + boff[0][s2]);
            b1[s2] = *(const bf16x8*)(xhb + boff[1][s2]);
        }
        __builtin_amdgcn_s_setprio(1);
#pragma unroll
        for (int s2 = 0; s2 < 2; ++s2) {
            acc[0][0] = __builtin_amdgcn_mfma_f32_32x32x16_bf16(a0[s2], b0[s2], acc[0][0], 0, 0, 0);
            acc[0][1] = __builtin_amdgcn_mfma_f32_32x32x16_bf16(a0[s2], b1[s2], acc[0][1], 0, 0, 0);
            acc[1][0] = __builtin_amdgcn_mfma_f32_32x32x16_bf16(a1[s2], b0[s2], acc[1][0], 0, 0, 0);
            acc[1][1] = __builtin_amdgcn_mfma_f32_32x32x16_bf16(a1[s2], b1[s2], acc[1][1], 0, 0, 0);
        }
        __builtin_amdgcn_s_setprio(0);
        __builtin_amdgcn_s_barrier();  // reads of slot u&1 retired -> restage safe
    }
    __syncthreads();

    // ---- acts epilogue ----
    auto stage_rw = [&](int c, int sl) {
        gl_lds16((const char*)wr_l + (size_t)c * 8192 + tid * 16,
                 lds + 65536 + sl * 8192 + tid * 16);
    };
    if (!skipres) stage_rw(0, 0);   // HBM latency hides under activation VALU

    float psum[16];
#pragma unroll
    for (int u = 0; u < 16; ++u) psum[u] = 0.0f;

#pragma unroll
    for (int n = 0; n < 2; ++n) {
        int t = wn * 64 + n * 32 + l31;
        int sw = (t & 7) << 4;
#pragma unroll
        for (int rg = 0; rg < 4; ++rg) {
            int ch0 = wm * 32 + rg * 8 + 4 * h;
            bf16x4 hv, lv;
#pragma unroll
            for (int j = 0; j < 4; ++j) {
                int r = rg * 4 + j;
                float a1v = acc[0][n][r] + dbias[ch0 + j];
                float a2v = acc[1][n][r] + dbias[128 + ch0 + j];
                float a = fast_tanh(a1v) * fast_sigmoid(a2v);
                psum[rg * 4 + j] += a;
                bf16_t hb = (bf16_t)a;
                hv[j] = hb;
                lv[j] = (bf16_t)(a - (float)hb);
            }
            int low = (t * 256 + ch0 * 2) ^ sw;
            *(bf16x4*)(lds + low) = hv;
            *(bf16x4*)(lds + 32768 + low) = lv;
        }
    }

#pragma unroll
    for (int u = 0; u < 16; ++u) {
        float v = psum[u];
        v += __shfl_xor(v, 1);
        v += __shfl_xor(v, 2);
        v += __shfl_xor(v, 4);
        v += __shfl_xor(v, 8);
        v += __shfl_xor(v, 16);
        psum[u] = v;
    }
    if (l31 == 0) {
#pragma unroll
        for (int u = 0; u < 16; ++u) {
            int ch = wm * 32 + (u >> 2) * 8 + 4 * h + (u & 3);
            atomicAdd(asum_l + b * 128 + ch, psum[u]);
        }
    }
    if (skipres) return;

    asm volatile("s_waitcnt lgkmcnt(0)" ::: "memory");
    __builtin_amdgcn_s_barrier();   // acts visible to all waves; resW c0 in flight

    // ---- residual K-loop: M=128 x N=128, 4 superchunks x 2 phases ----
    f32x16 accr[2];
    accr[0] = (f32x16)(0.0f);
    accr[1] = (f32x16)(0.0f);
    int tl_[2], mk_[2];
#pragma unroll
    for (int n = 0; n < 2; ++n) {
        tl_[n] = wn * 64 + n * 32 + l31;
        mk_[n] = (tl_[n] & 7) << 4;
    }

    for (int u = 0; u < 4; ++u) {
        if (u < 3) {
            stage_rw(u + 1, (u + 1) & 1);
            asm volatile("s_waitcnt vmcnt(1)" ::: "memory");
        } else {
            asm volatile("s_waitcnt vmcnt(0)" ::: "memory");
        }
        __builtin_amdgcn_s_barrier();

        const char* ab = lds + 65536 + (u & 1) * 8192;
        int cb = u << 6;
#pragma unroll
        for (int ph = 0; ph < 2; ++ph) {
            const char* bb = lds + (ph ? 32768 : 0);
            bf16x8 av[2], bv[2][2];
#pragma unroll
            for (int s2 = 0; s2 < 2; ++s2) {
                av[s2] = *(const bf16x8*)(ab + (wm * 32 + l31) * 64 +
                                          (((s2 * 2 + h) ^ swz) << 4));
#pragma unroll
                for (int n = 0; n < 2; ++n) {
                    int low = (cb + ((s2 * 2 + h) << 4)) ^ mk_[n];
                    bv[n][s2] = *(const bf16x8*)(bb + tl_[n] * 256 + low);
                }
            }
            __builtin_amdgcn_s_setprio(1);
#pragma unroll
            for (int s2 = 0; s2 < 2; ++s2) {
                accr[0] = __builtin_amdgcn_mfma_f32_32x32x16_bf16(av[s2], bv[0][s2], accr[0], 0, 0, 0);
                accr[1] = __builtin_amdgcn_mfma_f32_32x32x16_bf16(av[s2], bv[1][s2], accr[1], 0, 0, 0);
            }
            __builtin_amdgcn_s_setprio(0);
        }
        __builtin_amdgcn_s_barrier();
    }

    // ---- residual epilogue (coalesced via LDS) ----
#pragma unroll
    for (int n = 0; n < 2; ++n) {
        int t = tl_[n];
        int sw = (t & 7) << 4;
#pragma unroll
        for (int rg = 0; rg < 4; ++rg) {
            int ch0 = wm * 32 + rg * 8 + 4 * h;
            bf16x4 hv, lv;
#pragma unroll
            for (int j = 0; j < 4; ++j) {
                float v = accr[n][rg * 4 + j] + rbias[ch0 + j];
                bf16_t hb = (bf16_t)v;
                hv[j] = hb;
                lv[j] = (bf16_t)(v - (float)hb);
            }
            int low = (t * 256 + ch0 * 2) ^ sw;
            *(bf16x4*)(lds + low) = hv;
            *(bf16x4*)(lds + 32768 + low) = lv;
        }
    }
    __syncthreads();

#pragma unroll
    for (int it = 0; it < 4; ++it) {
        int g = it * 512 + tid;
        int byte = g * 16;
        int t = byte >> 8;
        int off = byte & 255;
        int phys = byte ^ ((t & 7) << 4);   // XOR preserves 16B chunks
        bf16x8 hv = *(const bf16x8*)(lds + phys);
        bf16x8 lv = *(const bf16x8*)(lds + 32768 + phys);
        size_t gofs = ((size_t)b * 4096 + t0 + t) * 256 + off;   // bytes
        bf16x8 oh = *(const bf16x8*)((const char*)xc_hi + gofs);
        bf16x8 ol = *(const bf16x8*)((const char*)xc_lo + gofs);
        bf16x8 nh, nl;
#pragma unroll
        for (int j = 0; j < 8; ++j) {
            float v = (float)hv[j] + (float)lv[j] + (float)oh[j] + (float)ol[j];
            bf16_t hb = (bf16_t)v;
            nh[j] = hb;
            nl[j] = (bf16_t)(v - (float)hb);
        }
        *(bf16x8*)((char*)xn_hi + gofs) = nh;
        *(bf16x8*)((char*)xn_lo + gofs) = nl;
    }
}

// ---------------- input pointwise MFMA (K=256 ch, 2 phases) ----------------
__global__ __launch_bounds__(256) void pw_mfma_in(
    const bf16_t* __restrict__ sh, const bf16_t* __restrict__ sl,
    const float* __restrict__ bias,
    bf16_t* __restrict__ xth, bf16_t* __restrict__ xtl, int b_off)
{
    __shared__ __align__(16) char lds[49152];
    const int tid = threadIdx.x;
    const int wave = tid >> 6, lane = tid & 63;
    const int l31 = lane & 31, h = lane >> 5;
    const int wm = wave & 1, wn = wave >> 1;
    const int t0 = blockIdx.x * 128;
    const int bz = blockIdx.z;
    const bf16_t* w = (const bf16_t*)g_wi_dev;

    f32x16 acc[2][2];
#pragma unroll
    for (int m = 0; m < 2; ++m)
#pragma unroll
        for (int n = 0; n < 2; ++n) acc[m][n] = (f32x16)(0.0f);

    auto stage = [&](int u, int sl_) {
        const char* wsrc = (const char*)w + (size_t)u * 8192;
        char* wdst = lds + sl_ * 8192;
        gl_lds16(wsrc + tid * 16, wdst + tid * 16);
        gl_lds16(wsrc + (tid + 256) * 16, wdst + (tid + 256) * 16);
#pragma unroll
        for (int it = 0; it < 2; ++it) {
            int row = (tid >> 2) + it * 64;
            int ps = tid & 3;
            int sx = ps ^ ((row >> 1) & 3);
            size_t gi = ((size_t)bz * 4096 + t0 + row) * 256 + u * 32 + sx * 8;
            gl_lds16(sh + gi, lds + 16384 + sl_ * 8192 + (row * 4 + ps) * 16);
            gl_lds16(sl + gi, lds + 32768 + sl_ * 8192 + (row * 4 + ps) * 16);
        }
    };

    stage(0, 0);
    const int swz = (l31 >> 1) & 3;
    int aoff[2][2], boff[2][2];
#pragma unroll
    for (int m = 0; m < 2; ++m)
#pragma unroll
        for (int s2 = 0; s2 < 2; ++s2)
            aoff[m][s2] = (wm * 64 + m * 32 + l31) * 64 + (((s2 * 2 + h) ^ swz) << 4);
#pragma unroll
    for (int n = 0; n < 2; ++n)
#pragma unroll
        for (int s2 = 0; s2 < 2; ++s2)
            boff[n][s2] = (wn * 64 + n * 32 + l31) * 64 + (((s2 * 2 + h) ^ swz) << 4);

    for (int u = 0; u < 8; ++u) {
        if (u < 7) {
            stage(u + 1, (u + 1) & 1);
            asm volatile("s_waitcnt vmcnt(6)" ::: "memory");
        } else {
            asm volatile("s_waitcnt vmcnt(0)" ::: "memory");
        }
        __builtin_amdgcn_s_barrier();

        const char* wb = lds + (u & 1) * 8192;
#pragma unroll
        for (int ph = 0; ph < 2; ++ph) {
            const char* xb = lds + (ph ? 32768 : 16384) + (u & 1) * 8192;
            bf16x8 a0[2], a1[2], b0[2], b1[2];
#pragma unroll
            for (int s2 = 0; s2 < 2; ++s2) {
                a0[s2] = *(const bf16x8*)(wb + aoff[0][s2]);
                a1[s2] = *(const bf16x8*)(wb + aoff[1][s2]);
                b0[s2] = *(const bf16x8*)(xb + boff[0][s2]);
                b1[s2] = *(const bf16x8*)(xb + boff[1][s2]);
            }
#pragma unroll
            for (int s2 = 0; s2 < 2; ++s2) {
                acc[0][0] = __builtin_amdgcn_mfma_f32_32x32x16_bf16(a0[s2], b0[s2], acc[0][0], 0, 0, 0);
                acc[0][1] = __builtin_amdgcn_mfma_f32_32x32x16_bf16(a0[s2], b1[s2], acc[0][1], 0, 0, 0);
                acc[1][0] = __builtin_amdgcn_mfma_f32_32x32x16_bf16(a1[s2], b0[s2], acc[1][0], 0, 0, 0);
                acc[1][1] = __builtin_amdgcn_mfma_f32_32x32x16_bf16(a1[s2], b1[s2], acc[1][1], 0, 0, 0);
            }
        }
        __builtin_amdgcn_s_barrier();
    }

    const int b = b_off + bz;
#pragma unroll
    for (int n = 0; n < 2; ++n) {
        int t = wn * 64 + n * 32 + l31;
        size_t trow = ((size_t)b * 4096 + t0 + t) * 128;
#pragma unroll
        for (int m = 0; m < 2; ++m) {
#pragma unroll
            for (int rg = 0; rg < 4; ++rg) {
                int ch0 = wm * 64 + m * 32 + rg * 8 + 4 * h;
                bf16x4 nh, nl;
#pragma unroll
                for (int j = 0; j < 4; ++j) {
                    float v = acc[m][n][rg * 4 + j] + bias[ch0 + j];
                    bf16_t hb = (bf16_t)v;
                    nh[j] = hb;
                    nl[j] = (bf16_t)(v - (float)hb);
                }
                *(bf16x4*)(xth + trow + ch0) = nh;
                *(bf16x4*)(xtl + trow + ch0) = nl;
            }
        }
    }
}

// ---------------- output head ----------------
__global__ __launch_bounds__(256) void skip_partial(
    const float* __restrict__ asum, const float* __restrict__ skip_w)
{
    const int i = blockIdx.x >> 4, b = blockIdx.x & 15, s = threadIdx.x;
    const float* sw = skip_w + ((size_t)i * 256 + s) * 128;
    const float* as = asum + i * 2048 + b * 128;
    float t = 0.0f;
#pragma unroll 8
    for (int r = 0; r < 128; ++r) t = fmaf(sw[r], as[r], t);
    atomicAdd(&g_pooled[b * 256 + s], t);
}

__global__ __launch_bounds__(256) void head_kernel(
    const float* __restrict__ skip_b, const float* __restrict__ w_out,
    const float* __restrict__ lin_w, const float* __restrict__ lin_b,
    float* __restrict__ out)
{
    const int b = blockIdx.x;
    const int s = threadIdx.x;
    float sb = 0.0f;
#pragma unroll
    for (int i = 0; i < 16; ++i) sb += skip_b[i * 256 + s];
    __shared__ float pl[256];
    pl[s] = g_pooled[b * 256 + s] * (1.0f / 4096.0f) + sb;
    __syncthreads();
    __shared__ float o1[12];
    if (s < 12) {
        float v = 0.0f;
        for (int q = 0; q < 256; ++q) v = fmaf(w_out[s * 256 + q], pl[q], v);
        o1[s] = v;
    }
    __syncthreads();
    if (s < 12) {
        float v = lin_b[s];
#pragma unroll
        for (int m = 0; m < 12; ++m) v = fmaf(lin_w[s * 12 + m], o1[m], v);
        out[b * 12 + s] = v;
    }
}

// ================= fallback fp32 path (round-1, proven) =================
__global__ __launch_bounds__(256) void pw_conv_kernel(
    const float* __restrict__ src, const float* __restrict__ W,
    const float* __restrict__ bias, float* __restrict__ dst,
    int K, int accumulate)
{
    __shared__ float Wl[KC][68];
    __shared__ float Sl[KC][68];
    const int tid = threadIdx.x;
    const int t0 = blockIdx.x * 64;
    const int row0 = blockIdx.y * 64;
    const int b = blockIdx.z;
    const int i4 = (tid >> 4) * 4;
    const int j4 = (tid & 15) * 4;
    float acc[4][4];
#pragma unroll
    for (int r = 0; r < 4; ++r) {
        float bv = bias[row0 + i4 + r];
#pragma unroll
        for (int c = 0; c < 4; ++c) acc[r][c] = bv;
    }
    const float* sb = src + (size_t)b * K * 4096;
    for (int k0 = 0; k0 < K; k0 += KC) {
        __syncthreads();
#pragma unroll
        for (int it = 0; it < 8; ++it) {
            int idx = it * 256 + tid;
            int kk = idx & 31, oo = idx >> 5;
            Wl[kk][oo] = W[(size_t)(row0 + oo) * K + (k0 + kk)];
        }
#pragma unroll
        for (int it = 0; it < 8; ++it) {
            int idx = it * 256 + tid;
            int t = idx & 63, kk = idx >> 6;
            Sl[kk][t] = sb[(size_t)(k0 + kk) * 4096 + t0 + t];
        }
        __syncthreads();
#pragma unroll
        for (int kk = 0; kk < KC; ++kk) {
            float4 wv = *(const float4*)&Wl[kk][i4];
            float4 sv = *(const float4*)&Sl[kk][j4];
            float wr_[4] = {wv.x, wv.y, wv.z, wv.w};
            float sc[4] = {sv.x, sv.y, sv.z, sv.w};
#pragma unroll
            for (int r = 0; r < 4; ++r)
#pragma unroll
                for (int c = 0; c < 4; ++c)
                    acc[r][c] = fmaf(wr_[r], sc[c], acc[r][c]);
        }
    }
    float* db = dst + (size_t)b * 128 * 4096;
#pragma unroll
    for (int r = 0; r < 4; ++r) {
        float* p = db + (size_t)(row0 + i4 + r) * 4096 + t0 + j4;
        float4 v;
        if (accumulate) {
            float4 old = *(const float4*)p;
            v.x = acc[r][0] + old.x; v.y = acc[r][1] + old.y;
            v.z = acc[r][2] + old.z; v.w = acc[r][3] + old.w;
        } else {
            v.x = acc[r][0]; v.y = acc[r][1]; v.z = acc[r][2]; v.w = acc[r][3];
        }
        *(float4*)p = v;
    }
}

__global__ __launch_bounds__(256) void gated_conv_kernel(
    const float* __restrict__ x, const float* __restrict__ Wd,
    const float* __restrict__ dbias, float* __restrict__ acts, int d)
{
    __shared__ float Wt0[KC][68], Wt1[KC][68], Ws0[KC][68], Ws1[KC][68];
    __shared__ float Sc[KC][68], Sp[KC][68];
    const int tid = threadIdx.x;
    const int t0 = blockIdx.x * 64;
    const int row0 = blockIdx.y * 64;
    const int b = blockIdx.z;
    const int i4 = (tid >> 4) * 4;
    const int j4 = (tid & 15) * 4;
    float a1[4][4], a2[4][4];
#pragma unroll
    for (int r = 0; r < 4; ++r) {
        float bt = dbias[row0 + i4 + r];
        float bs = dbias[128 + row0 + i4 + r];
#pragma unroll
        for (int c = 0; c < 4; ++c) { a1[r][c] = bt; a2[r][c] = bs; }
    }
    const float* xb = x + (size_t)b * 128 * 4096;
    for (int k0 = 0; k0 < 128; k0 += KC) {
        __syncthreads();
#pragma unroll
        for (int it = 0; it < 8; ++it) {
            int idx = it * 256 + tid;
            int kk = idx & 31, oo = idx >> 5;
            float2 wt = *(const float2*)(Wd + ((size_t)(row0 + oo) * 128 + (k0 + kk)) * 2);
            float2 ws = *(const float2*)(Wd + ((size_t)(128 + row0 + oo) * 128 + (k0 + kk)) * 2);
            Wt0[kk][oo] = wt.x; Wt1[kk][oo] = wt.y;
            Ws0[kk][oo] = ws.x; Ws1[kk][oo] = ws.y;
        }
#pragma unroll
        for (int it = 0; it < 8; ++it) {
            int idx = it * 256 + tid;
            int t = idx & 63, kk = idx >> 6;
            Sc[kk][t] = xb[(size_t)(k0 + kk) * 4096 + t0 + t];
            int gt = t0 + t - d;
            Sp[kk][t] = (gt >= 0) ? xb[(size_t)(k0 + kk) * 4096 + gt] : 0.0f;
        }
        __syncthreads();
#pragma unroll
        for (int kk = 0; kk < KC; ++kk) {
            float4 xcv4 = *(const float4*)&Sc[kk][j4];
            float4 xpv4 = *(const float4*)&Sp[kk][j4];
            float4 wt0 = *(const float4*)&Wt0[kk][i4];
            float4 wt1 = *(const float4*)&Wt1[kk][i4];
            float4 ws0 = *(const float4*)&Ws0[kk][i4];
            float4 ws1 = *(const float4*)&Ws1[kk][i4];
            float xc[4] = {xcv4.x, xcv4.y, xcv4.z, xcv4.w};
            float xp[4] = {xpv4.x, xpv4.y, xpv4.z, xpv4.w};
            float t0r[4] = {wt0.x, wt0.y, wt0.z, wt0.w};
            float t1r[4] = {wt1.x, wt1.y, wt1.z, wt1.w};
            float s0r[4] = {ws0.x, ws0.y, ws0.z, ws0.w};
            float s1r[4] = {ws1.x, ws1.y, ws1.z, ws1.w};
#pragma unroll
            for (int r = 0; r < 4; ++r)
#pragma unroll
                for (int c = 0; c < 4; ++c) {
                    a1[r][c] = fmaf(t0r[r], xp[c], a1[r][c]);
                    a1[r][c] = fmaf(t1r[r], xc[c], a1[r][c]);
                    a2[r][c] = fmaf(s0r[r], xp[c], a2[r][c]);
                    a2[r][c] = fmaf(s1r[r], xc[c], a2[r][c]);
                }
        }
    }
    float* ab = acts + (size_t)b * 128 * 4096;
#pragma unroll
    for (int r = 0; r < 4; ++r) {
        float4 v;
#pragma unroll
        for (int c = 0; c < 4; ++c) {
            float th = tanhf(a1[r][c]);
            float sg = 1.0f / (1.0f + expf(-a2[r][c]));
            ((float*)&v)[c] = th * sg;
        }
        *(float4*)&ab[(size_t)(row0 + i4 + r) * 4096 + t0 + j4] = v;
    }
}

__global__ __launch_bounds__(256) void actsum_kernel(
    const float* __restrict__ acts, float* __restrict__ out)
{
    const int br = blockIdx.x;
    const float* p = acts + (size_t)br * 4096;
    float s = 0.0f;
#pragma unroll
    for (int c = 0; c < 16; ++c) s += p[c * 256 + threadIdx.x];
    __shared__ float red[256];
    red[threadIdx.x] = s;
    __syncthreads();
    for (int off = 128; off > 0; off >>= 1) {
        if (threadIdx.x < off) red[threadIdx.x] += red[threadIdx.x + off];
        __syncthreads();
    }
    if (threadIdx.x == 0) out[br] = red[0];
}

__global__ __launch_bounds__(256) void final_kernel(
    const float* __restrict__ actsum, const float* __restrict__ skip_w,
    const float* __restrict__ skip_b, const float* __restrict__ w_out,
    const float* __restrict__ lin_w, const float* __restrict__ lin_b,
    float* __restrict__ out)
{
    const int b = blockIdx.x;
    const int s = threadIdx.x;
    float acc = 0.0f;
    for (int i = 0; i < 16; ++i) {
        const float* sw = skip_w + ((size_t)i * 256 + s) * 128;
        const float* as = actsum + ((size_t)i * 16 + b) * 128;
        float t = 0.0f;
#pragma unroll 8
        for (int r = 0; r < 128; ++r) t = fmaf(sw[r], as[r], t);
        acc += t;
    }
    float sb = 0.0f;
    for (int i = 0; i < 16; ++i) sb += skip_b[i * 256 + s];
    __shared__ float pl[256];
    pl[s] = acc * (1.0f / 4096.0f) + sb;
    __syncthreads();
    __shared__ float o1[12];
    if (s < 12) {
        float v = 0.0f;
        for (int qq = 0; qq < 256; ++qq) v = fmaf(w_out[s * 256 + qq], pl[qq], v);
        o1[s] = v;
    }
    __syncthreads();
    if (s < 12) {
        float v = lin_b[s];
#pragma unroll
        for (int m = 0; m < 12; ++m) v = fmaf(lin_w[s * 12 + m], o1[m], v);
        out[b * 12 + s] = v;
    }
}

// =======================================================================
extern "C" void kernel_launch(void* const* d_in, const int* in_sizes, int n_in,
                              void* d_out, int out_size, void* d_ws, size_t ws_size,
                              hipStream_t stream)
{
    const float* input    = (const float*)d_in[0];
    const float* w_in     = (const float*)d_in[1];
    const float* b_in     = (const float*)d_in[2];
    const float* dilate_w = (const float*)d_in[3];
    const float* dilate_b = (const float*)d_in[4];
    const float* res_w    = (const float*)d_in[5];
    const float* res_b    = (const float*)d_in[6];
    const float* skip_w   = (const float*)d_in[7];
    const float* skip_b   = (const float*)d_in[8];
    const float* w_out    = (const float*)d_in[9];
    const float* lin_w    = (const float*)d_in[10];
    const float* lin_b    = (const float*)d_in[11];
    float* out = (float*)d_out;

    const size_t NEED = 77103104ULL;
    if (ws_size >= NEED) {
        char* base = (char*)d_ws;
        bf16_t* xtA_hi = (bf16_t*)(base);                 // 16,777,216 B
        bf16_t* xtA_lo = (bf16_t*)(base + 16777216);      // 16,777,216 B
        bf16_t* xtB_hi = (bf16_t*)(base + 33554432);      // 16,777,216 B
        bf16_t* xtB_lo = (bf16_t*)(base + 50331648);      // 16,777,216 B
        bf16_t* wg     = (bf16_t*)(base + 67108864);      //  2,097,152 B
        bf16_t* wr     = (bf16_t*)(base + 69206016);      //    524,288 B
        float*  asum   = (float*)(base + 69730304);       //    131,072 B
        bf16_t* zeros  = (bf16_t*)(base + 69861376);      //     65,536 B

        hipMemsetAsync(asum, 0, 131072, stream);
        zero_misc_kernel<<<dim3(128), dim3(256), 0, stream>>>(zeros);
        prep_wg_kernel<<<dim3(4096), dim3(256), 0, stream>>>(dilate_w, wg);
        prep_wr_kernel<<<dim3(960), dim3(256), 0, stream>>>(res_w, wr);
        prep_wi_kernel<<<dim3(128), dim3(256), 0, stream>>>(w_in);

        // input conv in two 8-batch passes; xtB buffers as transpose scratch
        for (int pass = 0; pass < 2; ++pass) {
            transpose_in<<<dim3(64, 4, 8), dim3(256), 0, stream>>>(
                input, xtB_hi, xtB_lo, pass * 8);
            pw_mfma_in<<<dim3(32, 1, 8), dim3(256), 0, stream>>>(
                xtB_hi, xtB_lo, b_in, xtA_hi, xtA_lo, pass * 8);
        }

        for (int i = 0; i < 16; ++i) {
            int d = 1 << (i % 9);
            const bf16_t* xc_hi = (i & 1) ? xtB_hi : xtA_hi;
            const bf16_t* xc_lo = (i & 1) ? xtB_lo : xtA_lo;
            bf16_t* xn_hi = (i & 1) ? xtA_hi : xtB_hi;
            bf16_t* xn_lo = (i & 1) ? xtA_lo : xtB_lo;
            int skipres = (i == 15) ? 1 : 0;
            fused_layer<<<dim3(32, 1, 16), dim3(512), 0, stream>>>(
                xc_hi, xc_lo, xn_hi, xn_lo, zeros,
                wg + (size_t)i * 65536, dilate_b + i * 256,
                wr + (size_t)(skipres ? 0 : i) * 16384,
                res_b + (skipres ? 0 : i) * 128,
                asum + i * 2048, d, skipres);
        }
        skip_partial<<<dim3(256), dim3(256), 0, stream>>>(asum, skip_w);
        head_kernel<<<dim3(16), dim3(256), 0, stream>>>(
            skip_b, w_out, lin_w, lin_b, out);
    } else {
        // fallback: fp32 VALU path (round 1)
        float* ws   = (float*)d_ws;
        float* x    = ws;
        float* acts = ws + 8388608;
        float* asum = ws + 16777216;
        dim3 grid(64, 2, 16), blk(256, 1, 1);
        pw_conv_kernel<<<grid, blk, 0, stream>>>(input, w_in, b_in, x, 256, 0);
        for (int i = 0; i < 16; ++i) {
            int d = 1 << (i % 9);
            gated_conv_kernel<<<grid, blk, 0, stream>>>(
                x, dilate_w + (size_t)i * 256 * 128 * 2, dilate_b + i * 256, acts, d);
            actsum_kernel<<<dim3(2048), blk, 0, stream>>>(acts, asum + i * 2048);
            if (i < 15) {
                pw_conv_kernel<<<grid, blk, 0, stream>>>(
                    acts, res_w + (size_t)i * 128 * 128, res_b + i * 128, x, 128, 1);
            }
        }
        final_kernel<<<dim3(16), blk, 0, stream>>>(
            asum, skip_w, skip_b, w_out, lin_w, lin_b, out);
    }
}

// Round 12
// 486.519 us; speedup vs baseline: 2.7131x; 1.5920x over previous
//
#include <hip/hip_runtime.h>
#include <hip/hip_bf16.h>

// WaveNet forward on gfx950 — round 12.
// r11 + three fixes:
//  1) asum atomics -> LDS psum + coalesced plain store to per-(layer,b,tile)
//     partials (atomics counted toward vmcnt and stalled the res loop).
//  2) res weights (32KB) staged ONCE under activation VALU -> res K-loop is
//     barrier-free / vmcnt-free back-to-back MFMA.
//  3) acts quantized hi-only for the res GEMM (skip path stays fp32).
// Gated GEMM consumes Xhi only; x stays hi/lo in global (residual ~fp32).
// XCD-aware remap; coalesced residual epilogue via LDS.
// LDS 65KB: gated {Whi 2x16K [0,32K), Xhi 2x8K [32K,48K)};
// epilogue {acts-hi [0,32K), resW 32K [32K,64K), psum 1K [64K,65K)};
// res-epi {xn hi [0,32K), xn lo [32K,64K)}.
// Fallback (ws too small): round-1 fp32 VALU path.

#define KC 32

typedef __bf16 bf16_t;
typedef __bf16 bf16x4 __attribute__((ext_vector_type(4)));
typedef __bf16 bf16x8 __attribute__((ext_vector_type(8)));
typedef float f32x16 __attribute__((ext_vector_type(16)));

__device__ __align__(16) __bf16 g_wi_dev[32768];   // w_in bf16, swizzled
__device__ float g_pooled[4096];                    // [b][256] pooled skip

__device__ __forceinline__ void gl_lds16(const void* g, void* l) {
    __builtin_amdgcn_global_load_lds(
        (const __attribute__((address_space(1))) unsigned int*)g,
        (__attribute__((address_space(3))) unsigned int*)l, 16, 0, 0);
}

__device__ __forceinline__ float fast_sigmoid(float x) {
    float e = __builtin_amdgcn_exp2f(-1.4426950408889634f * x);
    return __builtin_amdgcn_rcpf(1.0f + e);
}
__device__ __forceinline__ float fast_tanh(float x) {
    float e = __builtin_amdgcn_exp2f(-2.8853900817779268f * x);
    return fmaf(2.0f, __builtin_amdgcn_rcpf(1.0f + e), -1.0f);
}

// ---------------- weight prep: bf16 quantize + swizzle ----------------
__global__ __launch_bounds__(256) void prep_wg_kernel(
    const float* __restrict__ dw, bf16_t* __restrict__ wg)
{
    int idx = blockIdx.x * 256 + threadIdx.x;   // 1,048,576
    int e = idx & 7, ps = (idx >> 3) & 3, row = (idx >> 5) & 255;
    int c = (idx >> 13) & 7, layer = idx >> 16;
    int s = ps ^ ((row >> 1) & 3);
    int k = c * 32 + s * 8 + e;
    int tap = k >> 7, ch = k & 127;
    wg[idx] = (bf16_t)dw[(((size_t)layer * 256 + row) * 128 + ch) * 2 + tap];
}

__global__ __launch_bounds__(256) void prep_wr_kernel(
    const float* __restrict__ rw, bf16_t* __restrict__ wr)
{
    int idx = blockIdx.x * 256 + threadIdx.x;   // 245,760 (15 layers)
    int e = idx & 7, ps = (idx >> 3) & 3, row = (idx >> 5) & 127;
    int c = (idx >> 12) & 3, layer = idx >> 14;
    int s = ps ^ ((row >> 1) & 3);
    int ch = c * 32 + s * 8 + e;
    wr[idx] = (bf16_t)rw[((size_t)layer * 128 + row) * 128 + ch];
}

__global__ __launch_bounds__(256) void prep_wi_kernel(const float* __restrict__ wi)
{
    int idx = blockIdx.x * 256 + threadIdx.x;   // 32,768
    int e = idx & 7, ps = (idx >> 3) & 3, row = (idx >> 5) & 127;
    int c = idx >> 12;
    int s = ps ^ ((row >> 1) & 3);
    int ch = c * 32 + s * 8 + e;
    g_wi_dev[idx] = (bf16_t)wi[(size_t)row * 256 + ch];
}

__global__ __launch_bounds__(256) void zero_misc_kernel(bf16_t* __restrict__ zeros)
{
    int idx = blockIdx.x * 256 + threadIdx.x;   // 32768
    zeros[idx] = (bf16_t)0.0f;
    if (idx < 4096) g_pooled[idx] = 0.0f;
}

// ---------------- input transpose: fp32 [ch][t] -> bf16 hi/lo [t][ch] ----------------
__global__ __launch_bounds__(256) void transpose_in(
    const float* __restrict__ input, bf16_t* __restrict__ th,
    bf16_t* __restrict__ tl, int b_off)
{
    __shared__ float Sl[64][65];
    const int tid = threadIdx.x;
    const int t0 = blockIdx.x * 64, ch0 = blockIdx.y * 64, bz = blockIdx.z;
    const int b = b_off + bz;
#pragma unroll
    for (int it = 0; it < 16; ++it) {
        int idx = it * 256 + tid;
        int t = idx & 63, ch = idx >> 6;
        Sl[ch][t] = input[((size_t)b * 256 + ch0 + ch) * 4096 + t0 + t];
    }
    __syncthreads();
#pragma unroll
    for (int it = 0; it < 16; ++it) {
        int idx = it * 256 + tid;
        int ch = idx & 63, t = idx >> 6;
        float v = Sl[ch][t];
        bf16_t hb = (bf16_t)v;
        size_t o = ((size_t)bz * 4096 + t0 + t) * 256 + ch0 + ch;
        th[o] = hb;
        tl[o] = (bf16_t)(v - (float)hb);
    }
}

// ---------------- fused layer: gated conv + acts + residual conv ----------------
__global__ __launch_bounds__(512, 4) void fused_layer(
    const bf16_t* __restrict__ xc_hi, const bf16_t* __restrict__ xc_lo,
    bf16_t* __restrict__ xn_hi, bf16_t* __restrict__ xn_lo,
    const bf16_t* __restrict__ zeros,
    const bf16_t* __restrict__ wg_l, const float* __restrict__ dbias,
    const bf16_t* __restrict__ wr_l, const float* __restrict__ rbias,
    float* __restrict__ asum_l, int d, int skipres)
{
    __shared__ __align__(16) char lds[66560];
    const int tid = threadIdx.x;
    const int wave = tid >> 6, lane = tid & 63;
    const int l31 = lane & 31, h = lane >> 5;
    const int wm = wave & 3, wn = wave >> 2;

    // XCD-aware remap: each XCD owns 2 batches x 32 contiguous t-tiles.
    const int wg = blockIdx.x + 32 * blockIdx.z;   // 0..511
    const int xcd = wg & 7;
    const int idxin = wg >> 3;                      // 0..63
    const int b = (xcd << 1) | (idxin >> 5);
    const int tile = idxin & 31;
    const int t0 = tile * 128;

    f32x16 acc[2][2];
#pragma unroll
    for (int m = 0; m < 2; ++m)
#pragma unroll
        for (int n = 0; n < 2; ++n) acc[m][n] = (f32x16)(0.0f);

    const int t_pos = tid >> 2;
    const int s_x = (tid & 3) ^ ((t_pos >> 1) & 3);
    const int chx = s_x << 3;

    // 3 loads/thread per superchunk: 2x Whi, 1x Xhi
    auto stage_g = [&](int u, int sl) {
        const char* wsrc = (const char*)wg_l + (size_t)u * 16384;
        char* wdst = lds + sl * 16384;
        gl_lds16(wsrc + tid * 16, wdst + tid * 16);
        gl_lds16(wsrc + (tid + 512) * 16, wdst + (tid + 512) * 16);
        int tap = (u >> 2) & 1;
        int ch = ((u & 3) << 5) + chx;
        int tg = t0 + t_pos - (tap ? 0 : d);
        const bf16_t* sph = (tg >= 0)
            ? (xc_hi + ((size_t)b * 4096 + tg) * 128 + ch) : (zeros + ch);
        gl_lds16(sph, lds + 32768 + sl * 8192 + tid * 16);
    };

    stage_g(0, 0);
    const int swz = (l31 >> 1) & 3;
    int aoff[2][2], boff[2][2];
#pragma unroll
    for (int m = 0; m < 2; ++m)
#pragma unroll
        for (int s2 = 0; s2 < 2; ++s2)
            aoff[m][s2] = ((m ? 128 + wm * 32 : wm * 32) + l31) * 64 +
                          (((s2 * 2 + h) ^ swz) << 4);
#pragma unroll
    for (int n = 0; n < 2; ++n)
#pragma unroll
        for (int s2 = 0; s2 < 2; ++s2)
            boff[n][s2] = (wn * 64 + n * 32 + l31) * 64 + (((s2 * 2 + h) ^ swz) << 4);

    for (int u = 0; u < 8; ++u) {
        if (u < 7) {
            stage_g(u + 1, (u + 1) & 1);
            asm volatile("s_waitcnt vmcnt(3)" ::: "memory");
        } else {
            asm volatile("s_waitcnt vmcnt(0)" ::: "memory");
        }
        __builtin_amdgcn_s_barrier();

        const char* whb = lds + (u & 1) * 16384;
        const char* xhb = lds + 32768 + (u & 1) * 8192;
        bf16x8 a0[2], a1[2], b0[2], b1[2];
#pragma unroll
        for (int s2 = 0; s2 < 2; ++s2) {
            a0[s2] = *(const bf16x8*)(whb + aoff[0][s2]);
            a1[s2] = *(const bf16x8*)(whb + aoff[1][s2]);
            b0[s2] = *(const bf16x8*)(xhb + boff[0][s2]);
            b1[s2] = *(const bf16x8*)(xhb + boff[1][s2]);
        }
        __builtin_amdgcn_s_setprio(1);
#pragma unroll
        for (int s2 = 0; s2 < 2; ++s2) {
            acc[0][0] = __builtin_amdgcn_mfma_f32_32x32x16_bf16(a0[s2], b0[s2], acc[0][0], 0, 0, 0);
            acc[0][1] = __builtin_amdgcn_mfma_f32_32x32x16_bf16(a0[s2], b1[s2], acc[0][1], 0, 0, 0);
            acc[1][0] = __builtin_amdgcn_mfma_f32_32x32x16_bf16(a1[s2], b0[s2], acc[1][0], 0, 0, 0);
            acc[1][1] = __builtin_amdgcn_mfma_f32_32x32x16_bf16(a1[s2], b1[s2], acc[1][1], 0, 0, 0);
        }
        __builtin_amdgcn_s_setprio(0);
        __builtin_amdgcn_s_barrier();
    }
    __syncthreads();

    // ---- acts epilogue ----
    // stage ALL res weights (32KB) once; they land under the activation VALU
    if (!skipres) {
#pragma unroll
        for (int r = 0; r < 4; ++r)
            gl_lds16((const char*)wr_l + (r * 512 + tid) * 16,
                     lds + 32768 + (r * 512 + tid) * 16);
    }

    float psum[16];
#pragma unroll
    for (int u = 0; u < 16; ++u) psum[u] = 0.0f;

#pragma unroll
    for (int n = 0; n < 2; ++n) {
        int t = wn * 64 + n * 32 + l31;
        int sw = (t & 7) << 4;
#pragma unroll
        for (int rg = 0; rg < 4; ++rg) {
            int ch0 = wm * 32 + rg * 8 + 4 * h;
            bf16x4 hv;
#pragma unroll
            for (int j = 0; j < 4; ++j) {
                int r = rg * 4 + j;
                float a1v = acc[0][n][r] + dbias[ch0 + j];
                float a2v = acc[1][n][r] + dbias[128 + ch0 + j];
                float a = fast_tanh(a1v) * fast_sigmoid(a2v);
                psum[rg * 4 + j] += a;
                hv[j] = (bf16_t)a;
            }
            int low = (t * 256 + ch0 * 2) ^ sw;
            *(bf16x4*)(lds + low) = hv;    // acts hi-only
        }
    }

#pragma unroll
    for (int u = 0; u < 16; ++u) {
        float v = psum[u];
        v += __shfl_xor(v, 1);
        v += __shfl_xor(v, 2);
        v += __shfl_xor(v, 4);
        v += __shfl_xor(v, 8);
        v += __shfl_xor(v, 16);
        psum[u] = v;
    }
    if (l31 == 0) {
        float* ps = (float*)(lds + 65536);
#pragma unroll
        for (int u = 0; u < 16; ++u) {
            int ch = wm * 32 + (u >> 2) * 8 + 4 * h + (u & 3);
            ps[wn * 128 + ch] = psum[u];
        }
    }

    asm volatile("s_waitcnt vmcnt(0) lgkmcnt(0)" ::: "memory");
    __builtin_amdgcn_s_barrier();   // acts + psum visible; resW landed

    // coalesced per-block partial store (replaces 16 contended atomics)
    if (tid < 128) {
        const float* ps = (const float*)(lds + 65536);
        asum_l[((size_t)b * 32 + tile) * 128 + tid] = ps[tid] + ps[128 + tid];
    }
    if (skipres) return;

    // ---- residual K-loop: all operands LDS-resident, no barriers ----
    f32x16 accr[2];
    accr[0] = (f32x16)(0.0f);
    accr[1] = (f32x16)(0.0f);
    int tl_[2], mk_[2];
#pragma unroll
    for (int n = 0; n < 2; ++n) {
        tl_[n] = wn * 64 + n * 32 + l31;
        mk_[n] = (tl_[n] & 7) << 4;
    }

    __builtin_amdgcn_s_setprio(1);
#pragma unroll
    for (int u = 0; u < 4; ++u) {
        const char* ab = lds + 32768 + u * 8192;
        int cb = u << 6;
        bf16x8 av[2], bv[2][2];
#pragma unroll
        for (int s2 = 0; s2 < 2; ++s2) {
            av[s2] = *(const bf16x8*)(ab + (wm * 32 + l31) * 64 +
                                      (((s2 * 2 + h) ^ swz) << 4));
#pragma unroll
            for (int n = 0; n < 2; ++n) {
                int low = (cb + ((s2 * 2 + h) << 4)) ^ mk_[n];
                bv[n][s2] = *(const bf16x8*)(lds + tl_[n] * 256 + low);
            }
        }
#pragma unroll
        for (int s2 = 0; s2 < 2; ++s2) {
            accr[0] = __builtin_amdgcn_mfma_f32_32x32x16_bf16(av[s2], bv[0][s2], accr[0], 0, 0, 0);
            accr[1] = __builtin_amdgcn_mfma_f32_32x32x16_bf16(av[s2], bv[1][s2], accr[1], 0, 0, 0);
        }
    }
    __builtin_amdgcn_s_setprio(0);
    __syncthreads();   // all waves' acts/resW reads retired before restaging

    // ---- residual epilogue (coalesced via LDS) ----
#pragma unroll
    for (int n = 0; n < 2; ++n) {
        int t = tl_[n];
        int sw = (t & 7) << 4;
#pragma unroll
        for (int rg = 0; rg < 4; ++rg) {
            int ch0 = wm * 32 + rg * 8 + 4 * h;
            bf16x4 hv, lv;
#pragma unroll
            for (int j = 0; j < 4; ++j) {
                float v = accr[n][rg * 4 + j] + rbias[ch0 + j];
                bf16_t hb = (bf16_t)v;
                hv[j] = hb;
                lv[j] = (bf16_t)(v - (float)hb);
            }
            int low = (t * 256 + ch0 * 2) ^ sw;
            *(bf16x4*)(lds + low) = hv;
            *(bf16x4*)(lds + 32768 + low) = lv;
        }
    }
    __syncthreads();

#pragma unroll
    for (int it = 0; it < 4; ++it) {
        int g = it * 512 + tid;
        int byte = g * 16;
        int t = byte >> 8;
        int off = byte & 255;
        int phys = byte ^ ((t & 7) << 4);
        bf16x8 hv = *(const bf16x8*)(lds + phys);
        bf16x8 lv = *(const bf16x8*)(lds + 32768 + phys);
        size_t gofs = ((size_t)b * 4096 + t0 + t) * 256 + off;
        bf16x8 oh = *(const bf16x8*)((const char*)xc_hi + gofs);
        bf16x8 ol = *(const bf16x8*)((const char*)xc_lo + gofs);
        bf16x8 nh, nl;
#pragma unroll
        for (int j = 0; j < 8; ++j) {
            float v = (float)hv[j] + (float)lv[j] + (float)oh[j] + (float)ol[j];
            bf16_t hb = (bf16_t)v;
            nh[j] = hb;
            nl[j] = (bf16_t)(v - (float)hb);
        }
        *(bf16x8*)((char*)xn_hi + gofs) = nh;
        *(bf16x8*)((char*)xn_lo + gofs) = nl;
    }
}

// ---------------- input pointwise MFMA (K=256 ch, 2 phases) ----------------
__global__ __launch_bounds__(256) void pw_mfma_in(
    const bf16_t* __restrict__ sh, const bf16_t* __restrict__ sl,
    const float* __restrict__ bias,
    bf16_t* __restrict__ xth, bf16_t* __restrict__ xtl, int b_off)
{
    __shared__ __align__(16) char lds[49152];
    const int tid = threadIdx.x;
    const int wave = tid >> 6, lane = tid & 63;
    const int l31 = lane & 31, h = lane >> 5;
    const int wm = wave & 1, wn = wave >> 1;
    const int t0 = blockIdx.x * 128;
    const int bz = blockIdx.z;
    const bf16_t* w = (const bf16_t*)g_wi_dev;

    f32x16 acc[2][2];
#pragma unroll
    for (int m = 0; m < 2; ++m)
#pragma unroll
        for (int n = 0; n < 2; ++n) acc[m][n] = (f32x16)(0.0f);

    auto stage = [&](int u, int sl_) {
        const char* wsrc = (const char*)w + (size_t)u * 8192;
        char* wdst = lds + sl_ * 8192;
        gl_lds16(wsrc + tid * 16, wdst + tid * 16);
        gl_lds16(wsrc + (tid + 256) * 16, wdst + (tid + 256) * 16);
#pragma unroll
        for (int it = 0; it < 2; ++it) {
            int row = (tid >> 2) + it * 64;
            int ps = tid & 3;
            int sx = ps ^ ((row >> 1) & 3);
            size_t gi = ((size_t)bz * 4096 + t0 + row) * 256 + u * 32 + sx * 8;
            gl_lds16(sh + gi, lds + 16384 + sl_ * 8192 + (row * 4 + ps) * 16);
            gl_lds16(sl + gi, lds + 32768 + sl_ * 8192 + (row * 4 + ps) * 16);
        }
    };

    stage(0, 0);
    const int swz = (l31 >> 1) & 3;
    int aoff[2][2], boff[2][2];
#pragma unroll
    for (int m = 0; m < 2; ++m)
#pragma unroll
        for (int s2 = 0; s2 < 2; ++s2)
            aoff[m][s2] = (wm * 64 + m * 32 + l31) * 64 + (((s2 * 2 + h) ^ swz) << 4);
#pragma unroll
    for (int n = 0; n < 2; ++n)
#pragma unroll
        for (int s2 = 0; s2 < 2; ++s2)
            boff[n][s2] = (wn * 64 + n * 32 + l31) * 64 + (((s2 * 2 + h) ^ swz) << 4);

    for (int u = 0; u < 8; ++u) {
        if (u < 7) {
            stage(u + 1, (u + 1) & 1);
            asm volatile("s_waitcnt vmcnt(6)" ::: "memory");
        } else {
            asm volatile("s_waitcnt vmcnt(0)" ::: "memory");
        }
        __builtin_amdgcn_s_barrier();

        const char* wb = lds + (u & 1) * 8192;
#pragma unroll
        for (int ph = 0; ph < 2; ++ph) {
            const char* xb = lds + (ph ? 32768 : 16384) + (u & 1) * 8192;
            bf16x8 a0[2], a1[2], b0[2], b1[2];
#pragma unroll
            for (int s2 = 0; s2 < 2; ++s2) {
                a0[s2] = *(const bf16x8*)(wb + aoff[0][s2]);
                a1[s2] = *(const bf16x8*)(wb + aoff[1][s2]);
                b0[s2] = *(const bf16x8*)(xb + boff[0][s2]);
                b1[s2] = *(const bf16x8*)(xb + boff[1][s2]);
            }
#pragma unroll
            for (int s2 = 0; s2 < 2; ++s2) {
                acc[0][0] = __builtin_amdgcn_mfma_f32_32x32x16_bf16(a0[s2], b0[s2], acc[0][0], 0, 0, 0);
                acc[0][1] = __builtin_amdgcn_mfma_f32_32x32x16_bf16(a0[s2], b1[s2], acc[0][1], 0, 0, 0);
                acc[1][0] = __builtin_amdgcn_mfma_f32_32x32x16_bf16(a1[s2], b0[s2], acc[1][0], 0, 0, 0);
                acc[1][1] = __builtin_amdgcn_mfma_f32_32x32x16_bf16(a1[s2], b1[s2], acc[1][1], 0, 0, 0);
            }
        }
        __builtin_amdgcn_s_barrier();
    }

    const int b = b_off + bz;
#pragma unroll
    for (int n = 0; n < 2; ++n) {
        int t = wn * 64 + n * 32 + l31;
        size_t trow = ((size_t)b * 4096 + t0 + t) * 128;
#pragma unroll
        for (int m = 0; m < 2; ++m) {
#pragma unroll
            for (int rg = 0; rg < 4; ++rg) {
                int ch0 = wm * 64 + m * 32 + rg * 8 + 4 * h;
                bf16x4 nh, nl;
#pragma unroll
                for (int j = 0; j < 4; ++j) {
                    float v = acc[m][n][rg * 4 + j] + bias[ch0 + j];
                    bf16_t hb = (bf16_t)v;
                    nh[j] = hb;
                    nl[j] = (bf16_t)(v - (float)hb);
                }
                *(bf16x4*)(xth + trow + ch0) = nh;
                *(bf16x4*)(xtl + trow + ch0) = nl;
            }
        }
    }
}

// ---------------- output head ----------------
__global__ __launch_bounds__(256) void skip_partial(
    const float* __restrict__ asum2, const float* __restrict__ skip_w)
{
    const int i = blockIdx.x >> 4, b = blockIdx.x & 15, s = threadIdx.x;
    __shared__ float as_[128];
    if (s < 128) {
        const float* p = asum2 + ((size_t)(i * 16 + b) * 32) * 128 + s;
        float v = 0.0f;
#pragma unroll
        for (int tl2 = 0; tl2 < 32; ++tl2) v += p[tl2 * 128];
        as_[s] = v;
    }
    __syncthreads();
    const float* sw = skip_w + ((size_t)i * 256 + s) * 128;
    float t = 0.0f;
#pragma unroll 8
    for (int r = 0; r < 128; ++r) t = fmaf(sw[r], as_[r], t);
    atomicAdd(&g_pooled[b * 256 + s], t);
}

__global__ __launch_bounds__(256) void head_kernel(
    const float* __restrict__ skip_b, const float* __restrict__ w_out,
    const float* __restrict__ lin_w, const float* __restrict__ lin_b,
    float* __restrict__ out)
{
    const int b = blockIdx.x;
    const int s = threadIdx.x;
    float sb = 0.0f;
#pragma unroll
    for (int i = 0; i < 16; ++i) sb += skip_b[i * 256 + s];
    __shared__ float pl[256];
    pl[s] = g_pooled[b * 256 + s] * (1.0f / 4096.0f) + sb;
    __syncthreads();
    __shared__ float o1[12];
    if (s < 12) {
        float v = 0.0f;
        for (int q = 0; q < 256; ++q) v = fmaf(w_out[s * 256 + q], pl[q], v);
        o1[s] = v;
    }
    __syncthreads();
    if (s < 12) {
        float v = lin_b[s];
#pragma unroll
        for (int m = 0; m < 12; ++m) v = fmaf(lin_w[s * 12 + m], o1[m], v);
        out[b * 12 + s] = v;
    }
}

// ================= fallback fp32 path (round-1, proven) =================
__global__ __launch_bounds__(256) void pw_conv_kernel(
    const float* __restrict__ src, const float* __restrict__ W,
    const float* __restrict__ bias, float* __restrict__ dst,
    int K, int accumulate)
{
    __shared__ float Wl[KC][68];
    __shared__ float Sl[KC][68];
    const int tid = threadIdx.x;
    const int t0 = blockIdx.x * 64;
    const int row0 = blockIdx.y * 64;
    const int b = blockIdx.z;
    const int i4 = (tid >> 4) * 4;
    const int j4 = (tid & 15) * 4;
    float acc[4][4];
#pragma unroll
    for (int r = 0; r < 4; ++r) {
        float bv = bias[row0 + i4 + r];
#pragma unroll
        for (int c = 0; c < 4; ++c) acc[r][c] = bv;
    }
    const float* sb = src + (size_t)b * K * 4096;
    for (int k0 = 0; k0 < K; k0 += KC) {
        __syncthreads();
#pragma unroll
        for (int it = 0; it < 8; ++it) {
            int idx = it * 256 + tid;
            int kk = idx & 31, oo = idx >> 5;
            Wl[kk][oo] = W[(size_t)(row0 + oo) * K + (k0 + kk)];
        }
#pragma unroll
        for (int it = 0; it < 8; ++it) {
            int idx = it * 256 + tid;
            int t = idx & 63, kk = idx >> 6;
            Sl[kk][t] = sb[(size_t)(k0 + kk) * 4096 + t0 + t];
        }
        __syncthreads();
#pragma unroll
        for (int kk = 0; kk < KC; ++kk) {
            float4 wv = *(const float4*)&Wl[kk][i4];
            float4 sv = *(const float4*)&Sl[kk][j4];
            float wr_[4] = {wv.x, wv.y, wv.z, wv.w};
            float sc[4] = {sv.x, sv.y, sv.z, sv.w};
#pragma unroll
            for (int r = 0; r < 4; ++r)
#pragma unroll
                for (int c = 0; c < 4; ++c)
                    acc[r][c] = fmaf(wr_[r], sc[c], acc[r][c]);
        }
    }
    float* db = dst + (size_t)b * 128 * 4096;
#pragma unroll
    for (int r = 0; r < 4; ++r) {
        float* p = db + (size_t)(row0 + i4 + r) * 4096 + t0 + j4;
        float4 v;
        if (accumulate) {
            float4 old = *(const float4*)p;
            v.x = acc[r][0] + old.x; v.y = acc[r][1] + old.y;
            v.z = acc[r][2] + old.z; v.w = acc[r][3] + old.w;
        } else {
            v.x = acc[r][0]; v.y = acc[r][1]; v.z = acc[r][2]; v.w = acc[r][3];
        }
        *(float4*)p = v;
    }
}

__global__ __launch_bounds__(256) void gated_conv_kernel(
    const float* __restrict__ x, const float* __restrict__ Wd,
    const float* __restrict__ dbias, float* __restrict__ acts, int d)
{
    __shared__ float Wt0[KC][68], Wt1[KC][68], Ws0[KC][68], Ws1[KC][68];
    __shared__ float Sc[KC][68], Sp[KC][68];
    const int tid = threadIdx.x;
    const int t0 = blockIdx.x * 64;
    const int row0 = blockIdx.y * 64;
    const int b = blockIdx.z;
    const int i4 = (tid >> 4) * 4;
    const int j4 = (tid & 15) * 4;
    float a1[4][4], a2[4][4];
#pragma unroll
    for (int r = 0; r < 4; ++r) {
        float bt = dbias[row0 + i4 + r];
        float bs = dbias[128 + row0 + i4 + r];
#pragma unroll
        for (int c = 0; c < 4; ++c) { a1[r][c] = bt; a2[r][c] = bs; }
    }
    const float* xb = x + (size_t)b * 128 * 4096;
    for (int k0 = 0; k0 < 128; k0 += KC) {
        __syncthreads();
#pragma unroll
        for (int it = 0; it < 8; ++it) {
            int idx = it * 256 + tid;
            int kk = idx & 31, oo = idx >> 5;
            float2 wt = *(const float2*)(Wd + ((size_t)(row0 + oo) * 128 + (k0 + kk)) * 2);
            float2 ws = *(const float2*)(Wd + ((size_t)(128 + row0 + oo) * 128 + (k0 + kk)) * 2);
            Wt0[kk][oo] = wt.x; Wt1[kk][oo] = wt.y;
            Ws0[kk][oo] = ws.x; Ws1[kk][oo] = ws.y;
        }
#pragma unroll
        for (int it = 0; it < 8; ++it) {
            int idx = it * 256 + tid;
            int t = idx & 63, kk = idx >> 6;
            Sc[kk][t] = xb[(size_t)(k0 + kk) * 4096 + t0 + t];
            int gt = t0 + t - d;
            Sp[kk][t] = (gt >= 0) ? xb[(size_t)(k0 + kk) * 4096 + gt] : 0.0f;
        }
        __syncthreads();
#pragma unroll
        for (int kk = 0; kk < KC; ++kk) {
            float4 xcv4 = *(const float4*)&Sc[kk][j4];
            float4 xpv4 = *(const float4*)&Sp[kk][j4];
            float4 wt0 = *(const float4*)&Wt0[kk][i4];
            float4 wt1 = *(const float4*)&Wt1[kk][i4];
            float4 ws0 = *(const float4*)&Ws0[kk][i4];
            float4 ws1 = *(const float4*)&Ws1[kk][i4];
            float xc[4] = {xcv4.x, xcv4.y, xcv4.z, xcv4.w};
            float xp[4] = {xpv4.x, xpv4.y, xpv4.z, xpv4.w};
            float t0r[4] = {wt0.x, wt0.y, wt0.z, wt0.w};
            float t1r[4] = {wt1.x, wt1.y, wt1.z, wt1.w};
            float s0r[4] = {ws0.x, ws0.y, ws0.z, ws0.w};
            float s1r[4] = {ws1.x, ws1.y, ws1.z, ws1.w};
#pragma unroll
            for (int r = 0; r < 4; ++r)
#pragma unroll
                for (int c = 0; c < 4; ++c) {
                    a1[r][c] = fmaf(t0r[r], xp[c], a1[r][c]);
                    a1[r][c] = fmaf(t1r[r], xc[c], a1[r][c]);
                    a2[r][c] = fmaf(s0r[r], xp[c], a2[r][c]);
                    a2[r][c] = fmaf(s1r[r], xc[c], a2[r][c]);
                }
        }
    }
    float* ab = acts + (size_t)b * 128 * 4096;
#pragma unroll
    for (int r = 0; r < 4; ++r) {
        float4 v;
#pragma unroll
        for (int c = 0; c < 4; ++c) {
            float th = tanhf(a1[r][c]);
            float sg = 1.0f / (1.0f + expf(-a2[r][c]));
            ((float*)&v)[c] = th * sg;
        }
        *(float4*)&ab[(size_t)(row0 + i4 + r) * 4096 + t0 + j4] = v;
    }
}

__global__ __launch_bounds__(256) void actsum_kernel(
    const float* __restrict__ acts, float* __restrict__ out)
{
    const int br = blockIdx.x;
    const float* p = acts + (size_t)br * 4096;
    float s = 0.0f;
#pragma unroll
    for (int c = 0; c < 16; ++c) s += p[c * 256 + threadIdx.x];
    __shared__ float red[256];
    red[threadIdx.x] = s;
    __syncthreads();
    for (int off = 128; off > 0; off >>= 1) {
        if (threadIdx.x < off) red[threadIdx.x] += red[threadIdx.x + off];
        __syncthreads();
    }
    if (threadIdx.x == 0) out[br] = red[0];
}

__global__ __launch_bounds__(256) void final_kernel(
    const float* __restrict__ actsum, const float* __restrict__ skip_w,
    const float* __restrict__ skip_b, const float* __restrict__ w_out,
    const float* __restrict__ lin_w, const float* __restrict__ lin_b,
    float* __restrict__ out)
{
    const int b = blockIdx.x;
    const int s = threadIdx.x;
    float acc = 0.0f;
    for (int i = 0; i < 16; ++i) {
        const float* sw = skip_w + ((size_t)i * 256 + s) * 128;
        const float* as = actsum + ((size_t)i * 16 + b) * 128;
        float t = 0.0f;
#pragma unroll 8
        for (int r = 0; r < 128; ++r) t = fmaf(sw[r], as[r], t);
        acc += t;
    }
    float sb = 0.0f;
    for (int i = 0; i < 16; ++i) sb += skip_b[i * 256 + s];
    __shared__ float pl[256];
    pl[s] = acc * (1.0f / 4096.0f) + sb;
    __syncthreads();
    __shared__ float o1[12];
    if (s < 12) {
        float v = 0.0f;
        for (int qq = 0; qq < 256; ++qq) v = fmaf(w_out[s * 256 + qq], pl[qq], v);
        o1[s] = v;
    }
    __syncthreads();
    if (s < 12) {
        float v = lin_b[s];
#pragma unroll
        for (int m = 0; m < 12; ++m) v = fmaf(lin_w[s * 12 + m], o1[m], v);
        out[b * 12 + s] = v;
    }
}

// =======================================================================
extern "C" void kernel_launch(void* const* d_in, const int* in_sizes, int n_in,
                              void* d_out, int out_size, void* d_ws, size_t ws_size,
                              hipStream_t stream)
{
    const float* input    = (const float*)d_in[0];
    const float* w_in     = (const float*)d_in[1];
    const float* b_in     = (const float*)d_in[2];
    const float* dilate_w = (const float*)d_in[3];
    const float* dilate_b = (const float*)d_in[4];
    const float* res_w    = (const float*)d_in[5];
    const float* res_b    = (const float*)d_in[6];
    const float* skip_w   = (const float*)d_in[7];
    const float* skip_b   = (const float*)d_in[8];
    const float* w_out    = (const float*)d_in[9];
    const float* lin_w    = (const float*)d_in[10];
    const float* lin_b    = (const float*)d_in[11];
    float* out = (float*)d_out;

    const size_t NEED = 77103104ULL;
    if (ws_size >= NEED) {
        char* base = (char*)d_ws;
        bf16_t* xtA_hi = (bf16_t*)(base);                 // 16,777,216 B
        bf16_t* xtA_lo = (bf16_t*)(base + 16777216);      // 16,777,216 B
        bf16_t* xtB_hi = (bf16_t*)(base + 33554432);      // 16,777,216 B
        bf16_t* xtB_lo = (bf16_t*)(base + 50331648);      // 16,777,216 B
        bf16_t* wg     = (bf16_t*)(base + 67108864);      //  2,097,152 B
        bf16_t* wr     = (bf16_t*)(base + 69206016);      //    524,288 B
        float*  asum2  = (float*)(base + 69730304);       //  4,194,304 B
        bf16_t* zeros  = (bf16_t*)(base + 73924608);      //     65,536 B

        zero_misc_kernel<<<dim3(128), dim3(256), 0, stream>>>(zeros);
        prep_wg_kernel<<<dim3(4096), dim3(256), 0, stream>>>(dilate_w, wg);
        prep_wr_kernel<<<dim3(960), dim3(256), 0, stream>>>(res_w, wr);
        prep_wi_kernel<<<dim3(128), dim3(256), 0, stream>>>(w_in);

        // input conv in two 8-batch passes; xtB buffers as transpose scratch
        for (int pass = 0; pass < 2; ++pass) {
            transpose_in<<<dim3(64, 4, 8), dim3(256), 0, stream>>>(
                input, xtB_hi, xtB_lo, pass * 8);
            pw_mfma_in<<<dim3(32, 1, 8), dim3(256), 0, stream>>>(
                xtB_hi, xtB_lo, b_in, xtA_hi, xtA_lo, pass * 8);
        }

        for (int i = 0; i < 16; ++i) {
            int d = 1 << (i % 9);
            const bf16_t* xc_hi = (i & 1) ? xtB_hi : xtA_hi;
            const bf16_t* xc_lo = (i & 1) ? xtB_lo : xtA_lo;
            bf16_t* xn_hi = (i & 1) ? xtA_hi : xtB_hi;
            bf16_t* xn_lo = (i & 1) ? xtA_lo : xtB_lo;
            int skipres = (i == 15) ? 1 : 0;
            fused_layer<<<dim3(32, 1, 16), dim3(512), 0, stream>>>(
                xc_hi, xc_lo, xn_hi, xn_lo, zeros,
                wg + (size_t)i * 65536, dilate_b + i * 256,
                wr + (size_t)(skipres ? 0 : i) * 16384,
                res_b + (skipres ? 0 : i) * 128,
                asum2 + (size_t)i * 65536, d, skipres);
        }
        skip_partial<<<dim3(256), dim3(256), 0, stream>>>(asum2, skip_w);
        head_kernel<<<dim3(16), dim3(256), 0, stream>>>(
            skip_b, w_out, lin_w, lin_b, out);
    } else {
        // fallback: fp32 VALU path (round 1)
        float* ws   = (float*)d_ws;
        float* x    = ws;
        float* acts = ws + 8388608;
        float* asum = ws + 16777216;
        dim3 grid(64, 2, 16), blk(256, 1, 1);
        pw_conv_kernel<<<grid, blk, 0, stream>>>(input, w_in, b_in, x, 256, 0);
        for (int i = 0; i < 16; ++i) {
            int d = 1 << (i % 9);
            gated_conv_kernel<<<grid, blk, 0, stream>>>(
                x, dilate_w + (size_t)i * 256 * 128 * 2, dilate_b + i * 256, acts, d);
            actsum_kernel<<<dim3(2048), blk, 0, stream>>>(acts, asum + i * 2048);
            if (i < 15) {
                pw_conv_kernel<<<grid, blk, 0, stream>>>(
                    acts, res_w + (size_t)i * 128 * 128, res_b + i * 128, x, 128, 1);
            }
        }
        final_kernel<<<dim3(16), blk, 0, stream>>>(
            asum, skip_w, skip_b, w_out, lin_w, lin_b, out);
    }
}

// Round 13
// 392.626 us; speedup vs baseline: 3.3619x; 1.2391x over previous
//
#include <hip/hip_runtime.h>
#include <hip/hip_bf16.h>

// WaveNet forward on gfx950 — round 13.
// Residual stream x is bf16 hi-only (per-t rounding errors cancel in the
// mean-pooled skip head; W-quant error dominates). Gated GEMM = Whi·Xhi.
// Gated K-loop: 8 superchunks {Whi 16K, Xhi 8K}, triple-buffered,
// prefetch distance 2 (vmcnt(6)). Res weights (32KB) staged once under the
// activation VALU -> barrier-free res K-loop. asum via LDS psum + plain
// coalesced partial store (no atomics). Coalesced res epilogue via LDS.
// XCD-aware block remap. Fallback (ws too small): round-1 fp32 VALU path.

#define KC 32

typedef __bf16 bf16_t;
typedef __bf16 bf16x4 __attribute__((ext_vector_type(4)));
typedef __bf16 bf16x8 __attribute__((ext_vector_type(8)));
typedef float f32x16 __attribute__((ext_vector_type(16)));

__device__ __align__(16) __bf16 g_wi_dev[32768];   // w_in bf16, swizzled
__device__ float g_pooled[4096];                    // [b][256] pooled skip

__device__ __forceinline__ void gl_lds16(const void* g, void* l) {
    __builtin_amdgcn_global_load_lds(
        (const __attribute__((address_space(1))) unsigned int*)g,
        (__attribute__((address_space(3))) unsigned int*)l, 16, 0, 0);
}

__device__ __forceinline__ float fast_sigmoid(float x) {
    float e = __builtin_amdgcn_exp2f(-1.4426950408889634f * x);
    return __builtin_amdgcn_rcpf(1.0f + e);
}
__device__ __forceinline__ float fast_tanh(float x) {
    float e = __builtin_amdgcn_exp2f(-2.8853900817779268f * x);
    return fmaf(2.0f, __builtin_amdgcn_rcpf(1.0f + e), -1.0f);
}

// ---------------- weight prep: bf16 quantize + swizzle ----------------
__global__ __launch_bounds__(256) void prep_wg_kernel(
    const float* __restrict__ dw, bf16_t* __restrict__ wg)
{
    int idx = blockIdx.x * 256 + threadIdx.x;   // 1,048,576
    int e = idx & 7, ps = (idx >> 3) & 3, row = (idx >> 5) & 255;
    int c = (idx >> 13) & 7, layer = idx >> 16;
    int s = ps ^ ((row >> 1) & 3);
    int k = c * 32 + s * 8 + e;
    int tap = k >> 7, ch = k & 127;
    wg[idx] = (bf16_t)dw[(((size_t)layer * 256 + row) * 128 + ch) * 2 + tap];
}

__global__ __launch_bounds__(256) void prep_wr_kernel(
    const float* __restrict__ rw, bf16_t* __restrict__ wr)
{
    int idx = blockIdx.x * 256 + threadIdx.x;   // 245,760 (15 layers)
    int e = idx & 7, ps = (idx >> 3) & 3, row = (idx >> 5) & 127;
    int c = (idx >> 12) & 3, layer = idx >> 14;
    int s = ps ^ ((row >> 1) & 3);
    int ch = c * 32 + s * 8 + e;
    wr[idx] = (bf16_t)rw[((size_t)layer * 128 + row) * 128 + ch];
}

__global__ __launch_bounds__(256) void prep_wi_kernel(const float* __restrict__ wi)
{
    int idx = blockIdx.x * 256 + threadIdx.x;   // 32,768
    int e = idx & 7, ps = (idx >> 3) & 3, row = (idx >> 5) & 127;
    int c = idx >> 12;
    int s = ps ^ ((row >> 1) & 3);
    int ch = c * 32 + s * 8 + e;
    g_wi_dev[idx] = (bf16_t)wi[(size_t)row * 256 + ch];
}

__global__ __launch_bounds__(256) void zero_misc_kernel(bf16_t* __restrict__ zeros)
{
    int idx = blockIdx.x * 256 + threadIdx.x;   // 32768
    zeros[idx] = (bf16_t)0.0f;
    if (idx < 4096) g_pooled[idx] = 0.0f;
}

// ---------------- input transpose: fp32 [ch][t] -> bf16 [t][ch] ----------------
__global__ __launch_bounds__(256) void transpose_in(
    const float* __restrict__ input, bf16_t* __restrict__ th, int b_off)
{
    __shared__ float Sl[64][65];
    const int tid = threadIdx.x;
    const int t0 = blockIdx.x * 64, ch0 = blockIdx.y * 64, bz = blockIdx.z;
    const int b = b_off + bz;
#pragma unroll
    for (int it = 0; it < 16; ++it) {
        int idx = it * 256 + tid;
        int t = idx & 63, ch = idx >> 6;
        Sl[ch][t] = input[((size_t)b * 256 + ch0 + ch) * 4096 + t0 + t];
    }
    __syncthreads();
#pragma unroll
    for (int it = 0; it < 16; ++it) {
        int idx = it * 256 + tid;
        int ch = idx & 63, t = idx >> 6;
        th[((size_t)bz * 4096 + t0 + t) * 256 + ch0 + ch] = (bf16_t)Sl[ch][t];
    }
}

// ---------------- fused layer: gated conv + acts + residual conv ----------------
// 512 threads (8 waves). LDS 72KB:
//   gated loop : Whi 3x16K [0,49152), Xhi 3x8K [49152,73728)
//   epilogue   : acts hi [0,32K), resW 32K [32K,64K), psum 1K [64K,65K)
//   res epi    : xn hi [0,32K)
__global__ __launch_bounds__(512, 4) void fused_layer(
    const bf16_t* __restrict__ xc, bf16_t* __restrict__ xn,
    const bf16_t* __restrict__ zeros,
    const bf16_t* __restrict__ wg_l, const float* __restrict__ dbias,
    const bf16_t* __restrict__ wr_l, const float* __restrict__ rbias,
    float* __restrict__ asum_l, int d, int skipres)
{
    __shared__ __align__(16) char lds[73728];
    const int tid = threadIdx.x;
    const int wave = tid >> 6, lane = tid & 63;
    const int l31 = lane & 31, h = lane >> 5;
    const int wm = wave & 3, wn = wave >> 2;

    // XCD-aware remap: each XCD owns 2 batches x 32 contiguous t-tiles.
    const int wg = blockIdx.x + 32 * blockIdx.z;   // 0..511
    const int xcd = wg & 7;
    const int idxin = wg >> 3;                      // 0..63
    const int b = (xcd << 1) | (idxin >> 5);
    const int tile = idxin & 31;
    const int t0 = tile * 128;

    f32x16 acc[2][2];
#pragma unroll
    for (int m = 0; m < 2; ++m)
#pragma unroll
        for (int n = 0; n < 2; ++n) acc[m][n] = (f32x16)(0.0f);

    const int t_pos = tid >> 2;
    const int s_x = (tid & 3) ^ ((t_pos >> 1) & 3);
    const int chx = s_x << 3;

    // 3 loads/thread per superchunk: 2x Whi, 1x Xhi
    auto stage_g = [&](int u) {
        int sl = u % 3;
        const char* wsrc = (const char*)wg_l + (size_t)u * 16384;
        char* wdst = lds + sl * 16384;
        gl_lds16(wsrc + tid * 16, wdst + tid * 16);
        gl_lds16(wsrc + (tid + 512) * 16, wdst + (tid + 512) * 16);
        int tap = (u >> 2) & 1;
        int ch = ((u & 3) << 5) + chx;
        int tg = t0 + t_pos - (tap ? 0 : d);
        const bf16_t* sph = (tg >= 0)
            ? (xc + ((size_t)b * 4096 + tg) * 128 + ch) : (zeros + ch);
        gl_lds16(sph, lds + 49152 + sl * 8192 + tid * 16);
    };

    stage_g(0);
    stage_g(1);
    const int swz = (l31 >> 1) & 3;
    int aoff[2][2], boff[2][2];
#pragma unroll
    for (int m = 0; m < 2; ++m)
#pragma unroll
        for (int s2 = 0; s2 < 2; ++s2)
            aoff[m][s2] = ((m ? 128 + wm * 32 : wm * 32) + l31) * 64 +
                          (((s2 * 2 + h) ^ swz) << 4);
#pragma unroll
    for (int n = 0; n < 2; ++n)
#pragma unroll
        for (int s2 = 0; s2 < 2; ++s2)
            boff[n][s2] = (wn * 64 + n * 32 + l31) * 64 + (((s2 * 2 + h) ^ swz) << 4);

    for (int u = 0; u < 8; ++u) {
        if (u < 6) {
            stage_g(u + 2);
            asm volatile("s_waitcnt vmcnt(6)" ::: "memory"); // chunk u landed
        } else if (u < 7) {
            asm volatile("s_waitcnt vmcnt(3)" ::: "memory");
        } else {
            asm volatile("s_waitcnt vmcnt(0)" ::: "memory");
        }
        __builtin_amdgcn_s_barrier();

        const char* whb = lds + (u % 3) * 16384;
        const char* xhb = lds + 49152 + (u % 3) * 8192;
        bf16x8 a0[2], a1[2], b0[2], b1[2];
#pragma unroll
        for (int s2 = 0; s2 < 2; ++s2) {
            a0[s2] = *(const bf16x8*)(whb + aoff[0][s2]);
            a1[s2] = *(const bf16x8*)(whb + aoff[1][s2]);
            b0[s2] = *(const bf16x8*)(xhb + boff[0][s2]);
            b1[s2] = *(const bf16x8*)(xhb + boff[1][s2]);
        }
        __builtin_amdgcn_s_setprio(1);
#pragma unroll
        for (int s2 = 0; s2 < 2; ++s2) {
            acc[0][0] = __builtin_amdgcn_mfma_f32_32x32x16_bf16(a0[s2], b0[s2], acc[0][0], 0, 0, 0);
            acc[0][1] = __builtin_amdgcn_mfma_f32_32x32x16_bf16(a0[s2], b1[s2], acc[0][1], 0, 0, 0);
            acc[1][0] = __builtin_amdgcn_mfma_f32_32x32x16_bf16(a1[s2], b0[s2], acc[1][0], 0, 0, 0);
            acc[1][1] = __builtin_amdgcn_mfma_f32_32x32x16_bf16(a1[s2], b1[s2], acc[1][1], 0, 0, 0);
        }
        __builtin_amdgcn_s_setprio(0);
        __builtin_amdgcn_s_barrier();  // reads of slot u%3 retired -> restage safe
    }
    __syncthreads();

    // ---- acts epilogue ----
    // stage ALL res weights (32KB) once; they land under the activation VALU
    if (!skipres) {
#pragma unroll
        for (int r = 0; r < 4; ++r)
            gl_lds16((const char*)wr_l + (r * 512 + tid) * 16,
                     lds + 32768 + (r * 512 + tid) * 16);
    }

    float psum[16];
#pragma unroll
    for (int u = 0; u < 16; ++u) psum[u] = 0.0f;

#pragma unroll
    for (int n = 0; n < 2; ++n) {
        int t = wn * 64 + n * 32 + l31;
        int sw = (t & 7) << 4;
#pragma unroll
        for (int rg = 0; rg < 4; ++rg) {
            int ch0 = wm * 32 + rg * 8 + 4 * h;
            bf16x4 hv;
#pragma unroll
            for (int j = 0; j < 4; ++j) {
                int r = rg * 4 + j;
                float a1v = acc[0][n][r] + dbias[ch0 + j];
                float a2v = acc[1][n][r] + dbias[128 + ch0 + j];
                float a = fast_tanh(a1v) * fast_sigmoid(a2v);
                psum[rg * 4 + j] += a;
                hv[j] = (bf16_t)a;
            }
            int low = (t * 256 + ch0 * 2) ^ sw;
            *(bf16x4*)(lds + low) = hv;    // acts hi-only
        }
    }

#pragma unroll
    for (int u = 0; u < 16; ++u) {
        float v = psum[u];
        v += __shfl_xor(v, 1);
        v += __shfl_xor(v, 2);
        v += __shfl_xor(v, 4);
        v += __shfl_xor(v, 8);
        v += __shfl_xor(v, 16);
        psum[u] = v;
    }
    if (l31 == 0) {
        float* ps = (float*)(lds + 65536);
#pragma unroll
        for (int u = 0; u < 16; ++u) {
            int ch = wm * 32 + (u >> 2) * 8 + 4 * h + (u & 3);
            ps[wn * 128 + ch] = psum[u];
        }
    }

    asm volatile("s_waitcnt vmcnt(0) lgkmcnt(0)" ::: "memory");
    __builtin_amdgcn_s_barrier();   // acts + psum visible; resW landed

    // coalesced per-block partial store (no atomics)
    if (tid < 128) {
        const float* ps = (const float*)(lds + 65536);
        asum_l[((size_t)b * 32 + tile) * 128 + tid] = ps[tid] + ps[128 + tid];
    }
    if (skipres) return;

    // ---- residual K-loop: all operands LDS-resident, no barriers ----
    f32x16 accr[2];
    accr[0] = (f32x16)(0.0f);
    accr[1] = (f32x16)(0.0f);
    int tl_[2], mk_[2];
#pragma unroll
    for (int n = 0; n < 2; ++n) {
        tl_[n] = wn * 64 + n * 32 + l31;
        mk_[n] = (tl_[n] & 7) << 4;
    }

    __builtin_amdgcn_s_setprio(1);
#pragma unroll
    for (int u = 0; u < 4; ++u) {
        const char* ab = lds + 32768 + u * 8192;
        int cb = u << 6;
        bf16x8 av[2], bv[2][2];
#pragma unroll
        for (int s2 = 0; s2 < 2; ++s2) {
            av[s2] = *(const bf16x8*)(ab + (wm * 32 + l31) * 64 +
                                      (((s2 * 2 + h) ^ swz) << 4));
#pragma unroll
            for (int n = 0; n < 2; ++n) {
                int low = (cb + ((s2 * 2 + h) << 4)) ^ mk_[n];
                bv[n][s2] = *(const bf16x8*)(lds + tl_[n] * 256 + low);
            }
        }
#pragma unroll
        for (int s2 = 0; s2 < 2; ++s2) {
            accr[0] = __builtin_amdgcn_mfma_f32_32x32x16_bf16(av[s2], bv[0][s2], accr[0], 0, 0, 0);
            accr[1] = __builtin_amdgcn_mfma_f32_32x32x16_bf16(av[s2], bv[1][s2], accr[1], 0, 0, 0);
        }
    }
    __builtin_amdgcn_s_setprio(0);
    __syncthreads();   // all waves' acts/resW reads retired before restaging

    // ---- residual epilogue (coalesced via LDS, hi-only) ----
#pragma unroll
    for (int n = 0; n < 2; ++n) {
        int t = tl_[n];
        int sw = (t & 7) << 4;
#pragma unroll
        for (int rg = 0; rg < 4; ++rg) {
            int ch0 = wm * 32 + rg * 8 + 4 * h;
            bf16x4 hv;
#pragma unroll
            for (int j = 0; j < 4; ++j)
                hv[j] = (bf16_t)(accr[n][rg * 4 + j] + rbias[ch0 + j]);
            int low = (t * 256 + ch0 * 2) ^ sw;
            *(bf16x4*)(lds + low) = hv;
        }
    }
    __syncthreads();

#pragma unroll
    for (int it = 0; it < 4; ++it) {
        int g = it * 512 + tid;
        int byte = g * 16;
        int t = byte >> 8;
        int off = byte & 255;
        int phys = byte ^ ((t & 7) << 4);
        bf16x8 hv = *(const bf16x8*)(lds + phys);
        size_t gofs = ((size_t)b * 4096 + t0 + t) * 256 + off;   // bytes
        bf16x8 oh = *(const bf16x8*)((const char*)xc + gofs);
        bf16x8 nh;
#pragma unroll
        for (int j = 0; j < 8; ++j)
            nh[j] = (bf16_t)((float)hv[j] + (float)oh[j]);
        *(bf16x8*)((char*)xn + gofs) = nh;
    }
}

// ---------------- input pointwise MFMA (K=256 ch, single phase) ----------------
// LDS 32KB: W dbuf 2x8K [0,16K), X dbuf 2x8K [16K,32K).
__global__ __launch_bounds__(256) void pw_mfma_in(
    const bf16_t* __restrict__ sh, const float* __restrict__ bias,
    bf16_t* __restrict__ xth, int b_off)
{
    __shared__ __align__(16) char lds[32768];
    const int tid = threadIdx.x;
    const int wave = tid >> 6, lane = tid & 63;
    const int l31 = lane & 31, h = lane >> 5;
    const int wm = wave & 1, wn = wave >> 1;
    const int t0 = blockIdx.x * 128;
    const int bz = blockIdx.z;
    const bf16_t* w = (const bf16_t*)g_wi_dev;

    f32x16 acc[2][2];
#pragma unroll
    for (int m = 0; m < 2; ++m)
#pragma unroll
        for (int n = 0; n < 2; ++n) acc[m][n] = (f32x16)(0.0f);

    auto stage = [&](int u, int sl_) {
        const char* wsrc = (const char*)w + (size_t)u * 8192;
        char* wdst = lds + sl_ * 8192;
        gl_lds16(wsrc + tid * 16, wdst + tid * 16);
        gl_lds16(wsrc + (tid + 256) * 16, wdst + (tid + 256) * 16);
#pragma unroll
        for (int it = 0; it < 2; ++it) {
            int row = (tid >> 2) + it * 64;
            int ps = tid & 3;
            int sx = ps ^ ((row >> 1) & 3);
            size_t gi = ((size_t)bz * 4096 + t0 + row) * 256 + u * 32 + sx * 8;
            gl_lds16(sh + gi, lds + 16384 + sl_ * 8192 + (row * 4 + ps) * 16);
        }
    };

    stage(0, 0);
    const int swz = (l31 >> 1) & 3;
    int aoff[2][2], boff[2][2];
#pragma unroll
    for (int m = 0; m < 2; ++m)
#pragma unroll
        for (int s2 = 0; s2 < 2; ++s2)
            aoff[m][s2] = (wm * 64 + m * 32 + l31) * 64 + (((s2 * 2 + h) ^ swz) << 4);
#pragma unroll
    for (int n = 0; n < 2; ++n)
#pragma unroll
        for (int s2 = 0; s2 < 2; ++s2)
            boff[n][s2] = (wn * 64 + n * 32 + l31) * 64 + (((s2 * 2 + h) ^ swz) << 4);

    for (int u = 0; u < 8; ++u) {
        if (u < 7) {
            stage(u + 1, (u + 1) & 1);
            asm volatile("s_waitcnt vmcnt(4)" ::: "memory");
        } else {
            asm volatile("s_waitcnt vmcnt(0)" ::: "memory");
        }
        __builtin_amdgcn_s_barrier();

        const char* wb = lds + (u & 1) * 8192;
        const char* xb = lds + 16384 + (u & 1) * 8192;
        bf16x8 a0[2], a1[2], b0[2], b1[2];
#pragma unroll
        for (int s2 = 0; s2 < 2; ++s2) {
            a0[s2] = *(const bf16x8*)(wb + aoff[0][s2]);
            a1[s2] = *(const bf16x8*)(wb + aoff[1][s2]);
            b0[s2] = *(const bf16x8*)(xb + boff[0][s2]);
            b1[s2] = *(const bf16x8*)(xb + boff[1][s2]);
        }
#pragma unroll
        for (int s2 = 0; s2 < 2; ++s2) {
            acc[0][0] = __builtin_amdgcn_mfma_f32_32x32x16_bf16(a0[s2], b0[s2], acc[0][0], 0, 0, 0);
            acc[0][1] = __builtin_amdgcn_mfma_f32_32x32x16_bf16(a0[s2], b1[s2], acc[0][1], 0, 0, 0);
            acc[1][0] = __builtin_amdgcn_mfma_f32_32x32x16_bf16(a1[s2], b0[s2], acc[1][0], 0, 0, 0);
            acc[1][1] = __builtin_amdgcn_mfma_f32_32x32x16_bf16(a1[s2], b1[s2], acc[1][1], 0, 0, 0);
        }
        __builtin_amdgcn_s_barrier();
    }

    const int b = b_off + bz;
#pragma unroll
    for (int n = 0; n < 2; ++n) {
        int t = wn * 64 + n * 32 + l31;
        size_t trow = ((size_t)b * 4096 + t0 + t) * 128;
#pragma unroll
        for (int m = 0; m < 2; ++m) {
#pragma unroll
            for (int rg = 0; rg < 4; ++rg) {
                int ch0 = wm * 64 + m * 32 + rg * 8 + 4 * h;
                bf16x4 nh;
#pragma unroll
                for (int j = 0; j < 4; ++j)
                    nh[j] = (bf16_t)(acc[m][n][rg * 4 + j] + bias[ch0 + j]);
                *(bf16x4*)(xth + trow + ch0) = nh;
            }
        }
    }
}

// ---------------- output head ----------------
__global__ __launch_bounds__(256) void skip_partial(
    const float* __restrict__ asum2, const float* __restrict__ skip_w)
{
    const int i = blockIdx.x >> 4, b = blockIdx.x & 15, s = threadIdx.x;
    __shared__ float as_[128];
    if (s < 128) {
        const float* p = asum2 + ((size_t)(i * 16 + b) * 32) * 128 + s;
        float v = 0.0f;
#pragma unroll
        for (int tl2 = 0; tl2 < 32; ++tl2) v += p[tl2 * 128];
        as_[s] = v;
    }
    __syncthreads();
    const float* sw = skip_w + ((size_t)i * 256 + s) * 128;
    float t = 0.0f;
#pragma unroll 8
    for (int r = 0; r < 128; ++r) t = fmaf(sw[r], as_[r], t);
    atomicAdd(&g_pooled[b * 256 + s], t);
}

__global__ __launch_bounds__(256) void head_kernel(
    const float* __restrict__ skip_b, const float* __restrict__ w_out,
    const float* __restrict__ lin_w, const float* __restrict__ lin_b,
    float* __restrict__ out)
{
    const int b = blockIdx.x;
    const int s = threadIdx.x;
    float sb = 0.0f;
#pragma unroll
    for (int i = 0; i < 16; ++i) sb += skip_b[i * 256 + s];
    __shared__ float pl[256];
    pl[s] = g_pooled[b * 256 + s] * (1.0f / 4096.0f) + sb;
    __syncthreads();
    __shared__ float o1[12];
    if (s < 12) {
        float v = 0.0f;
        for (int q = 0; q < 256; ++q) v = fmaf(w_out[s * 256 + q], pl[q], v);
        o1[s] = v;
    }
    __syncthreads();
    if (s < 12) {
        float v = lin_b[s];
#pragma unroll
        for (int m = 0; m < 12; ++m) v = fmaf(lin_w[s * 12 + m], o1[m], v);
        out[b * 12 + s] = v;
    }
}

// ================= fallback fp32 path (round-1, proven) =================
__global__ __launch_bounds__(256) void pw_conv_kernel(
    const float* __restrict__ src, const float* __restrict__ W,
    const float* __restrict__ bias, float* __restrict__ dst,
    int K, int accumulate)
{
    __shared__ float Wl[KC][68];
    __shared__ float Sl[KC][68];
    const int tid = threadIdx.x;
    const int t0 = blockIdx.x * 64;
    const int row0 = blockIdx.y * 64;
    const int b = blockIdx.z;
    const int i4 = (tid >> 4) * 4;
    const int j4 = (tid & 15) * 4;
    float acc[4][4];
#pragma unroll
    for (int r = 0; r < 4; ++r) {
        float bv = bias[row0 + i4 + r];
#pragma unroll
        for (int c = 0; c < 4; ++c) acc[r][c] = bv;
    }
    const float* sb = src + (size_t)b * K * 4096;
    for (int k0 = 0; k0 < K; k0 += KC) {
        __syncthreads();
#pragma unroll
        for (int it = 0; it < 8; ++it) {
            int idx = it * 256 + tid;
            int kk = idx & 31, oo = idx >> 5;
            Wl[kk][oo] = W[(size_t)(row0 + oo) * K + (k0 + kk)];
        }
#pragma unroll
        for (int it = 0; it < 8; ++it) {
            int idx = it * 256 + tid;
            int t = idx & 63, kk = idx >> 6;
            Sl[kk][t] = sb[(size_t)(k0 + kk) * 4096 + t0 + t];
        }
        __syncthreads();
#pragma unroll
        for (int kk = 0; kk < KC; ++kk) {
            float4 wv = *(const float4*)&Wl[kk][i4];
            float4 sv = *(const float4*)&Sl[kk][j4];
            float wr_[4] = {wv.x, wv.y, wv.z, wv.w};
            float sc[4] = {sv.x, sv.y, sv.z, sv.w};
#pragma unroll
            for (int r = 0; r < 4; ++r)
#pragma unroll
                for (int c = 0; c < 4; ++c)
                    acc[r][c] = fmaf(wr_[r], sc[c], acc[r][c]);
        }
    }
    float* db = dst + (size_t)b * 128 * 4096;
#pragma unroll
    for (int r = 0; r < 4; ++r) {
        float* p = db + (size_t)(row0 + i4 + r) * 4096 + t0 + j4;
        float4 v;
        if (accumulate) {
            float4 old = *(const float4*)p;
            v.x = acc[r][0] + old.x; v.y = acc[r][1] + old.y;
            v.z = acc[r][2] + old.z; v.w = acc[r][3] + old.w;
        } else {
            v.x = acc[r][0]; v.y = acc[r][1]; v.z = acc[r][2]; v.w = acc[r][3];
        }
        *(float4*)p = v;
    }
}

__global__ __launch_bounds__(256) void gated_conv_kernel(
    const float* __restrict__ x, const float* __restrict__ Wd,
    const float* __restrict__ dbias, float* __restrict__ acts, int d)
{
    __shared__ float Wt0[KC][68], Wt1[KC][68], Ws0[KC][68], Ws1[KC][68];
    __shared__ float Sc[KC][68], Sp[KC][68];
    const int tid = threadIdx.x;
    const int t0 = blockIdx.x * 64;
    const int row0 = blockIdx.y * 64;
    const int b = blockIdx.z;
    const int i4 = (tid >> 4) * 4;
    const int j4 = (tid & 15) * 4;
    float a1[4][4], a2[4][4];
#pragma unroll
    for (int r = 0; r < 4; ++r) {
        float bt = dbias[row0 + i4 + r];
        float bs = dbias[128 + row0 + i4 + r];
#pragma unroll
        for (int c = 0; c < 4; ++c) { a1[r][c] = bt; a2[r][c] = bs; }
    }
    const float* xb = x + (size_t)b * 128 * 4096;
    for (int k0 = 0; k0 < 128; k0 += KC) {
        __syncthreads();
#pragma unroll
        for (int it = 0; it < 8; ++it) {
            int idx = it * 256 + tid;
            int kk = idx & 31, oo = idx >> 5;
            float2 wt = *(const float2*)(Wd + ((size_t)(row0 + oo) * 128 + (k0 + kk)) * 2);
            float2 ws = *(const float2*)(Wd + ((size_t)(128 + row0 + oo) * 128 + (k0 + kk)) * 2);
            Wt0[kk][oo] = wt.x; Wt1[kk][oo] = wt.y;
            Ws0[kk][oo] = ws.x; Ws1[kk][oo] = ws.y;
        }
#pragma unroll
        for (int it = 0; it < 8; ++it) {
            int idx = it * 256 + tid;
            int t = idx & 63, kk = idx >> 6;
            Sc[kk][t] = xb[(size_t)(k0 + kk) * 4096 + t0 + t];
            int gt = t0 + t - d;
            Sp[kk][t] = (gt >= 0) ? xb[(size_t)(k0 + kk) * 4096 + gt] : 0.0f;
        }
        __syncthreads();
#pragma unroll
        for (int kk = 0; kk < KC; ++kk) {
            float4 xcv4 = *(const float4*)&Sc[kk][j4];
            float4 xpv4 = *(const float4*)&Sp[kk][j4];
            float4 wt0 = *(const float4*)&Wt0[kk][i4];
            float4 wt1 = *(const float4*)&Wt1[kk][i4];
            float4 ws0 = *(const float4*)&Ws0[kk][i4];
            float4 ws1 = *(const float4*)&Ws1[kk][i4];
            float xc[4] = {xcv4.x, xcv4.y, xcv4.z, xcv4.w};
            float xp[4] = {xpv4.x, xpv4.y, xpv4.z, xpv4.w};
            float t0r[4] = {wt0.x, wt0.y, wt0.z, wt0.w};
            float t1r[4] = {wt1.x, wt1.y, wt1.z, wt1.w};
            float s0r[4] = {ws0.x, ws0.y, ws0.z, ws0.w};
            float s1r[4] = {ws1.x, ws1.y, ws1.z, ws1.w};
#pragma unroll
            for (int r = 0; r < 4; ++r)
#pragma unroll
                for (int c = 0; c < 4; ++c) {
                    a1[r][c] = fmaf(t0r[r], xp[c], a1[r][c]);
                    a1[r][c] = fmaf(t1r[r], xc[c], a1[r][c]);
                    a2[r][c] = fmaf(s0r[r], xp[c], a2[r][c]);
                    a2[r][c] = fmaf(s1r[r], xc[c], a2[r][c]);
                }
        }
    }
    float* ab = acts + (size_t)b * 128 * 4096;
#pragma unroll
    for (int r = 0; r < 4; ++r) {
        float4 v;
#pragma unroll
        for (int c = 0; c < 4; ++c) {
            float th = tanhf(a1[r][c]);
            float sg = 1.0f / (1.0f + expf(-a2[r][c]));
            ((float*)&v)[c] = th * sg;
        }
        *(float4*)&ab[(size_t)(row0 + i4 + r) * 4096 + t0 + j4] = v;
    }
}

__global__ __launch_bounds__(256) void actsum_kernel(
    const float* __restrict__ acts, float* __restrict__ out)
{
    const int br = blockIdx.x;
    const float* p = acts + (size_t)br * 4096;
    float s = 0.0f;
#pragma unroll
    for (int c = 0; c < 16; ++c) s += p[c * 256 + threadIdx.x];
    __shared__ float red[256];
    red[threadIdx.x] = s;
    __syncthreads();
    for (int off = 128; off > 0; off >>= 1) {
        if (threadIdx.x < off) red[threadIdx.x] += red[threadIdx.x + off];
        __syncthreads();
    }
    if (threadIdx.x == 0) out[br] = red[0];
}

__global__ __launch_bounds__(256) void final_kernel(
    const float* __restrict__ actsum, const float* __restrict__ skip_w,
    const float* __restrict__ skip_b, const float* __restrict__ w_out,
    const float* __restrict__ lin_w, const float* __restrict__ lin_b,
    float* __restrict__ out)
{
    const int b = blockIdx.x;
    const int s = threadIdx.x;
    float acc = 0.0f;
    for (int i = 0; i < 16; ++i) {
        const float* sw = skip_w + ((size_t)i * 256 + s) * 128;
        const float* as = actsum + ((size_t)i * 16 + b) * 128;
        float t = 0.0f;
#pragma unroll 8
        for (int r = 0; r < 128; ++r) t = fmaf(sw[r], as[r], t);
        acc += t;
    }
    float sb = 0.0f;
    for (int i = 0; i < 16; ++i) sb += skip_b[i * 256 + s];
    __shared__ float pl[256];
    pl[s] = acc * (1.0f / 4096.0f) + sb;
    __syncthreads();
    __shared__ float o1[12];
    if (s < 12) {
        float v = 0.0f;
        for (int qq = 0; qq < 256; ++qq) v = fmaf(w_out[s * 256 + qq], pl[qq], v);
        o1[s] = v;
    }
    __syncthreads();
    if (s < 12) {
        float v = lin_b[s];
#pragma unroll
        for (int m = 0; m < 12; ++m) v = fmaf(lin_w[s * 12 + m], o1[m], v);
        out[b * 12 + s] = v;
    }
}

// =======================================================================
extern "C" void kernel_launch(void* const* d_in, const int* in_sizes, int n_in,
                              void* d_out, int out_size, void* d_ws, size_t ws_size,
                              hipStream_t stream)
{
    const float* input    = (const float*)d_in[0];
    const float* w_in     = (const float*)d_in[1];
    const float* b_in     = (const float*)d_in[2];
    const float* dilate_w = (const float*)d_in[3];
    const float* dilate_b = (const float*)d_in[4];
    const float* res_w    = (const float*)d_in[5];
    const float* res_b    = (const float*)d_in[6];
    const float* skip_w   = (const float*)d_in[7];
    const float* skip_b   = (const float*)d_in[8];
    const float* w_out    = (const float*)d_in[9];
    const float* lin_w    = (const float*)d_in[10];
    const float* lin_b    = (const float*)d_in[11];
    float* out = (float*)d_out;

    const size_t NEED = 77103104ULL;
    if (ws_size >= NEED) {
        char* base = (char*)d_ws;
        bf16_t* xtA   = (bf16_t*)(base);                 // 16,777,216 B
        bf16_t* xtB   = (bf16_t*)(base + 16777216);      // 16,777,216 B (also transpose scratch)
        bf16_t* wg    = (bf16_t*)(base + 33554432);      //  2,097,152 B
        bf16_t* wr    = (bf16_t*)(base + 35651584);      //    524,288 B
        float*  asum2 = (float*)(base + 36175872);       //  4,194,304 B
        bf16_t* zeros = (bf16_t*)(base + 40370176);      //     65,536 B

        zero_misc_kernel<<<dim3(128), dim3(256), 0, stream>>>(zeros);
        prep_wg_kernel<<<dim3(4096), dim3(256), 0, stream>>>(dilate_w, wg);
        prep_wr_kernel<<<dim3(960), dim3(256), 0, stream>>>(res_w, wr);
        prep_wi_kernel<<<dim3(128), dim3(256), 0, stream>>>(w_in);

        // input conv in two 8-batch passes; xtB as transpose scratch
        for (int pass = 0; pass < 2; ++pass) {
            transpose_in<<<dim3(64, 4, 8), dim3(256), 0, stream>>>(
                input, xtB, pass * 8);
            pw_mfma_in<<<dim3(32, 1, 8), dim3(256), 0, stream>>>(
                xtB, b_in, xtA, pass * 8);
        }

        for (int i = 0; i < 16; ++i) {
            int d = 1 << (i % 9);
            const bf16_t* xc = (i & 1) ? xtB : xtA;
            bf16_t* xn = (i & 1) ? xtA : xtB;
            int skipres = (i == 15) ? 1 : 0;
            fused_layer<<<dim3(32, 1, 16), dim3(512), 0, stream>>>(
                xc, xn, zeros,
                wg + (size_t)i * 65536, dilate_b + i * 256,
                wr + (size_t)(skipres ? 0 : i) * 16384,
                res_b + (skipres ? 0 : i) * 128,
                asum2 + (size_t)i * 65536, d, skipres);
        }
        skip_partial<<<dim3(256), dim3(256), 0, stream>>>(asum2, skip_w);
        head_kernel<<<dim3(16), dim3(256), 0, stream>>>(
            skip_b, w_out, lin_w, lin_b, out);
    } else {
        // fallback: fp32 VALU path (round 1)
        float* ws   = (float*)d_ws;
        float* x    = ws;
        float* acts = ws + 8388608;
        float* asum = ws + 16777216;
        dim3 grid(64, 2, 16), blk(256, 1, 1);
        pw_conv_kernel<<<grid, blk, 0, stream>>>(input, w_in, b_in, x, 256, 0);
        for (int i = 0; i < 16; ++i) {
            int d = 1 << (i % 9);
            gated_conv_kernel<<<grid, blk, 0, stream>>>(
                x, dilate_w + (size_t)i * 256 * 128 * 2, dilate_b + i * 256, acts, d);
            actsum_kernel<<<dim3(2048), blk, 0, stream>>>(acts, asum + i * 2048);
            if (i < 15) {
                pw_conv_kernel<<<grid, blk, 0, stream>>>(
                    acts, res_w + (size_t)i * 128 * 128, res_b + i * 128, x, 128, 1);
            }
        }
        final_kernel<<<dim3(16), blk, 0, stream>>>(
            asum, skip_w, skip_b, w_out, lin_w, lin_b, out);
    }
}

// Round 16
// 391.364 us; speedup vs baseline: 3.3728x; 1.0032x over previous
//
#include <hip/hip_runtime.h>
#include <hip/hip_bf16.h>

// WaveNet forward on gfx950 — round 16 (byte-exact revert to round 13,
// the artifact that passed full validation incl. post-timing at 392.6 us).
// Residual stream x is bf16 hi-only (per-t rounding errors cancel in the
// mean-pooled skip head; W-quant error dominates). Gated GEMM = Whi·Xhi.
// Gated K-loop: 8 superchunks {Whi 16K, Xhi 8K}, triple-buffered,
// prefetch distance 2 (vmcnt(6)). Res weights (32KB) staged once under the
// activation VALU -> barrier-free res K-loop. asum via LDS psum + plain
// coalesced partial store (no atomics). Coalesced res epilogue via LDS.
// XCD-aware block remap. Fallback (ws too small): round-1 fp32 VALU path.

#define KC 32

typedef __bf16 bf16_t;
typedef __bf16 bf16x4 __attribute__((ext_vector_type(4)));
typedef __bf16 bf16x8 __attribute__((ext_vector_type(8)));
typedef float f32x16 __attribute__((ext_vector_type(16)));

__device__ __align__(16) __bf16 g_wi_dev[32768];   // w_in bf16, swizzled
__device__ float g_pooled[4096];                    // [b][256] pooled skip

__device__ __forceinline__ void gl_lds16(const void* g, void* l) {
    __builtin_amdgcn_global_load_lds(
        (const __attribute__((address_space(1))) unsigned int*)g,
        (__attribute__((address_space(3))) unsigned int*)l, 16, 0, 0);
}

__device__ __forceinline__ float fast_sigmoid(float x) {
    float e = __builtin_amdgcn_exp2f(-1.4426950408889634f * x);
    return __builtin_amdgcn_rcpf(1.0f + e);
}
__device__ __forceinline__ float fast_tanh(float x) {
    float e = __builtin_amdgcn_exp2f(-2.8853900817779268f * x);
    return fmaf(2.0f, __builtin_amdgcn_rcpf(1.0f + e), -1.0f);
}

// ---------------- weight prep: bf16 quantize + swizzle ----------------
__global__ __launch_bounds__(256) void prep_wg_kernel(
    const float* __restrict__ dw, bf16_t* __restrict__ wg)
{
    int idx = blockIdx.x * 256 + threadIdx.x;   // 1,048,576
    int e = idx & 7, ps = (idx >> 3) & 3, row = (idx >> 5) & 255;
    int c = (idx >> 13) & 7, layer = idx >> 16;
    int s = ps ^ ((row >> 1) & 3);
    int k = c * 32 + s * 8 + e;
    int tap = k >> 7, ch = k & 127;
    wg[idx] = (bf16_t)dw[(((size_t)layer * 256 + row) * 128 + ch) * 2 + tap];
}

__global__ __launch_bounds__(256) void prep_wr_kernel(
    const float* __restrict__ rw, bf16_t* __restrict__ wr)
{
    int idx = blockIdx.x * 256 + threadIdx.x;   // 245,760 (15 layers)
    int e = idx & 7, ps = (idx >> 3) & 3, row = (idx >> 5) & 127;
    int c = (idx >> 12) & 3, layer = idx >> 14;
    int s = ps ^ ((row >> 1) & 3);
    int ch = c * 32 + s * 8 + e;
    wr[idx] = (bf16_t)rw[((size_t)layer * 128 + row) * 128 + ch];
}

__global__ __launch_bounds__(256) void prep_wi_kernel(const float* __restrict__ wi)
{
    int idx = blockIdx.x * 256 + threadIdx.x;   // 32,768
    int e = idx & 7, ps = (idx >> 3) & 3, row = (idx >> 5) & 127;
    int c = idx >> 12;
    int s = ps ^ ((row >> 1) & 3);
    int ch = c * 32 + s * 8 + e;
    g_wi_dev[idx] = (bf16_t)wi[(size_t)row * 256 + ch];
}

__global__ __launch_bounds__(256) void zero_misc_kernel(bf16_t* __restrict__ zeros)
{
    int idx = blockIdx.x * 256 + threadIdx.x;   // 32768
    zeros[idx] = (bf16_t)0.0f;
    if (idx < 4096) g_pooled[idx] = 0.0f;
}

// ---------------- input transpose: fp32 [ch][t] -> bf16 [t][ch] ----------------
__global__ __launch_bounds__(256) void transpose_in(
    const float* __restrict__ input, bf16_t* __restrict__ th, int b_off)
{
    __shared__ float Sl[64][65];
    const int tid = threadIdx.x;
    const int t0 = blockIdx.x * 64, ch0 = blockIdx.y * 64, bz = blockIdx.z;
    const int b = b_off + bz;
#pragma unroll
    for (int it = 0; it < 16; ++it) {
        int idx = it * 256 + tid;
        int t = idx & 63, ch = idx >> 6;
        Sl[ch][t] = input[((size_t)b * 256 + ch0 + ch) * 4096 + t0 + t];
    }
    __syncthreads();
#pragma unroll
    for (int it = 0; it < 16; ++it) {
        int idx = it * 256 + tid;
        int ch = idx & 63, t = idx >> 6;
        th[((size_t)bz * 4096 + t0 + t) * 256 + ch0 + ch] = (bf16_t)Sl[ch][t];
    }
}

// ---------------- fused layer: gated conv + acts + residual conv ----------------
// 512 threads (8 waves). LDS 72KB:
//   gated loop : Whi 3x16K [0,49152), Xhi 3x8K [49152,73728)
//   epilogue   : acts hi [0,32K), resW 32K [32K,64K), psum 1K [64K,65K)
//   res epi    : xn hi [0,32K)
__global__ __launch_bounds__(512, 4) void fused_layer(
    const bf16_t* __restrict__ xc, bf16_t* __restrict__ xn,
    const bf16_t* __restrict__ zeros,
    const bf16_t* __restrict__ wg_l, const float* __restrict__ dbias,
    const bf16_t* __restrict__ wr_l, const float* __restrict__ rbias,
    float* __restrict__ asum_l, int d, int skipres)
{
    __shared__ __align__(16) char lds[73728];
    const int tid = threadIdx.x;
    const int wave = tid >> 6, lane = tid & 63;
    const int l31 = lane & 31, h = lane >> 5;
    const int wm = wave & 3, wn = wave >> 2;

    // XCD-aware remap: each XCD owns 2 batches x 32 contiguous t-tiles.
    const int wg = blockIdx.x + 32 * blockIdx.z;   // 0..511
    const int xcd = wg & 7;
    const int idxin = wg >> 3;                      // 0..63
    const int b = (xcd << 1) | (idxin >> 5);
    const int tile = idxin & 31;
    const int t0 = tile * 128;

    f32x16 acc[2][2];
#pragma unroll
    for (int m = 0; m < 2; ++m)
#pragma unroll
        for (int n = 0; n < 2; ++n) acc[m][n] = (f32x16)(0.0f);

    const int t_pos = tid >> 2;
    const int s_x = (tid & 3) ^ ((t_pos >> 1) & 3);
    const int chx = s_x << 3;

    // 3 loads/thread per superchunk: 2x Whi, 1x Xhi
    auto stage_g = [&](int u) {
        int sl = u % 3;
        const char* wsrc = (const char*)wg_l + (size_t)u * 16384;
        char* wdst = lds + sl * 16384;
        gl_lds16(wsrc + tid * 16, wdst + tid * 16);
        gl_lds16(wsrc + (tid + 512) * 16, wdst + (tid + 512) * 16);
        int tap = (u >> 2) & 1;
        int ch = ((u & 3) << 5) + chx;
        int tg = t0 + t_pos - (tap ? 0 : d);
        const bf16_t* sph = (tg >= 0)
            ? (xc + ((size_t)b * 4096 + tg) * 128 + ch) : (zeros + ch);
        gl_lds16(sph, lds + 49152 + sl * 8192 + tid * 16);
    };

    stage_g(0);
    stage_g(1);
    const int swz = (l31 >> 1) & 3;
    int aoff[2][2], boff[2][2];
#pragma unroll
    for (int m = 0; m < 2; ++m)
#pragma unroll
        for (int s2 = 0; s2 < 2; ++s2)
            aoff[m][s2] = ((m ? 128 + wm * 32 : wm * 32) + l31) * 64 +
                          (((s2 * 2 + h) ^ swz) << 4);
#pragma unroll
    for (int n = 0; n < 2; ++n)
#pragma unroll
        for (int s2 = 0; s2 < 2; ++s2)
            boff[n][s2] = (wn * 64 + n * 32 + l31) * 64 + (((s2 * 2 + h) ^ swz) << 4);

    for (int u = 0; u < 8; ++u) {
        if (u < 6) {
            stage_g(u + 2);
            asm volatile("s_waitcnt vmcnt(6)" ::: "memory"); // chunk u landed
        } else if (u < 7) {
            asm volatile("s_waitcnt vmcnt(3)" ::: "memory");
        } else {
            asm volatile("s_waitcnt vmcnt(0)" ::: "memory");
        }
        __builtin_amdgcn_s_barrier();

        const char* whb = lds + (u % 3) * 16384;
        const char* xhb = lds + 49152 + (u % 3) * 8192;
        bf16x8 a0[2], a1[2], b0[2], b1[2];
#pragma unroll
        for (int s2 = 0; s2 < 2; ++s2) {
            a0[s2] = *(const bf16x8*)(whb + aoff[0][s2]);
            a1[s2] = *(const bf16x8*)(whb + aoff[1][s2]);
            b0[s2] = *(const bf16x8*)(xhb + boff[0][s2]);
            b1[s2] = *(const bf16x8*)(xhb + boff[1][s2]);
        }
        __builtin_amdgcn_s_setprio(1);
#pragma unroll
        for (int s2 = 0; s2 < 2; ++s2) {
            acc[0][0] = __builtin_amdgcn_mfma_f32_32x32x16_bf16(a0[s2], b0[s2], acc[0][0], 0, 0, 0);
            acc[0][1] = __builtin_amdgcn_mfma_f32_32x32x16_bf16(a0[s2], b1[s2], acc[0][1], 0, 0, 0);
            acc[1][0] = __builtin_amdgcn_mfma_f32_32x32x16_bf16(a1[s2], b0[s2], acc[1][0], 0, 0, 0);
            acc[1][1] = __builtin_amdgcn_mfma_f32_32x32x16_bf16(a1[s2], b1[s2], acc[1][1], 0, 0, 0);
        }
        __builtin_amdgcn_s_setprio(0);
        __builtin_amdgcn_s_barrier();  // reads of slot u%3 retired -> restage safe
    }
    __syncthreads();

    // ---- acts epilogue ----
    // stage ALL res weights (32KB) once; they land under the activation VALU
    if (!skipres) {
#pragma unroll
        for (int r = 0; r < 4; ++r)
            gl_lds16((const char*)wr_l + (r * 512 + tid) * 16,
                     lds + 32768 + (r * 512 + tid) * 16);
    }

    float psum[16];
#pragma unroll
    for (int u = 0; u < 16; ++u) psum[u] = 0.0f;

#pragma unroll
    for (int n = 0; n < 2; ++n) {
        int t = wn * 64 + n * 32 + l31;
        int sw = (t & 7) << 4;
#pragma unroll
        for (int rg = 0; rg < 4; ++rg) {
            int ch0 = wm * 32 + rg * 8 + 4 * h;
            bf16x4 hv;
#pragma unroll
            for (int j = 0; j < 4; ++j) {
                int r = rg * 4 + j;
                float a1v = acc[0][n][r] + dbias[ch0 + j];
                float a2v = acc[1][n][r] + dbias[128 + ch0 + j];
                float a = fast_tanh(a1v) * fast_sigmoid(a2v);
                psum[rg * 4 + j] += a;
                hv[j] = (bf16_t)a;
            }
            int low = (t * 256 + ch0 * 2) ^ sw;
            *(bf16x4*)(lds + low) = hv;    // acts hi-only
        }
    }

#pragma unroll
    for (int u = 0; u < 16; ++u) {
        float v = psum[u];
        v += __shfl_xor(v, 1);
        v += __shfl_xor(v, 2);
        v += __shfl_xor(v, 4);
        v += __shfl_xor(v, 8);
        v += __shfl_xor(v, 16);
        psum[u] = v;
    }
    if (l31 == 0) {
        float* ps = (float*)(lds + 65536);
#pragma unroll
        for (int u = 0; u < 16; ++u) {
            int ch = wm * 32 + (u >> 2) * 8 + 4 * h + (u & 3);
            ps[wn * 128 + ch] = psum[u];
        }
    }

    asm volatile("s_waitcnt vmcnt(0) lgkmcnt(0)" ::: "memory");
    __builtin_amdgcn_s_barrier();   // acts + psum visible; resW landed

    // coalesced per-block partial store (no atomics)
    if (tid < 128) {
        const float* ps = (const float*)(lds + 65536);
        asum_l[((size_t)b * 32 + tile) * 128 + tid] = ps[tid] + ps[128 + tid];
    }
    if (skipres) return;

    // ---- residual K-loop: all operands LDS-resident, no barriers ----
    f32x16 accr[2];
    accr[0] = (f32x16)(0.0f);
    accr[1] = (f32x16)(0.0f);
    int tl_[2], mk_[2];
#pragma unroll
    for (int n = 0; n < 2; ++n) {
        tl_[n] = wn * 64 + n * 32 + l31;
        mk_[n] = (tl_[n] & 7) << 4;
    }

    __builtin_amdgcn_s_setprio(1);
#pragma unroll
    for (int u = 0; u < 4; ++u) {
        const char* ab = lds + 32768 + u * 8192;
        int cb = u << 6;
        bf16x8 av[2], bv[2][2];
#pragma unroll
        for (int s2 = 0; s2 < 2; ++s2) {
            av[s2] = *(const bf16x8*)(ab + (wm * 32 + l31) * 64 +
                                      (((s2 * 2 + h) ^ swz) << 4));
#pragma unroll
            for (int n = 0; n < 2; ++n) {
                int low = (cb + ((s2 * 2 + h) << 4)) ^ mk_[n];
                bv[n][s2] = *(const bf16x8*)(lds + tl_[n] * 256 + low);
            }
        }
#pragma unroll
        for (int s2 = 0; s2 < 2; ++s2) {
            accr[0] = __builtin_amdgcn_mfma_f32_32x32x16_bf16(av[s2], bv[0][s2], accr[0], 0, 0, 0);
            accr[1] = __builtin_amdgcn_mfma_f32_32x32x16_bf16(av[s2], bv[1][s2], accr[1], 0, 0, 0);
        }
    }
    __builtin_amdgcn_s_setprio(0);
    __syncthreads();   // all waves' acts/resW reads retired before restaging

    // ---- residual epilogue (coalesced via LDS, hi-only) ----
#pragma unroll
    for (int n = 0; n < 2; ++n) {
        int t = tl_[n];
        int sw = (t & 7) << 4;
#pragma unroll
        for (int rg = 0; rg < 4; ++rg) {
            int ch0 = wm * 32 + rg * 8 + 4 * h;
            bf16x4 hv;
#pragma unroll
            for (int j = 0; j < 4; ++j)
                hv[j] = (bf16_t)(accr[n][rg * 4 + j] + rbias[ch0 + j]);
            int low = (t * 256 + ch0 * 2) ^ sw;
            *(bf16x4*)(lds + low) = hv;
        }
    }
    __syncthreads();

#pragma unroll
    for (int it = 0; it < 4; ++it) {
        int g = it * 512 + tid;
        int byte = g * 16;
        int t = byte >> 8;
        int off = byte & 255;
        int phys = byte ^ ((t & 7) << 4);
        bf16x8 hv = *(const bf16x8*)(lds + phys);
        size_t gofs = ((size_t)b * 4096 + t0 + t) * 256 + off;   // bytes
        bf16x8 oh = *(const bf16x8*)((const char*)xc + gofs);
        bf16x8 nh;
#pragma unroll
        for (int j = 0; j < 8; ++j)
            nh[j] = (bf16_t)((float)hv[j] + (float)oh[j]);
        *(bf16x8*)((char*)xn + gofs) = nh;
    }
}

// ---------------- input pointwise MFMA (K=256 ch, single phase) ----------------
// LDS 32KB: W dbuf 2x8K [0,16K), X dbuf 2x8K [16K,32K).
__global__ __launch_bounds__(256) void pw_mfma_in(
    const bf16_t* __restrict__ sh, const float* __restrict__ bias,
    bf16_t* __restrict__ xth, int b_off)
{
    __shared__ __align__(16) char lds[32768];
    const int tid = threadIdx.x;
    const int wave = tid >> 6, lane = tid & 63;
    const int l31 = lane & 31, h = lane >> 5;
    const int wm = wave & 1, wn = wave >> 1;
    const int t0 = blockIdx.x * 128;
    const int bz = blockIdx.z;
    const bf16_t* w = (const bf16_t*)g_wi_dev;

    f32x16 acc[2][2];
#pragma unroll
    for (int m = 0; m < 2; ++m)
#pragma unroll
        for (int n = 0; n < 2; ++n) acc[m][n] = (f32x16)(0.0f);

    auto stage = [&](int u, int sl_) {
        const char* wsrc = (const char*)w + (size_t)u * 8192;
        char* wdst = lds + sl_ * 8192;
        gl_lds16(wsrc + tid * 16, wdst + tid * 16);
        gl_lds16(wsrc + (tid + 256) * 16, wdst + (tid + 256) * 16);
#pragma unroll
        for (int it = 0; it < 2; ++it) {
            int row = (tid >> 2) + it * 64;
            int ps = tid & 3;
            int sx = ps ^ ((row >> 1) & 3);
            size_t gi = ((size_t)bz * 4096 + t0 + row) * 256 + u * 32 + sx * 8;
            gl_lds16(sh + gi, lds + 16384 + sl_ * 8192 + (row * 4 + ps) * 16);
        }
    };

    stage(0, 0);
    const int swz = (l31 >> 1) & 3;
    int aoff[2][2], boff[2][2];
#pragma unroll
    for (int m = 0; m < 2; ++m)
#pragma unroll
        for (int s2 = 0; s2 < 2; ++s2)
            aoff[m][s2] = (wm * 64 + m * 32 + l31) * 64 + (((s2 * 2 + h) ^ swz) << 4);
#pragma unroll
    for (int n = 0; n < 2; ++n)
#pragma unroll
        for (int s2 = 0; s2 < 2; ++s2)
            boff[n][s2] = (wn * 64 + n * 32 + l31) * 64 + (((s2 * 2 + h) ^ swz) << 4);

    for (int u = 0; u < 8; ++u) {
        if (u < 7) {
            stage(u + 1, (u + 1) & 1);
            asm volatile("s_waitcnt vmcnt(4)" ::: "memory");
        } else {
            asm volatile("s_waitcnt vmcnt(0)" ::: "memory");
        }
        __builtin_amdgcn_s_barrier();

        const char* wb = lds + (u & 1) * 8192;
        const char* xb = lds + 16384 + (u & 1) * 8192;
        bf16x8 a0[2], a1[2], b0[2], b1[2];
#pragma unroll
        for (int s2 = 0; s2 < 2; ++s2) {
            a0[s2] = *(const bf16x8*)(wb + aoff[0][s2]);
            a1[s2] = *(const bf16x8*)(wb + aoff[1][s2]);
            b0[s2] = *(const bf16x8*)(xb + boff[0][s2]);
            b1[s2] = *(const bf16x8*)(xb + boff[1][s2]);
        }
#pragma unroll
        for (int s2 = 0; s2 < 2; ++s2) {
            acc[0][0] = __builtin_amdgcn_mfma_f32_32x32x16_bf16(a0[s2], b0[s2], acc[0][0], 0, 0, 0);
            acc[0][1] = __builtin_amdgcn_mfma_f32_32x32x16_bf16(a0[s2], b1[s2], acc[0][1], 0, 0, 0);
            acc[1][0] = __builtin_amdgcn_mfma_f32_32x32x16_bf16(a1[s2], b0[s2], acc[1][0], 0, 0, 0);
            acc[1][1] = __builtin_amdgcn_mfma_f32_32x32x16_bf16(a1[s2], b1[s2], acc[1][1], 0, 0, 0);
        }
        __builtin_amdgcn_s_barrier();
    }

    const int b = b_off + bz;
#pragma unroll
    for (int n = 0; n < 2; ++n) {
        int t = wn * 64 + n * 32 + l31;
        size_t trow = ((size_t)b * 4096 + t0 + t) * 128;
#pragma unroll
        for (int m = 0; m < 2; ++m) {
#pragma unroll
            for (int rg = 0; rg < 4; ++rg) {
                int ch0 = wm * 64 + m * 32 + rg * 8 + 4 * h;
                bf16x4 nh;
#pragma unroll
                for (int j = 0; j < 4; ++j)
                    nh[j] = (bf16_t)(acc[m][n][rg * 4 + j] + bias[ch0 + j]);
                *(bf16x4*)(xth + trow + ch0) = nh;
            }
        }
    }
}

// ---------------- output head ----------------
__global__ __launch_bounds__(256) void skip_partial(
    const float* __restrict__ asum2, const float* __restrict__ skip_w)
{
    const int i = blockIdx.x >> 4, b = blockIdx.x & 15, s = threadIdx.x;
    __shared__ float as_[128];
    if (s < 128) {
        const float* p = asum2 + ((size_t)(i * 16 + b) * 32) * 128 + s;
        float v = 0.0f;
#pragma unroll
        for (int tl2 = 0; tl2 < 32; ++tl2) v += p[tl2 * 128];
        as_[s] = v;
    }
    __syncthreads();
    const float* sw = skip_w + ((size_t)i * 256 + s) * 128;
    float t = 0.0f;
#pragma unroll 8
    for (int r = 0; r < 128; ++r) t = fmaf(sw[r], as_[r], t);
    atomicAdd(&g_pooled[b * 256 + s], t);
}

__global__ __launch_bounds__(256) void head_kernel(
    const float* __restrict__ skip_b, const float* __restrict__ w_out,
    const float* __restrict__ lin_w, const float* __restrict__ lin_b,
    float* __restrict__ out)
{
    const int b = blockIdx.x;
    const int s = threadIdx.x;
    float sb = 0.0f;
#pragma unroll
    for (int i = 0; i < 16; ++i) sb += skip_b[i * 256 + s];
    __shared__ float pl[256];
    pl[s] = g_pooled[b * 256 + s] * (1.0f / 4096.0f) + sb;
    __syncthreads();
    __shared__ float o1[12];
    if (s < 12) {
        float v = 0.0f;
        for (int q = 0; q < 256; ++q) v = fmaf(w_out[s * 256 + q], pl[q], v);
        o1[s] = v;
    }
    __syncthreads();
    if (s < 12) {
        float v = lin_b[s];
#pragma unroll
        for (int m = 0; m < 12; ++m) v = fmaf(lin_w[s * 12 + m], o1[m], v);
        out[b * 12 + s] = v;
    }
}

// ================= fallback fp32 path (round-1, proven) =================
__global__ __launch_bounds__(256) void pw_conv_kernel(
    const float* __restrict__ src, const float* __restrict__ W,
    const float* __restrict__ bias, float* __restrict__ dst,
    int K, int accumulate)
{
    __shared__ float Wl[KC][68];
    __shared__ float Sl[KC][68];
    const int tid = threadIdx.x;
    const int t0 = blockIdx.x * 64;
    const int row0 = blockIdx.y * 64;
    const int b = blockIdx.z;
    const int i4 = (tid >> 4) * 4;
    const int j4 = (tid & 15) * 4;
    float acc[4][4];
#pragma unroll
    for (int r = 0; r < 4; ++r) {
        float bv = bias[row0 + i4 + r];
#pragma unroll
        for (int c = 0; c < 4; ++c) acc[r][c] = bv;
    }
    const float* sb = src + (size_t)b * K * 4096;
    for (int k0 = 0; k0 < K; k0 += KC) {
        __syncthreads();
#pragma unroll
        for (int it = 0; it < 8; ++it) {
            int idx = it * 256 + tid;
            int kk = idx & 31, oo = idx >> 5;
            Wl[kk][oo] = W[(size_t)(row0 + oo) * K + (k0 + kk)];
        }
#pragma unroll
        for (int it = 0; it < 8; ++it) {
            int idx = it * 256 + tid;
            int t = idx & 63, kk = idx >> 6;
            Sl[kk][t] = sb[(size_t)(k0 + kk) * 4096 + t0 + t];
        }
        __syncthreads();
#pragma unroll
        for (int kk = 0; kk < KC; ++kk) {
            float4 wv = *(const float4*)&Wl[kk][i4];
            float4 sv = *(const float4*)&Sl[kk][j4];
            float wr_[4] = {wv.x, wv.y, wv.z, wv.w};
            float sc[4] = {sv.x, sv.y, sv.z, sv.w};
#pragma unroll
            for (int r = 0; r < 4; ++r)
#pragma unroll
                for (int c = 0; c < 4; ++c)
                    acc[r][c] = fmaf(wr_[r], sc[c], acc[r][c]);
        }
    }
    float* db = dst + (size_t)b * 128 * 4096;
#pragma unroll
    for (int r = 0; r < 4; ++r) {
        float* p = db + (size_t)(row0 + i4 + r) * 4096 + t0 + j4;
        float4 v;
        if (accumulate) {
            float4 old = *(const float4*)p;
            v.x = acc[r][0] + old.x; v.y = acc[r][1] + old.y;
            v.z = acc[r][2] + old.z; v.w = acc[r][3] + old.w;
        } else {
            v.x = acc[r][0]; v.y = acc[r][1]; v.z = acc[r][2]; v.w = acc[r][3];
        }
        *(float4*)p = v;
    }
}

__global__ __launch_bounds__(256) void gated_conv_kernel(
    const float* __restrict__ x, const float* __restrict__ Wd,
    const float* __restrict__ dbias, float* __restrict__ acts, int d)
{
    __shared__ float Wt0[KC][68], Wt1[KC][68], Ws0[KC][68], Ws1[KC][68];
    __shared__ float Sc[KC][68], Sp[KC][68];
    const int tid = threadIdx.x;
    const int t0 = blockIdx.x * 64;
    const int row0 = blockIdx.y * 64;
    const int b = blockIdx.z;
    const int i4 = (tid >> 4) * 4;
    const int j4 = (tid & 15) * 4;
    float a1[4][4], a2[4][4];
#pragma unroll
    for (int r = 0; r < 4; ++r) {
        float bt = dbias[row0 + i4 + r];
        float bs = dbias[128 + row0 + i4 + r];
#pragma unroll
        for (int c = 0; c < 4; ++c) { a1[r][c] = bt; a2[r][c] = bs; }
    }
    const float* xb = x + (size_t)b * 128 * 4096;
    for (int k0 = 0; k0 < 128; k0 += KC) {
        __syncthreads();
#pragma unroll
        for (int it = 0; it < 8; ++it) {
            int idx = it * 256 + tid;
            int kk = idx & 31, oo = idx >> 5;
            float2 wt = *(const float2*)(Wd + ((size_t)(row0 + oo) * 128 + (k0 + kk)) * 2);
            float2 ws = *(const float2*)(Wd + ((size_t)(128 + row0 + oo) * 128 + (k0 + kk)) * 2);
            Wt0[kk][oo] = wt.x; Wt1[kk][oo] = wt.y;
            Ws0[kk][oo] = ws.x; Ws1[kk][oo] = ws.y;
        }
#pragma unroll
        for (int it = 0; it < 8; ++it) {
            int idx = it * 256 + tid;
            int t = idx & 63, kk = idx >> 6;
            Sc[kk][t] = xb[(size_t)(k0 + kk) * 4096 + t0 + t];
            int gt = t0 + t - d;
            Sp[kk][t] = (gt >= 0) ? xb[(size_t)(k0 + kk) * 4096 + gt] : 0.0f;
        }
        __syncthreads();
#pragma unroll
        for (int kk = 0; kk < KC; ++kk) {
            float4 xcv4 = *(const float4*)&Sc[kk][j4];
            float4 xpv4 = *(const float4*)&Sp[kk][j4];
            float4 wt0 = *(const float4*)&Wt0[kk][i4];
            float4 wt1 = *(const float4*)&Wt1[kk][i4];
            float4 ws0 = *(const float4*)&Ws0[kk][i4];
            float4 ws1 = *(const float4*)&Ws1[kk][i4];
            float xc[4] = {xcv4.x, xcv4.y, xcv4.z, xcv4.w};
            float xp[4] = {xpv4.x, xpv4.y, xpv4.z, xpv4.w};
            float t0r[4] = {wt0.x, wt0.y, wt0.z, wt0.w};
            float t1r[4] = {wt1.x, wt1.y, wt1.z, wt1.w};
            float s0r[4] = {ws0.x, ws0.y, ws0.z, ws0.w};
            float s1r[4] = {ws1.x, ws1.y, ws1.z, ws1.w};
#pragma unroll
            for (int r = 0; r < 4; ++r)
#pragma unroll
                for (int c = 0; c < 4; ++c) {
                    a1[r][c] = fmaf(t0r[r], xp[c], a1[r][c]);
                    a1[r][c] = fmaf(t1r[r], xc[c], a1[r][c]);
                    a2[r][c] = fmaf(s0r[r], xp[c], a2[r][c]);
                    a2[r][c] = fmaf(s1r[r], xc[c], a2[r][c]);
                }
        }
    }
    float* ab = acts + (size_t)b * 128 * 4096;
#pragma unroll
    for (int r = 0; r < 4; ++r) {
        float4 v;
#pragma unroll
        for (int c = 0; c < 4; ++c) {
            float th = tanhf(a1[r][c]);
            float sg = 1.0f / (1.0f + expf(-a2[r][c]));
            ((float*)&v)[c] = th * sg;
        }
        *(float4*)&ab[(size_t)(row0 + i4 + r) * 4096 + t0 + j4] = v;
    }
}

__global__ __launch_bounds__(256) void actsum_kernel(
    const float* __restrict__ acts, float* __restrict__ out)
{
    const int br = blockIdx.x;
    const float* p = acts + (size_t)br * 4096;
    float s = 0.0f;
#pragma unroll
    for (int c = 0; c < 16; ++c) s += p[c * 256 + threadIdx.x];
    __shared__ float red[256];
    red[threadIdx.x] = s;
    __syncthreads();
    for (int off = 128; off > 0; off >>= 1) {
        if (threadIdx.x < off) red[threadIdx.x] += red[threadIdx.x + off];
        __syncthreads();
    }
    if (threadIdx.x == 0) out[br] = red[0];
}

__global__ __launch_bounds__(256) void final_kernel(
    const float* __restrict__ actsum, const float* __restrict__ skip_w,
    const float* __restrict__ skip_b, const float* __restrict__ w_out,
    const float* __restrict__ lin_w, const float* __restrict__ lin_b,
    float* __restrict__ out)
{
    const int b = blockIdx.x;
    const int s = threadIdx.x;
    float acc = 0.0f;
    for (int i = 0; i < 16; ++i) {
        const float* sw = skip_w + ((size_t)i * 256 + s) * 128;
        const float* as = actsum + ((size_t)i * 16 + b) * 128;
        float t = 0.0f;
#pragma unroll 8
        for (int r = 0; r < 128; ++r) t = fmaf(sw[r], as[r], t);
        acc += t;
    }
    float sb = 0.0f;
    for (int i = 0; i < 16; ++i) sb += skip_b[i * 256 + s];
    __shared__ float pl[256];
    pl[s] = acc * (1.0f / 4096.0f) + sb;
    __syncthreads();
    __shared__ float o1[12];
    if (s < 12) {
        float v = 0.0f;
        for (int qq = 0; qq < 256; ++qq) v = fmaf(w_out[s * 256 + qq], pl[qq], v);
        o1[s] = v;
    }
    __syncthreads();
    if (s < 12) {
        float v = lin_b[s];
#pragma unroll
        for (int m = 0; m < 12; ++m) v = fmaf(lin_w[s * 12 + m], o1[m], v);
        out[b * 12 + s] = v;
    }
}

// =======================================================================
extern "C" void kernel_launch(void* const* d_in, const int* in_sizes, int n_in,
                              void* d_out, int out_size, void* d_ws, size_t ws_size,
                              hipStream_t stream)
{
    const float* input    = (const float*)d_in[0];
    const float* w_in     = (const float*)d_in[1];
    const float* b_in     = (const float*)d_in[2];
    const float* dilate_w = (const float*)d_in[3];
    const float* dilate_b = (const float*)d_in[4];
    const float* res_w    = (const float*)d_in[5];
    const float* res_b    = (const float*)d_in[6];
    const float* skip_w   = (const float*)d_in[7];
    const float* skip_b   = (const float*)d_in[8];
    const float* w_out    = (const float*)d_in[9];
    const float* lin_w    = (const float*)d_in[10];
    const float* lin_b    = (const float*)d_in[11];
    float* out = (float*)d_out;

    const size_t NEED = 77103104ULL;
    if (ws_size >= NEED) {
        char* base = (char*)d_ws;
        bf16_t* xtA   = (bf16_t*)(base);                 // 16,777,216 B
        bf16_t* xtB   = (bf16_t*)(base + 16777216);      // 16,777,216 B (also transpose scratch)
        bf16_t* wg    = (bf16_t*)(base + 33554432);      //  2,097,152 B
        bf16_t* wr    = (bf16_t*)(base + 35651584);      //    524,288 B
        float*  asum2 = (float*)(base + 36175872);       //  4,194,304 B
        bf16_t* zeros = (bf16_t*)(base + 40370176);      //     65,536 B

        zero_misc_kernel<<<dim3(128), dim3(256), 0, stream>>>(zeros);
        prep_wg_kernel<<<dim3(4096), dim3(256), 0, stream>>>(dilate_w, wg);
        prep_wr_kernel<<<dim3(960), dim3(256), 0, stream>>>(res_w, wr);
        prep_wi_kernel<<<dim3(128), dim3(256), 0, stream>>>(w_in);

        // input conv in two 8-batch passes; xtB as transpose scratch
        for (int pass = 0; pass < 2; ++pass) {
            transpose_in<<<dim3(64, 4, 8), dim3(256), 0, stream>>>(
                input, xtB, pass * 8);
            pw_mfma_in<<<dim3(32, 1, 8), dim3(256), 0, stream>>>(
                xtB, b_in, xtA, pass * 8);
        }

        for (int i = 0; i < 16; ++i) {
            int d = 1 << (i % 9);
            const bf16_t* xc = (i & 1) ? xtB : xtA;
            bf16_t* xn = (i & 1) ? xtA : xtB;
            int skipres = (i == 15) ? 1 : 0;
            fused_layer<<<dim3(32, 1, 16), dim3(512), 0, stream>>>(
                xc, xn, zeros,
                wg + (size_t)i * 65536, dilate_b + i * 256,
                wr + (size_t)(skipres ? 0 : i) * 16384,
                res_b + (skipres ? 0 : i) * 128,
                asum2 + (size_t)i * 65536, d, skipres);
        }
        skip_partial<<<dim3(256), dim3(256), 0, stream>>>(asum2, skip_w);
        head_kernel<<<dim3(16), dim3(256), 0, stream>>>(
            skip_b, w_out, lin_w, lin_b, out);
    } else {
        // fallback: fp32 VALU path (round 1)
        float* ws   = (float*)d_ws;
        float* x    = ws;
        float* acts = ws + 8388608;
        float* asum = ws + 16777216;
        dim3 grid(64, 2, 16), blk(256, 1, 1);
        pw_conv_kernel<<<grid, blk, 0, stream>>>(input, w_in, b_in, x, 256, 0);
        for (int i = 0; i < 16; ++i) {
            int d = 1 << (i % 9);
            gated_conv_kernel<<<grid, blk, 0, stream>>>(
                x, dilate_w + (size_t)i * 256 * 128 * 2, dilate_b + i * 256, acts, d);
            actsum_kernel<<<dim3(2048), blk, 0, stream>>>(acts, asum + i * 2048);
            if (i < 15) {
                pw_conv_kernel<<<grid, blk, 0, stream>>>(
                    acts, res_w + (size_t)i * 128 * 128, res_b + i * 128, x, 128, 1);
            }
        }
        final_kernel<<<dim3(16), blk, 0, stream>>>(
            asum, skip_w, skip_b, w_out, lin_w, lin_b, out);
    }
}